// Round 1
// baseline (1145.255 us; speedup 1.0000x reference)
//
#include <hip/hip_runtime.h>
#include <math.h>

// Problem constants
#define CB 2
#define CS 512
#define CD 1024
#define CH 16
#define CHD 64
#define CF 4096
#define CE 8
#define CK 2
#define CT (CB*CS)      // 1024 tokens
#define CBH (CB*CH)     // 32 (batch*heads)
#define CEPS 1e-6f
#define MAXROWS 2560    // 2048 + 8*63 padded, rounded up
#define MAXTILES (MAXROWS/64)

// ---------------------------------------------------------------------------
// RMSNorm: one block per token row (D=1024), 256 threads * float4
__global__ __launch_bounds__(256) void rmsnorm_kernel(
    const float* __restrict__ x, const float* __restrict__ w,
    float* __restrict__ out) {
  int t = blockIdx.x;
  int tid = threadIdx.x;
  const float4* xr = (const float4*)(x + (size_t)t * CD);
  float4 xv = xr[tid];
  float ss = xv.x*xv.x + xv.y*xv.y + xv.z*xv.z + xv.w*xv.w;
  for (int off = 32; off > 0; off >>= 1) ss += __shfl_down(ss, off);
  __shared__ float red[4];
  __shared__ float s_scale;
  int lane = tid & 63, wid = tid >> 6;
  if (lane == 0) red[wid] = ss;
  __syncthreads();
  if (tid == 0) {
    float tot = red[0] + red[1] + red[2] + red[3];
    s_scale = rsqrtf(tot / (float)CD + CEPS);
  }
  __syncthreads();
  float sc = s_scale;
  float4 wv = ((const float4*)w)[tid];
  float4 o;
  o.x = xv.x * sc * wv.x;
  o.y = xv.y * sc * wv.y;
  o.z = xv.z * sc * wv.z;
  o.w = xv.w * sc * wv.w;
  ((float4*)(out + (size_t)t * CD))[tid] = o;
}

// ---------------------------------------------------------------------------
// Generic fp32 GEMM: C[M,N] = A[M,K] @ W[K,N] + bias[N] (+ res[M,N])
// 64x64 tile, BK=16, 256 threads, 4x4 per thread. M,N,K multiples of 64/16.
__global__ __launch_bounds__(256) void gemm_bias_kernel(
    const float* __restrict__ A, const float* __restrict__ W,
    const float* __restrict__ bias, const float* __restrict__ res,
    float* __restrict__ C, int M, int N, int Kdim) {
  __shared__ float As[16][64];   // As[k][m]
  __shared__ float Ws[16][64];   // Ws[k][n]
  int m0 = blockIdx.y * 64, n0 = blockIdx.x * 64;
  int tid = threadIdx.x;
  int tx = tid & 15, ty = tid >> 4;
  int arow = tid >> 2, ak = (tid & 3) * 4;     // A-tile loader coords
  int wrow = tid >> 4, wcol = (tid & 15) * 4;  // W-tile loader coords
  float acc[4][4] = {};
  for (int k0 = 0; k0 < Kdim; k0 += 16) {
    float4 a4 = *(const float4*)(A + (size_t)(m0 + arow) * Kdim + k0 + ak);
    As[ak+0][arow] = a4.x; As[ak+1][arow] = a4.y;
    As[ak+2][arow] = a4.z; As[ak+3][arow] = a4.w;
    *(float4*)&Ws[wrow][wcol] =
        *(const float4*)(W + (size_t)(k0 + wrow) * N + n0 + wcol);
    __syncthreads();
#pragma unroll
    for (int kk = 0; kk < 16; ++kk) {
      float4 ra = *(const float4*)&As[kk][ty * 4];
      float4 rb = *(const float4*)&Ws[kk][tx * 4];
      float pa[4] = {ra.x, ra.y, ra.z, ra.w};
      float pb[4] = {rb.x, rb.y, rb.z, rb.w};
#pragma unroll
      for (int i = 0; i < 4; ++i)
#pragma unroll
        for (int j = 0; j < 4; ++j) acc[i][j] += pa[i] * pb[j];
    }
    __syncthreads();
  }
#pragma unroll
  for (int i = 0; i < 4; ++i) {
    int r = m0 + ty * 4 + i;
#pragma unroll
    for (int j = 0; j < 4; ++j) {
      int c = n0 + tx * 4 + j;
      float v = acc[i][j] + bias[c];
      if (res) v += res[(size_t)r * N + c];
      C[(size_t)r * N + c] = v;
    }
  }
}

// ---------------------------------------------------------------------------
// Attention scores: S_tile[64q][64k] = Q Kt / 8 per (b,h). Skips blocks fully
// above the causal diagonal. No masking here (softmax reads only c<=r).
__global__ __launch_bounds__(256) void scores_kernel(
    const float* __restrict__ q, const float* __restrict__ kmat,
    float* __restrict__ scores) {
  int kt = blockIdx.x, qt = blockIdx.y, bh = blockIdx.z;
  if (kt > qt) return;
  int b = bh / CH, h = bh % CH;
  __shared__ float Qs[64][68];
  __shared__ float Ks[64][68];
  int tid = threadIdx.x;
#pragma unroll
  for (int i = 0; i < 4; ++i) {
    int row = (tid >> 4) + i * 16;
    int col = (tid & 15) * 4;
    *(float4*)&Qs[row][col] =
        *(const float4*)(q + (size_t)(b * CS + qt * 64 + row) * CD + h * CHD + col);
    *(float4*)&Ks[row][col] =
        *(const float4*)(kmat + (size_t)(b * CS + kt * 64 + row) * CD + h * CHD + col);
  }
  __syncthreads();
  int tx = tid & 15, ty = tid >> 4;
  float acc[4][4] = {};
#pragma unroll 16
  for (int d = 0; d < 64; ++d) {
    float ra[4], rb[4];
#pragma unroll
    for (int i = 0; i < 4; ++i) ra[i] = Qs[ty * 4 + i][d];
#pragma unroll
    for (int j = 0; j < 4; ++j) rb[j] = Ks[tx * 4 + j][d];
#pragma unroll
    for (int i = 0; i < 4; ++i)
#pragma unroll
      for (int j = 0; j < 4; ++j) acc[i][j] += ra[i] * rb[j];
  }
  size_t base = (size_t)bh * CS * CS;
#pragma unroll
  for (int i = 0; i < 4; ++i) {
    int r = qt * 64 + ty * 4 + i;
#pragma unroll
    for (int j = 0; j < 4; ++j) {
      int c = kt * 64 + tx * 4 + j;
      scores[base + (size_t)r * CS + c] = acc[i][j] * 0.125f;
    }
  }
}

// ---------------------------------------------------------------------------
// Causal row softmax in-place: row r uses cols 0..r, writes 0 for c>r.
__global__ __launch_bounds__(256) void softmax_kernel(float* __restrict__ scores) {
  int row = blockIdx.x;
  int bh = row / CS, r = row % CS;
  float* p = scores + (size_t)bh * CS * CS + (size_t)r * CS;
  int n = r + 1;
  int tid = threadIdx.x;
  __shared__ float buf[CS];
  __shared__ float redm[4], reds[4], sbc[2];
  float m = -1e30f;
  for (int c = tid; c < n; c += 256) {
    float v = p[c];
    buf[c] = v;
    m = fmaxf(m, v);
  }
  for (int off = 32; off > 0; off >>= 1) m = fmaxf(m, __shfl_down(m, off));
  int lane = tid & 63, wid = tid >> 6;
  if (lane == 0) redm[wid] = m;
  __syncthreads();
  if (tid == 0) sbc[0] = fmaxf(fmaxf(redm[0], redm[1]), fmaxf(redm[2], redm[3]));
  __syncthreads();
  float mmax = sbc[0];
  float s = 0.f;
  for (int c = tid; c < n; c += 256) {
    float e = __expf(buf[c] - mmax);
    buf[c] = e;
    s += e;
  }
  for (int off = 32; off > 0; off >>= 1) s += __shfl_down(s, off);
  if (lane == 0) reds[wid] = s;
  __syncthreads();
  if (tid == 0) sbc[1] = reds[0] + reds[1] + reds[2] + reds[3];
  __syncthreads();
  float inv = 1.0f / sbc[1];
  for (int c = tid; c < CS; c += 256) p[c] = (c < n) ? buf[c] * inv : 0.f;
}

// ---------------------------------------------------------------------------
// ctx[64q][64d] = P[64q][S] @ V[S][64d] per (qt, bh); K-loop only kt<=qt.
__global__ __launch_bounds__(256) void pv_kernel(
    const float* __restrict__ scores, const float* __restrict__ v,
    float* __restrict__ ctx) {
  int qt = blockIdx.x, bh = blockIdx.y;
  int b = bh / CH, h = bh % CH;
  __shared__ float Ps[64][68];  // [qrow][k]
  __shared__ float Vs[64][68];  // [k][d]
  int tid = threadIdx.x;
  int tx = tid & 15, ty = tid >> 4;
  float acc[4][4] = {};
  size_t base = (size_t)bh * CS * CS;
  for (int kt = 0; kt <= qt; ++kt) {
#pragma unroll
    for (int i = 0; i < 4; ++i) {
      int row = (tid >> 4) + i * 16;
      int col = (tid & 15) * 4;
      *(float4*)&Ps[row][col] =
          *(const float4*)(scores + base + (size_t)(qt * 64 + row) * CS + kt * 64 + col);
      *(float4*)&Vs[row][col] =
          *(const float4*)(v + (size_t)(b * CS + kt * 64 + row) * CD + h * CHD + col);
    }
    __syncthreads();
#pragma unroll 16
    for (int kk = 0; kk < 64; ++kk) {
      float ra[4];
#pragma unroll
      for (int i = 0; i < 4; ++i) ra[i] = Ps[ty * 4 + i][kk];
      float4 rb4 = *(const float4*)&Vs[kk][tx * 4];
      float rb[4] = {rb4.x, rb4.y, rb4.z, rb4.w};
#pragma unroll
      for (int i = 0; i < 4; ++i)
#pragma unroll
        for (int j = 0; j < 4; ++j) acc[i][j] += ra[i] * rb[j];
    }
    __syncthreads();
  }
#pragma unroll
  for (int i = 0; i < 4; ++i)
#pragma unroll
    for (int j = 0; j < 4; ++j)
      ctx[(size_t)(b * CS + qt * 64 + ty * 4 + i) * CD + h * CHD + tx * 4 + j] =
          acc[i][j];
}

// ---------------------------------------------------------------------------
__global__ void zero_kernel(int* counts, int* cursor, float* psum) {
  int i = threadIdx.x;
  if (i < CE) { counts[i] = 0; cursor[i] = 0; psum[i] = 0.f; }
}

// Router: one block per token. logits[8] = h2 . wr + br; softmax; top-2.
__global__ __launch_bounds__(256) void router_kernel(
    const float* __restrict__ h2, const float* __restrict__ wr,
    const float* __restrict__ br, int* __restrict__ top_i,
    float* __restrict__ top_p, int* __restrict__ counts,
    float* __restrict__ psum) {
  int t = blockIdx.x;
  int tid = threadIdx.x;
  float a[CE] = {};
  float4 hv = ((const float4*)(h2 + (size_t)t * CD))[tid];
  const float* wrow = wr + (size_t)tid * 4 * CE;
  float hvv[4] = {hv.x, hv.y, hv.z, hv.w};
#pragma unroll
  for (int i = 0; i < 4; ++i)
#pragma unroll
    for (int e = 0; e < CE; ++e) a[e] += hvv[i] * wrow[i * CE + e];
  __shared__ float red[256][CE];
#pragma unroll
  for (int e = 0; e < CE; ++e) red[tid][e] = a[e];
  __syncthreads();
  for (int s = 128; s > 0; s >>= 1) {
    if (tid < s) {
#pragma unroll
      for (int e = 0; e < CE; ++e) red[tid][e] += red[tid + s][e];
    }
    __syncthreads();
  }
  if (tid == 0) {
    float logits[CE], probs[CE];
    float mx = -1e30f;
#pragma unroll
    for (int e = 0; e < CE; ++e) {
      logits[e] = red[0][e] + br[e];
      mx = fmaxf(mx, logits[e]);
    }
    float sum = 0.f;
#pragma unroll
    for (int e = 0; e < CE; ++e) { probs[e] = __expf(logits[e] - mx); sum += probs[e]; }
    float inv = 1.0f / sum;
#pragma unroll
    for (int e = 0; e < CE; ++e) probs[e] *= inv;
    int i1 = 0;
#pragma unroll
    for (int e = 1; e < CE; ++e) if (probs[e] > probs[i1]) i1 = e;
    int i2 = (i1 == 0) ? 1 : 0;
#pragma unroll
    for (int e = 0; e < CE; ++e)
      if (e != i1 && probs[e] > probs[i2]) i2 = e;
    float p1 = probs[i1], p2 = probs[i2];
    float s12 = p1 + p2;
    top_i[t * 2 + 0] = i1;
    top_i[t * 2 + 1] = i2;
    top_p[t * 2 + 0] = p1 / s12;
    top_p[t * 2 + 1] = p2 / s12;
    atomicAdd(&counts[i1], 1);
    atomicAdd(&counts[i2], 1);
#pragma unroll
    for (int e = 0; e < CE; ++e) atomicAdd(&psum[e], probs[e]);
  }
}

// Finalize: padded (64-aligned) per-expert offsets, tile->expert map, aux loss.
__global__ void finalize_kernel(const int* __restrict__ counts,
                                const float* __restrict__ psum,
                                int* __restrict__ offs, int* __restrict__ tile_e,
                                int* __restrict__ total_padded,
                                int* __restrict__ row_map,
                                float* __restrict__ aux_out) {
  int tid = threadIdx.x;
  __shared__ int s_off[CE + 1];
  if (tid == 0) {
    int o = 0;
    for (int e = 0; e < CE; ++e) {
      s_off[e] = o;
      offs[e] = o;
      o += ((counts[e] + 63) >> 6) << 6;
    }
    s_off[CE] = o;
    offs[CE] = o;
    *total_padded = o;
    int nt = o >> 6;
    for (int i = 0; i < nt; ++i) {
      int e = 0;
      while (e < CE - 1 && i * 64 >= s_off[e + 1]) e++;
      tile_e[i] = e;
    }
    float aux = 0.f;
    for (int e = 0; e < CE; ++e)
      aux += ((float)counts[e] / (float)(CT * CK)) * (psum[e] / (float)CT);
    aux_out[0] = aux * (float)CE;
  }
  __syncthreads();
  for (int i = tid; i < MAXROWS; i += blockDim.x) row_map[i] = -1;
}

__global__ void gather_kernel(const int* __restrict__ top_i,
                              const int* __restrict__ offs,
                              int* __restrict__ cursor, int* __restrict__ row_map,
                              int* __restrict__ row_of) {
  int idx = blockIdx.x * blockDim.x + threadIdx.x;
  if (idx >= CT * CK) return;
  int e = top_i[idx];
  int pos = offs[e] + atomicAdd(&cursor[e], 1);
  row_map[pos] = idx >> 1;  // token id
  row_of[idx] = pos;
}

// ---------------------------------------------------------------------------
// Grouped expert GEMM. Rows are 64-padded per expert so each 64-row tile has
// one expert. If row_map != null, A rows gathered from Asrc[row_map[r]]
// (-1 -> zeros). Optional silu.
__global__ __launch_bounds__(256) void gemm_group_kernel(
    const float* __restrict__ Asrc, const int* __restrict__ row_map,
    const float* __restrict__ Wbase, const float* __restrict__ bbase,
    const int* __restrict__ tile_e, const int* __restrict__ total_padded,
    float* __restrict__ C, int N, int Kdim, int do_silu) {
  int rt = blockIdx.y;
  if (rt * 64 >= *total_padded) return;
  int e = tile_e[rt];
  const float* W = Wbase + (size_t)e * Kdim * N;
  const float* bias = bbase + (size_t)e * N;
  int n0 = blockIdx.x * 64;
  __shared__ float As[16][64];
  __shared__ float Ws[16][64];
  int tid = threadIdx.x;
  int tx = tid & 15, ty = tid >> 4;
  int lrow = tid >> 2, ak = (tid & 3) * 4;
  int wrow = tid >> 4, wcol = (tid & 15) * 4;
  const float* Arow = Asrc;
  bool valid = true;
  if (row_map) {
    int tok = row_map[rt * 64 + lrow];
    if (tok < 0) valid = false;
    else Arow = Asrc + (size_t)tok * Kdim;
  } else {
    Arow = Asrc + (size_t)(rt * 64 + lrow) * Kdim;
  }
  float acc[4][4] = {};
  for (int k0 = 0; k0 < Kdim; k0 += 16) {
    float4 a4 = make_float4(0.f, 0.f, 0.f, 0.f);
    if (valid) a4 = *(const float4*)(Arow + k0 + ak);
    As[ak+0][lrow] = a4.x; As[ak+1][lrow] = a4.y;
    As[ak+2][lrow] = a4.z; As[ak+3][lrow] = a4.w;
    *(float4*)&Ws[wrow][wcol] =
        *(const float4*)(W + (size_t)(k0 + wrow) * N + n0 + wcol);
    __syncthreads();
#pragma unroll
    for (int kk = 0; kk < 16; ++kk) {
      float4 ra = *(const float4*)&As[kk][ty * 4];
      float4 rb = *(const float4*)&Ws[kk][tx * 4];
      float pa[4] = {ra.x, ra.y, ra.z, ra.w};
      float pb[4] = {rb.x, rb.y, rb.z, rb.w};
#pragma unroll
      for (int i = 0; i < 4; ++i)
#pragma unroll
        for (int j = 0; j < 4; ++j) acc[i][j] += pa[i] * pb[j];
    }
    __syncthreads();
  }
#pragma unroll
  for (int i = 0; i < 4; ++i) {
    int r = rt * 64 + ty * 4 + i;
#pragma unroll
    for (int j = 0; j < 4; ++j) {
      int c = n0 + tx * 4 + j;
      float v = acc[i][j] + bias[c];
      if (do_silu) v = v / (1.f + __expf(-v));
      C[(size_t)r * N + c] = v;
    }
  }
}

// out[t] = x1[t] + sum_k top_p[t,k] * ff_rows[row_of[t,k]]
__global__ __launch_bounds__(256) void combine_kernel(
    const float* __restrict__ x1, const float* __restrict__ ff_rows,
    const int* __restrict__ row_of, const float* __restrict__ top_p,
    float* __restrict__ out) {
  int t = blockIdx.x;
  int tid = threadIdx.x;
  float4 r = ((const float4*)(x1 + (size_t)t * CD))[tid];
#pragma unroll
  for (int s = 0; s < CK; ++s) {
    float w = top_p[t * 2 + s];
    int row = row_of[t * 2 + s];
    float4 f = ((const float4*)(ff_rows + (size_t)row * CD))[tid];
    r.x += w * f.x; r.y += w * f.y; r.z += w * f.z; r.w += w * f.w;
  }
  ((float4*)(out + (size_t)t * CD))[tid] = r;
}

// ---------------------------------------------------------------------------
extern "C" void kernel_launch(void* const* d_in, const int* in_sizes, int n_in,
                              void* d_out, int out_size, void* d_ws,
                              size_t ws_size, hipStream_t stream) {
  const float* x   = (const float*)d_in[0];
  const float* n1w = (const float*)d_in[1];
  const float* n2w = (const float*)d_in[2];
  const float* wq  = (const float*)d_in[3];
  const float* bq  = (const float*)d_in[4];
  const float* wk  = (const float*)d_in[5];
  const float* bk  = (const float*)d_in[6];
  const float* wv  = (const float*)d_in[7];
  const float* bv  = (const float*)d_in[8];
  const float* wo  = (const float*)d_in[9];
  const float* bo  = (const float*)d_in[10];
  const float* wr  = (const float*)d_in[11];
  const float* br  = (const float*)d_in[12];
  const float* w1  = (const float*)d_in[13];
  const float* b1  = (const float*)d_in[14];
  const float* w2  = (const float*)d_in[15];
  const float* b2  = (const float*)d_in[16];
  float* out = (float*)d_out;

  float* ws = (float*)d_ws;
  size_t o = 0;
  float* f_h   = ws + o; o += (size_t)CT * CD;
  float* f_q   = ws + o; o += (size_t)CT * CD;
  float* f_k   = ws + o; o += (size_t)CT * CD;
  float* f_v   = ws + o; o += (size_t)CT * CD;
  float* f_ctx = ws + o; o += (size_t)CT * CD;
  float* f_x1  = ws + o; o += (size_t)CT * CD;
  float* f_big = ws + o; o += (size_t)MAXROWS * CF;  // scores (32MB) / hid (42MB)
  float* f_ff  = ws + o; o += (size_t)MAXROWS * CD;
  float* f_topp = ws + o; o += CT * CK;
  float* f_psum = ws + o; o += CE;
  int* i_topi   = (int*)(ws + o);
  int* i_rowof  = i_topi + CT * CK;
  int* i_rowmap = i_rowof + CT * CK;
  int* i_counts = i_rowmap + MAXROWS;
  int* i_cursor = i_counts + CE;
  int* i_offs   = i_cursor + CE;
  int* i_tile   = i_offs + CE + 1;
  int* i_total  = i_tile + MAXTILES;

  dim3 b256(256);
  dim3 gproj(CD / 64, CT / 64);

  rmsnorm_kernel<<<CT, b256, 0, stream>>>(x, n1w, f_h);
  gemm_bias_kernel<<<gproj, b256, 0, stream>>>(f_h, wq, bq, nullptr, f_q, CT, CD, CD);
  gemm_bias_kernel<<<gproj, b256, 0, stream>>>(f_h, wk, bk, nullptr, f_k, CT, CD, CD);
  gemm_bias_kernel<<<gproj, b256, 0, stream>>>(f_h, wv, bv, nullptr, f_v, CT, CD, CD);
  scores_kernel<<<dim3(CS / 64, CS / 64, CBH), b256, 0, stream>>>(f_q, f_k, f_big);
  softmax_kernel<<<CBH * CS, b256, 0, stream>>>(f_big);
  pv_kernel<<<dim3(CS / 64, CBH), b256, 0, stream>>>(f_big, f_v, f_ctx);
  gemm_bias_kernel<<<gproj, b256, 0, stream>>>(f_ctx, wo, bo, x, f_x1, CT, CD, CD);
  rmsnorm_kernel<<<CT, b256, 0, stream>>>(f_x1, n2w, f_h);
  zero_kernel<<<1, 64, 0, stream>>>(i_counts, i_cursor, f_psum);
  router_kernel<<<CT, b256, 0, stream>>>(f_h, wr, br, i_topi, f_topp, i_counts, f_psum);
  finalize_kernel<<<1, 64, 0, stream>>>(i_counts, f_psum, i_offs, i_tile, i_total,
                                        i_rowmap, out + (size_t)CT * CD);
  gather_kernel<<<(CT * CK + 255) / 256, b256, 0, stream>>>(i_topi, i_offs, i_cursor,
                                                            i_rowmap, i_rowof);
  gemm_group_kernel<<<dim3(CF / 64, MAXTILES), b256, 0, stream>>>(
      f_h, i_rowmap, w1, b1, i_tile, i_total, f_big, CF, CD, 1);
  gemm_group_kernel<<<dim3(CD / 64, MAXTILES), b256, 0, stream>>>(
      f_big, nullptr, w2, b2, i_tile, i_total, f_ff, CD, CF, 0);
  combine_kernel<<<CT, b256, 0, stream>>>(f_x1, f_ff, i_rowof, f_topp, out);
}

// Round 3
// 777.457 us; speedup vs baseline: 1.4731x; 1.4731x over previous
//
#include <hip/hip_runtime.h>
#include <math.h>

// Problem constants
#define CB 2
#define CS 512
#define CD 1024
#define CH 16
#define CHD 64
#define CF 4096
#define CE 8
#define CK 2
#define CT (CB*CS)      // 1024 tokens
#define CBH (CB*CH)     // 32 (batch*heads)
#define CEPS 1e-6f
#define QKVP 3072       // packed q|k|v row pitch
#define MAXROWS 3072    // 2048 + 8*127 padded to 128
#define MAXTILES (MAXROWS/128)

typedef __attribute__((ext_vector_type(8))) short bf16x8;
typedef __attribute__((ext_vector_type(4))) float f32x4;

__device__ __forceinline__ short f2bf(float f) {
  unsigned u = __float_as_uint(f);
  unsigned r = (u + 0x7FFF + ((u >> 16) & 1)) >> 16;
  return (short)r;
}

__device__ __forceinline__ void gload_lds16(const void* g, void* l) {
  __builtin_amdgcn_global_load_lds(
      (const __attribute__((address_space(1))) unsigned int*)g,
      (__attribute__((address_space(3))) unsigned int*)l, 16, 0, 0);
}

// ---------------------------------------------------------------------------
// RMSNorm: one block per token row (D=1024), 256 threads * float4. fp32 out.
__global__ __launch_bounds__(256) void rmsnorm_kernel(
    const float* __restrict__ x, const float* __restrict__ w,
    float* __restrict__ out) {
  int t = blockIdx.x;
  int tid = threadIdx.x;
  float4 xv = ((const float4*)(x + (size_t)t * CD))[tid];
  float ss = xv.x*xv.x + xv.y*xv.y + xv.z*xv.z + xv.w*xv.w;
  for (int off = 32; off > 0; off >>= 1) ss += __shfl_down(ss, off);
  __shared__ float red[4];
  __shared__ float s_scale;
  int lane = tid & 63, wid = tid >> 6;
  if (lane == 0) red[wid] = ss;
  __syncthreads();
  if (tid == 0) {
    float tot = red[0] + red[1] + red[2] + red[3];
    s_scale = rsqrtf(tot / (float)CD + CEPS);
  }
  __syncthreads();
  float sc = s_scale;
  float4 wv = ((const float4*)w)[tid];
  float4 o;
  o.x = xv.x * sc * wv.x;
  o.y = xv.y * sc * wv.y;
  o.z = xv.z * sc * wv.z;
  o.w = xv.w * sc * wv.w;
  ((float4*)(out + (size_t)t * CD))[tid] = o;
}

// ---------------------------------------------------------------------------
// fp32 GEMM: C[M,N] = A[M,K] @ W[K,N] + bias[N] (+res). C/res stride = Cld
// (for packed outputs). 64x64 tile, BK=16, 256 threads, 4x4 per thread.
__global__ __launch_bounds__(256) void gemm_bias_kernel(
    const float* __restrict__ A, const float* __restrict__ W,
    const float* __restrict__ bias, const float* __restrict__ res,
    float* __restrict__ C, int M, int N, int Kdim, int Cld) {
  __shared__ float As[16][64];   // As[k][m]
  __shared__ float Ws[16][64];   // Ws[k][n]
  int m0 = blockIdx.y * 64, n0 = blockIdx.x * 64;
  int tid = threadIdx.x;
  int tx = tid & 15, ty = tid >> 4;
  int arow = tid >> 2, ak = (tid & 3) * 4;
  int wrow = tid >> 4, wcol = (tid & 15) * 4;
  float acc[4][4] = {};
  for (int k0 = 0; k0 < Kdim; k0 += 16) {
    float4 a4 = *(const float4*)(A + (size_t)(m0 + arow) * Kdim + k0 + ak);
    As[ak+0][arow] = a4.x; As[ak+1][arow] = a4.y;
    As[ak+2][arow] = a4.z; As[ak+3][arow] = a4.w;
    *(float4*)&Ws[wrow][wcol] =
        *(const float4*)(W + (size_t)(k0 + wrow) * N + n0 + wcol);
    __syncthreads();
#pragma unroll
    for (int kk = 0; kk < 16; ++kk) {
      float4 ra = *(const float4*)&As[kk][ty * 4];
      float4 rb = *(const float4*)&Ws[kk][tx * 4];
      float pa[4] = {ra.x, ra.y, ra.z, ra.w};
      float pb[4] = {rb.x, rb.y, rb.z, rb.w};
#pragma unroll
      for (int i = 0; i < 4; ++i)
#pragma unroll
        for (int j = 0; j < 4; ++j) acc[i][j] += pa[i] * pb[j];
    }
    __syncthreads();
  }
#pragma unroll
  for (int i = 0; i < 4; ++i) {
    int r = m0 + ty * 4 + i;
#pragma unroll
    for (int j = 0; j < 4; ++j) {
      int c = n0 + tx * 4 + j;
      float v = acc[i][j] + bias[c];
      if (res) v += res[(size_t)r * Cld + c];
      C[(size_t)r * Cld + c] = v;
    }
  }
}

// ---------------------------------------------------------------------------
// Tiled transpose + fp32->bf16 convert: W[e][Kd][Nd] f32 -> Wt[e][Nd][Kd] bf16
__global__ __launch_bounds__(256) void transpose_convert_kernel(
    const float* __restrict__ W, short* __restrict__ Wt, int Kd, int Nd) {
  int e = blockIdx.z;
  const float* Wb = W + (size_t)e * Kd * Nd;
  short* Wtb = Wt + (size_t)e * Kd * Nd;
  int n0 = blockIdx.x * 32, k0 = blockIdx.y * 32;
  __shared__ float tile[32][33];
  int tx = threadIdx.x & 31, ty = threadIdx.x >> 5;
#pragma unroll
  for (int i = 0; i < 4; ++i)
    tile[ty + i * 8][tx] = Wb[(size_t)(k0 + ty + i * 8) * Nd + n0 + tx];
  __syncthreads();
#pragma unroll
  for (int i = 0; i < 4; ++i)
    Wtb[(size_t)(n0 + ty + i * 8) * Kd + k0 + tx] = f2bf(tile[tx][ty + i * 8]);
}

// ---------------------------------------------------------------------------
// bf16 MFMA grouped GEMM: C[M,N] = A[M,K] @ Bt[e][N,K]^T (+bias[e], silu,
// bf16 out). 128x128 tile, BK=32, 4 waves (2x2), 4x4 16x16x32 frags per wave.
// LDS fragment-ordered: chunk (g*128 + row)*16B holds A[row][k0+g*8..+8].
__device__ __forceinline__ void stage_tile(const short* __restrict__ gbase,
                                           int ldK, int row0, int k0,
                                           short* lds, int tid) {
  int wbase = tid & 192;  // wave-uniform chunk base
#pragma unroll
  for (int ic = 0; ic < 2; ++ic) {
    int c = ic * 256 + tid;
    int g = c >> 7, r = c & 127;
    const short* gsrc = gbase + (size_t)(row0 + r) * ldK + k0 + g * 8;
    short* ldst = lds + (size_t)(ic * 256 + wbase) * 8;
    gload_lds16(gsrc, ldst);
  }
}

template <int SILU, int OUTBF>
__global__ __launch_bounds__(256) void mfma_gemm_kernel(
    const short* __restrict__ A, const short* __restrict__ Bt,
    const float* __restrict__ bias, void* __restrict__ Cout, int N, int K,
    const int* __restrict__ tile_e, const int* __restrict__ total_rows) {
  __shared__ short As[4096];
  __shared__ short Bs[4096];
  int tid = threadIdx.x;
  int m0 = blockIdx.y * 128, n0 = blockIdx.x * 128;
  if (m0 >= *total_rows) return;
  int e = tile_e[blockIdx.y];
  const short* Btb = Bt + (size_t)e * N * K;
  const float* biasb = bias + (size_t)e * N;
  int lane = tid & 63, w = tid >> 6;
  int wr = w >> 1, wc = w & 1;
  int l15 = lane & 15, l4 = lane >> 4;
  f32x4 acc[4][4] = {};
  for (int k0 = 0; k0 < K; k0 += 32) {
    stage_tile(A, K, m0, k0, As, tid);
    stage_tile(Btb, K, n0, k0, Bs, tid);
    __syncthreads();
    bf16x8 a[4], b[4];
#pragma unroll
    for (int m = 0; m < 4; ++m)
      a[m] = *(const bf16x8*)&As[(size_t)(l4 * 128 + wr * 64 + m * 16 + l15) * 8];
#pragma unroll
    for (int n = 0; n < 4; ++n)
      b[n] = *(const bf16x8*)&Bs[(size_t)(l4 * 128 + wc * 64 + n * 16 + l15) * 8];
#pragma unroll
    for (int m = 0; m < 4; ++m)
#pragma unroll
      for (int n = 0; n < 4; ++n)
        acc[m][n] =
            __builtin_amdgcn_mfma_f32_16x16x32_bf16(a[m], b[n], acc[m][n], 0, 0, 0);
    __syncthreads();
  }
  float* outf = (float*)Cout;
  short* outb = (short*)Cout;
#pragma unroll
  for (int m = 0; m < 4; ++m) {
    int row = m0 + wr * 64 + m * 16 + l4 * 4;
#pragma unroll
    for (int n = 0; n < 4; ++n) {
      int col = n0 + wc * 64 + n * 16 + l15;
      float bv = biasb[col];
#pragma unroll
      for (int q = 0; q < 4; ++q) {
        float v = acc[m][n][q] + bv;
        if (SILU) v = v / (1.f + __expf(-v));
        if (OUTBF) outb[(size_t)(row + q) * N + col] = f2bf(v);
        else outf[(size_t)(row + q) * N + col] = v;
      }
    }
  }
}

// ---------------------------------------------------------------------------
// Attention scores: S_tile[64q][64k] = Q Kt / 8 per (b,h); packed qkv input.
__global__ __launch_bounds__(256) void scores_kernel(
    const float* __restrict__ qkv, float* __restrict__ scores) {
  int kt = blockIdx.x, qt = blockIdx.y, bh = blockIdx.z;
  if (kt > qt) return;
  int b = bh / CH, h = bh % CH;
  __shared__ float Qs[64][68];
  __shared__ float Ks[64][68];
  int tid = threadIdx.x;
#pragma unroll
  for (int i = 0; i < 4; ++i) {
    int row = (tid >> 4) + i * 16;
    int col = (tid & 15) * 4;
    *(float4*)&Qs[row][col] =
        *(const float4*)(qkv + (size_t)(b * CS + qt * 64 + row) * QKVP + h * CHD + col);
    *(float4*)&Ks[row][col] =
        *(const float4*)(qkv + (size_t)(b * CS + kt * 64 + row) * QKVP + 1024 + h * CHD + col);
  }
  __syncthreads();
  int tx = tid & 15, ty = tid >> 4;
  float acc[4][4] = {};
#pragma unroll 16
  for (int d = 0; d < 64; ++d) {
    float ra[4], rb[4];
#pragma unroll
    for (int i = 0; i < 4; ++i) ra[i] = Qs[ty * 4 + i][d];
#pragma unroll
    for (int j = 0; j < 4; ++j) rb[j] = Ks[tx * 4 + j][d];
#pragma unroll
    for (int i = 0; i < 4; ++i)
#pragma unroll
      for (int j = 0; j < 4; ++j) acc[i][j] += ra[i] * rb[j];
  }
  size_t base = (size_t)bh * CS * CS;
#pragma unroll
  for (int i = 0; i < 4; ++i) {
    int r = qt * 64 + ty * 4 + i;
#pragma unroll
    for (int j = 0; j < 4; ++j) {
      int c = kt * 64 + tx * 4 + j;
      scores[base + (size_t)r * CS + c] = acc[i][j] * 0.125f;
    }
  }
}

// Causal row softmax in-place: row r uses cols 0..r, writes 0 for c>r.
__global__ __launch_bounds__(256) void softmax_kernel(float* __restrict__ scores) {
  int row = blockIdx.x;
  int bh = row / CS, r = row % CS;
  float* p = scores + (size_t)bh * CS * CS + (size_t)r * CS;
  int n = r + 1;
  int tid = threadIdx.x;
  __shared__ float buf[CS];
  __shared__ float redm[4], reds[4], sbc[2];
  float m = -1e30f;
  for (int c = tid; c < n; c += 256) {
    float v = p[c];
    buf[c] = v;
    m = fmaxf(m, v);
  }
  for (int off = 32; off > 0; off >>= 1) m = fmaxf(m, __shfl_down(m, off));
  int lane = tid & 63, wid = tid >> 6;
  if (lane == 0) redm[wid] = m;
  __syncthreads();
  if (tid == 0) sbc[0] = fmaxf(fmaxf(redm[0], redm[1]), fmaxf(redm[2], redm[3]));
  __syncthreads();
  float mmax = sbc[0];
  float s = 0.f;
  for (int c = tid; c < n; c += 256) {
    float e = __expf(buf[c] - mmax);
    buf[c] = e;
    s += e;
  }
  for (int off = 32; off > 0; off >>= 1) s += __shfl_down(s, off);
  if (lane == 0) reds[wid] = s;
  __syncthreads();
  if (tid == 0) sbc[1] = reds[0] + reds[1] + reds[2] + reds[3];
  __syncthreads();
  float inv = 1.0f / sbc[1];
  for (int c = tid; c < CS; c += 256) p[c] = (c < n) ? buf[c] * inv : 0.f;
}

// ctx[64q][64d] = P[64q][S] @ V[S][64d] per (qt, bh); kt<=qt only. fp32 out.
__global__ __launch_bounds__(256) void pv_kernel(
    const float* __restrict__ scores, const float* __restrict__ qkv,
    float* __restrict__ ctx) {
  int qt = blockIdx.x, bh = blockIdx.y;
  int b = bh / CH, h = bh % CH;
  __shared__ float Ps[64][68];
  __shared__ float Vs[64][68];
  int tid = threadIdx.x;
  int tx = tid & 15, ty = tid >> 4;
  float acc[4][4] = {};
  size_t base = (size_t)bh * CS * CS;
  for (int kt = 0; kt <= qt; ++kt) {
#pragma unroll
    for (int i = 0; i < 4; ++i) {
      int row = (tid >> 4) + i * 16;
      int col = (tid & 15) * 4;
      *(float4*)&Ps[row][col] =
          *(const float4*)(scores + base + (size_t)(qt * 64 + row) * CS + kt * 64 + col);
      *(float4*)&Vs[row][col] =
          *(const float4*)(qkv + (size_t)(b * CS + kt * 64 + row) * QKVP + 2048 + h * CHD + col);
    }
    __syncthreads();
#pragma unroll 16
    for (int kk = 0; kk < 64; ++kk) {
      float ra[4];
#pragma unroll
      for (int i = 0; i < 4; ++i) ra[i] = Ps[ty * 4 + i][kk];
      float4 rb4 = *(const float4*)&Vs[kk][tx * 4];
      float rb[4] = {rb4.x, rb4.y, rb4.z, rb4.w};
#pragma unroll
      for (int i = 0; i < 4; ++i)
#pragma unroll
        for (int j = 0; j < 4; ++j) acc[i][j] += ra[i] * rb[j];
    }
    __syncthreads();
  }
#pragma unroll
  for (int i = 0; i < 4; ++i)
#pragma unroll
    for (int j = 0; j < 4; ++j)
      ctx[(size_t)(b * CS + qt * 64 + ty * 4 + i) * CD + h * CHD + tx * 4 + j] =
          acc[i][j];
}

// ---------------------------------------------------------------------------
__global__ void zero_kernel(int* counts, int* cursor, float* psum) {
  int i = threadIdx.x;
  if (i < CE) { counts[i] = 0; cursor[i] = 0; psum[i] = 0.f; }
}

__global__ __launch_bounds__(256) void router_kernel(
    const float* __restrict__ h2, const float* __restrict__ wr,
    const float* __restrict__ br, int* __restrict__ top_i,
    float* __restrict__ top_p, int* __restrict__ counts,
    float* __restrict__ psum) {
  int t = blockIdx.x;
  int tid = threadIdx.x;
  float a[CE] = {};
  float4 hv = ((const float4*)(h2 + (size_t)t * CD))[tid];
  const float* wrow = wr + (size_t)tid * 4 * CE;
  float hvv[4] = {hv.x, hv.y, hv.z, hv.w};
#pragma unroll
  for (int i = 0; i < 4; ++i)
#pragma unroll
    for (int e = 0; e < CE; ++e) a[e] += hvv[i] * wrow[i * CE + e];
  __shared__ float red[256][CE];
#pragma unroll
  for (int e = 0; e < CE; ++e) red[tid][e] = a[e];
  __syncthreads();
  for (int s = 128; s > 0; s >>= 1) {
    if (tid < s) {
#pragma unroll
      for (int e = 0; e < CE; ++e) red[tid][e] += red[tid + s][e];
    }
    __syncthreads();
  }
  if (tid == 0) {
    float logits[CE], probs[CE];
    float mx = -1e30f;
#pragma unroll
    for (int e = 0; e < CE; ++e) {
      logits[e] = red[0][e] + br[e];
      mx = fmaxf(mx, logits[e]);
    }
    float sum = 0.f;
#pragma unroll
    for (int e = 0; e < CE; ++e) { probs[e] = __expf(logits[e] - mx); sum += probs[e]; }
    float inv = 1.0f / sum;
#pragma unroll
    for (int e = 0; e < CE; ++e) probs[e] *= inv;
    int i1 = 0;
#pragma unroll
    for (int e = 1; e < CE; ++e) if (probs[e] > probs[i1]) i1 = e;
    int i2 = (i1 == 0) ? 1 : 0;
#pragma unroll
    for (int e = 0; e < CE; ++e)
      if (e != i1 && probs[e] > probs[i2]) i2 = e;
    float p1 = probs[i1], p2 = probs[i2];
    float s12 = p1 + p2;
    top_i[t * 2 + 0] = i1;
    top_i[t * 2 + 1] = i2;
    top_p[t * 2 + 0] = p1 / s12;
    top_p[t * 2 + 1] = p2 / s12;
    atomicAdd(&counts[i1], 1);
    atomicAdd(&counts[i2], 1);
#pragma unroll
    for (int e = 0; e < CE; ++e) atomicAdd(&psum[e], probs[e]);
  }
}

// Finalize: 128-aligned per-expert offsets, tile->expert map, aux loss.
__global__ void finalize_kernel(const int* __restrict__ counts,
                                const float* __restrict__ psum,
                                int* __restrict__ offs, int* __restrict__ tile_e,
                                int* __restrict__ total_padded,
                                int* __restrict__ row_map,
                                float* __restrict__ aux_out) {
  int tid = threadIdx.x;
  __shared__ int s_off[CE + 1];
  if (tid == 0) {
    int o = 0;
    for (int e = 0; e < CE; ++e) {
      s_off[e] = o;
      offs[e] = o;
      o += ((counts[e] + 127) >> 7) << 7;
    }
    s_off[CE] = o;
    offs[CE] = o;
    *total_padded = o;
    int nt = o >> 7;
    for (int i = 0; i < nt; ++i) {
      int e = 0;
      while (e < CE - 1 && i * 128 >= s_off[e + 1]) e++;
      tile_e[i] = e;
    }
    float aux = 0.f;
    for (int e = 0; e < CE; ++e)
      aux += ((float)counts[e] / (float)(CT * CK)) * (psum[e] / (float)CT);
    aux_out[0] = aux * (float)CE;
  }
  __syncthreads();
  for (int i = tid; i < MAXROWS; i += blockDim.x) row_map[i] = -1;
}

__global__ void gather_kernel(const int* __restrict__ top_i,
                              const int* __restrict__ offs,
                              int* __restrict__ cursor, int* __restrict__ row_map,
                              int* __restrict__ row_of) {
  int idx = blockIdx.x * blockDim.x + threadIdx.x;
  if (idx >= CT * CK) return;
  int e = top_i[idx];
  int pos = offs[e] + atomicAdd(&cursor[e], 1);
  row_map[pos] = idx >> 1;
  row_of[idx] = pos;
}

// Xg[row] = bf16(h2[row_map[row]]) or zeros for pad rows.
__global__ __launch_bounds__(256) void gatherx_kernel(
    const float* __restrict__ h2, const int* __restrict__ row_map,
    short* __restrict__ Xg) {
  int row = blockIdx.x;
  int tid = threadIdx.x;
  int tok = row_map[row];
  short4 o;
  if (tok < 0) {
    o = make_short4(0, 0, 0, 0);
  } else {
    float4 v = ((const float4*)(h2 + (size_t)tok * CD))[tid];
    o = make_short4(f2bf(v.x), f2bf(v.y), f2bf(v.z), f2bf(v.w));
  }
  ((short4*)(Xg + (size_t)row * CD))[tid] = o;
}

// out[t] = x1[t] + sum_k top_p[t,k] * ff_rows[row_of[t,k]]
__global__ __launch_bounds__(256) void combine_kernel(
    const float* __restrict__ x1, const float* __restrict__ ff_rows,
    const int* __restrict__ row_of, const float* __restrict__ top_p,
    float* __restrict__ out) {
  int t = blockIdx.x;
  int tid = threadIdx.x;
  float4 r = ((const float4*)(x1 + (size_t)t * CD))[tid];
#pragma unroll
  for (int s = 0; s < CK; ++s) {
    float w = top_p[t * 2 + s];
    int row = row_of[t * 2 + s];
    float4 f = ((const float4*)(ff_rows + (size_t)row * CD))[tid];
    r.x += w * f.x; r.y += w * f.y; r.z += w * f.z; r.w += w * f.w;
  }
  ((float4*)(out + (size_t)t * CD))[tid] = r;
}

// ---------------------------------------------------------------------------
extern "C" void kernel_launch(void* const* d_in, const int* in_sizes, int n_in,
                              void* d_out, int out_size, void* d_ws,
                              size_t ws_size, hipStream_t stream) {
  const float* x   = (const float*)d_in[0];
  const float* n1w = (const float*)d_in[1];
  const float* n2w = (const float*)d_in[2];
  const float* wq  = (const float*)d_in[3];
  const float* bq  = (const float*)d_in[4];
  const float* wk  = (const float*)d_in[5];
  const float* bk  = (const float*)d_in[6];
  const float* wv  = (const float*)d_in[7];
  const float* bv  = (const float*)d_in[8];
  const float* wo  = (const float*)d_in[9];
  const float* bo  = (const float*)d_in[10];
  const float* wr  = (const float*)d_in[11];
  const float* br  = (const float*)d_in[12];
  const float* w1  = (const float*)d_in[13];
  const float* b1  = (const float*)d_in[14];
  const float* w2  = (const float*)d_in[15];
  const float* b2  = (const float*)d_in[16];
  float* out = (float*)d_out;

  char* base = (char*)d_ws;
  size_t off = 0;
  auto alloc = [&](size_t bytes) -> void* {
    void* p = base + off;
    off += (bytes + 255) & ~(size_t)255;
    return p;
  };
  float* f_h    = (float*)alloc((size_t)CT * CD * 4);       // rmsnorm1 (fp32)
  float* f_qkv  = (float*)alloc((size_t)CT * QKVP * 4);     // packed q|k|v
  float* f_ctx  = (float*)alloc((size_t)CT * CD * 4);
  float* f_x1   = (float*)alloc((size_t)CT * CD * 4);
  float* f_h2   = (float*)alloc((size_t)CT * CD * 4);
  short* f_xg   = (short*)alloc((size_t)MAXROWS * CD * 2);  // gathered bf16
  short* f_hid  = (short*)alloc((size_t)MAXROWS * CF * 2);  // bf16 hid
  float* f_ff   = (float*)alloc((size_t)MAXROWS * CD * 4);
  float* f_topp = (float*)alloc(CT * CK * 4);
  float* f_psum = (float*)alloc(CE * 4);
  int* i_topi   = (int*)alloc(CT * CK * 4);
  int* i_rowof  = (int*)alloc(CT * CK * 4);
  int* i_rowmap = (int*)alloc(MAXROWS * 4);
  int* i_counts = (int*)alloc(CE * 4);
  int* i_cursor = (int*)alloc(CE * 4);
  int* i_offs   = (int*)alloc((CE + 1) * 4);
  int* i_tile   = (int*)alloc(MAXTILES * 4);
  int* i_total  = (int*)alloc(4);
  // R1 (64MB): scores(32MB) -> w1t(64MB) -> w2t(64MB), disjoint lifetimes
  void* R1 = alloc((size_t)CE * CD * CF * 2);
  float* f_scores = (float*)R1;
  short* f_w1t = (short*)R1;
  short* f_w2t = (short*)R1;

  dim3 b256(256);

  zero_kernel<<<1, 64, 0, stream>>>(i_counts, i_cursor, f_psum);

  // ---- attention path: fp32 (router-decision accuracy depends on it) ----
  rmsnorm_kernel<<<CT, b256, 0, stream>>>(x, n1w, f_h);
  gemm_bias_kernel<<<dim3(CD / 64, CT / 64), b256, 0, stream>>>(
      f_h, wq, bq, nullptr, f_qkv + 0, CT, CD, CD, QKVP);
  gemm_bias_kernel<<<dim3(CD / 64, CT / 64), b256, 0, stream>>>(
      f_h, wk, bk, nullptr, f_qkv + 1024, CT, CD, CD, QKVP);
  gemm_bias_kernel<<<dim3(CD / 64, CT / 64), b256, 0, stream>>>(
      f_h, wv, bv, nullptr, f_qkv + 2048, CT, CD, CD, QKVP);
  scores_kernel<<<dim3(CS / 64, CS / 64, CBH), b256, 0, stream>>>(f_qkv, f_scores);
  softmax_kernel<<<CBH * CS, b256, 0, stream>>>(f_scores);
  pv_kernel<<<dim3(CS / 64, CBH), b256, 0, stream>>>(f_scores, f_qkv, f_ctx);
  gemm_bias_kernel<<<dim3(CD / 64, CT / 64), b256, 0, stream>>>(
      f_ctx, wo, bo, x, f_x1, CT, CD, CD, CD);

  // ---- MoE path: routing fp32, expert GEMMs bf16 MFMA ----
  rmsnorm_kernel<<<CT, b256, 0, stream>>>(f_x1, n2w, f_h2);
  router_kernel<<<CT, b256, 0, stream>>>(f_h2, wr, br, i_topi, f_topp, i_counts,
                                         f_psum);
  finalize_kernel<<<1, 256, 0, stream>>>(i_counts, f_psum, i_offs, i_tile,
                                         i_total, i_rowmap, out + (size_t)CT * CD);
  gather_kernel<<<(CT * CK + 255) / 256, b256, 0, stream>>>(i_topi, i_offs,
                                                            i_cursor, i_rowmap,
                                                            i_rowof);
  gatherx_kernel<<<MAXROWS, b256, 0, stream>>>(f_h2, i_rowmap, f_xg);

  // expert GEMM1: hid = silu(Xg @ w1[e] + b1[e])  (bf16 out)
  transpose_convert_kernel<<<dim3(CF / 32, CD / 32, CE), b256, 0, stream>>>(
      w1, f_w1t, CD, CF);
  mfma_gemm_kernel<1, 1><<<dim3(CF / 128, MAXTILES), b256, 0, stream>>>(
      f_xg, f_w1t, b1, f_hid, CF, CD, i_tile, i_total);
  // expert GEMM2: ff = hid @ w2[e] + b2[e]  (fp32 out)
  transpose_convert_kernel<<<dim3(CD / 32, CF / 32, CE), b256, 0, stream>>>(
      w2, f_w2t, CF, CD);
  mfma_gemm_kernel<0, 0><<<dim3(CD / 128, MAXTILES), b256, 0, stream>>>(
      f_hid, f_w2t, b2, f_ff, CD, CF, i_tile, i_total);

  combine_kernel<<<CT, b256, 0, stream>>>(f_x1, f_ff, i_rowof, f_topp, out);
}

// Round 4
// 571.199 us; speedup vs baseline: 2.0050x; 1.3611x over previous
//
#include <hip/hip_runtime.h>
#include <math.h>

// Problem constants
#define CB 2
#define CS 512
#define CD 1024
#define CH 16
#define CHD 64
#define CF 4096
#define CE 8
#define CK 2
#define CT (CB*CS)      // 1024 tokens
#define CBH (CB*CH)     // 32 (batch*heads)
#define CEPS 1e-6f
#define QKVP 3072       // packed q|k|v row pitch
#define MAXROWS 3072    // 2048 + 8*127 padded to 128
#define MAXTILES (MAXROWS/128)

typedef __attribute__((ext_vector_type(8))) short bf16x8;
typedef __attribute__((ext_vector_type(4))) float f32x4;

__device__ __forceinline__ short f2bf(float f) {
  unsigned u = __float_as_uint(f);
  unsigned r = (u + 0x7FFF + ((u >> 16) & 1)) >> 16;
  return (short)r;
}
__device__ __forceinline__ float bf2f(short h) {
  return __uint_as_float(((unsigned)(unsigned short)h) << 16);
}

__device__ __forceinline__ void gload_lds16(const void* g, void* l) {
  __builtin_amdgcn_global_load_lds(
      (const __attribute__((address_space(1))) unsigned int*)g,
      (__attribute__((address_space(3))) unsigned int*)l, 16, 0, 0);
}

// ---------------------------------------------------------------------------
// RMSNorm. MODE 0: fp32 out (outA). MODE 2: hi/lo bf16 planes (outA=hi, outB=lo)
template <int MODE>
__global__ __launch_bounds__(256) void rmsnorm_kernel(
    const float* __restrict__ x, const float* __restrict__ w,
    void* __restrict__ outA, void* __restrict__ outB) {
  int t = blockIdx.x;
  int tid = threadIdx.x;
  float4 xv = ((const float4*)(x + (size_t)t * CD))[tid];
  float ss = xv.x*xv.x + xv.y*xv.y + xv.z*xv.z + xv.w*xv.w;
  for (int off = 32; off > 0; off >>= 1) ss += __shfl_down(ss, off);
  __shared__ float red[4];
  __shared__ float s_scale;
  int lane = tid & 63, wid = tid >> 6;
  if (lane == 0) red[wid] = ss;
  __syncthreads();
  if (tid == 0) {
    float tot = red[0] + red[1] + red[2] + red[3];
    s_scale = rsqrtf(tot / (float)CD + CEPS);
  }
  __syncthreads();
  float sc = s_scale;
  float4 wv = ((const float4*)w)[tid];
  float o[4] = {xv.x * sc * wv.x, xv.y * sc * wv.y,
                xv.z * sc * wv.z, xv.w * sc * wv.w};
  if (MODE == 0) {
    ((float4*)((float*)outA + (size_t)t * CD))[tid] =
        make_float4(o[0], o[1], o[2], o[3]);
  } else {
    short4 hi, lo;
    short* hp = (short*)&hi; short* lp = (short*)&lo;
#pragma unroll
    for (int i = 0; i < 4; ++i) {
      short h = f2bf(o[i]);
      hp[i] = h;
      lp[i] = f2bf(o[i] - bf2f(h));
    }
    ((short4*)((short*)outA + (size_t)t * CD))[tid] = hi;
    ((short4*)((short*)outB + (size_t)t * CD))[tid] = lo;
  }
}

// ---------------------------------------------------------------------------
// Tiled transpose: W[e][Kd][Nd] f32 -> Wth[e][Nd][Kd] bf16 (+ optional lo plane)
__global__ __launch_bounds__(256) void transpose_convert_kernel(
    const float* __restrict__ W, short* __restrict__ Wth,
    short* __restrict__ Wtl, int Kd, int Nd) {
  int e = blockIdx.z;
  const float* Wb = W + (size_t)e * Kd * Nd;
  size_t obase = (size_t)e * Kd * Nd;
  int n0 = blockIdx.x * 32, k0 = blockIdx.y * 32;
  __shared__ float tile[32][33];
  int tx = threadIdx.x & 31, ty = threadIdx.x >> 5;
#pragma unroll
  for (int i = 0; i < 4; ++i)
    tile[ty + i * 8][tx] = Wb[(size_t)(k0 + ty + i * 8) * Nd + n0 + tx];
  __syncthreads();
#pragma unroll
  for (int i = 0; i < 4; ++i) {
    float v = tile[tx][ty + i * 8];
    short hi = f2bf(v);
    size_t oi = obase + (size_t)(n0 + ty + i * 8) * Kd + k0 + tx;
    Wth[oi] = hi;
    if (Wtl) Wtl[oi] = f2bf(v - bf2f(hi));
  }
}

__global__ void pack_bias_kernel(const float* __restrict__ bq,
                                 const float* __restrict__ bk,
                                 const float* __restrict__ bv,
                                 float* __restrict__ out) {
  int i = blockIdx.x * 256 + threadIdx.x;
  if (i < QKVP)
    out[i] = (i < 1024) ? bq[i] : (i < 2048 ? bk[i - 1024] : bv[i - 2048]);
}

// ---------------------------------------------------------------------------
// Unified bf16 MFMA GEMM, 128x128 tile, BK=32, 4 waves (2x2), 4x4 frags/wave.
// LO=1: A/B given as hi+lo bf16 planes; acc += ah*bh + ah*bl + al*bh (~fp32).
// GROUPED=1: expert-grouped B/bias via tile_e (rows 128-padded per expert).
// gridDim.z>1: split-K -> fp32 partials at part[z][partM][N], no epilogue.
__device__ __forceinline__ void stage_tile(const short* __restrict__ gbase,
                                           int ldK, int row0, int k0,
                                           short* lds, int tid) {
  int wbase = tid & 192;  // wave-uniform chunk base
#pragma unroll
  for (int ic = 0; ic < 2; ++ic) {
    int c = ic * 256 + tid;
    int g = c >> 7, r = c & 127;
    const short* gsrc = gbase + (size_t)(row0 + r) * ldK + k0 + g * 8;
    short* ldst = lds + (size_t)(ic * 256 + wbase) * 8;
    gload_lds16(gsrc, ldst);
  }
}

template <int LO, int GROUPED>
__global__ __launch_bounds__(256) void mfma_gemm_kernel(
    const short* __restrict__ Ah, const short* __restrict__ Al,
    const short* __restrict__ Bh, const short* __restrict__ Bl,
    const float* __restrict__ bias, void* __restrict__ Cout,
    float* __restrict__ part, int partM, int N, int K, int silu, int outbf,
    const int* __restrict__ tile_e, const int* __restrict__ total_rows) {
  __shared__ short As[4096];
  __shared__ short Bs[4096];
  __shared__ short Als[LO ? 4096 : 64];
  __shared__ short Bls[LO ? 4096 : 64];
  int tid = threadIdx.x;
  int m0 = blockIdx.y * 128, n0 = blockIdx.x * 128;
  const short* Bhb = Bh;
  const short* Blb = Bl;
  const float* biasb = bias;
  if (GROUPED) {
    if (m0 >= *total_rows) return;
    int e = tile_e[blockIdx.y];
    Bhb = Bh + (size_t)e * N * K;
    biasb = bias + (size_t)e * N;
  }
  int kz = blockIdx.z;
  int kchunk = K / gridDim.z;
  int kbeg = kz * kchunk, kend = kbeg + kchunk;
  int lane = tid & 63, w = tid >> 6;
  int wr = w >> 1, wc = w & 1;
  int l15 = lane & 15, l4 = lane >> 4;
  f32x4 acc[4][4] = {};
  for (int k0 = kbeg; k0 < kend; k0 += 32) {
    stage_tile(Ah, K, m0, k0, As, tid);
    stage_tile(Bhb, K, n0, k0, Bs, tid);
    if (LO) {
      stage_tile(Al, K, m0, k0, Als, tid);
      stage_tile(Blb, K, n0, k0, Bls, tid);
    }
    __syncthreads();
    bf16x8 ah[4], al[4];
#pragma unroll
    for (int m = 0; m < 4; ++m) {
      int idx = (l4 * 128 + wr * 64 + m * 16 + l15) * 8;
      ah[m] = *(const bf16x8*)&As[idx];
      if (LO) al[m] = *(const bf16x8*)&Als[idx];
    }
#pragma unroll
    for (int n = 0; n < 4; ++n) {
      int idx = (l4 * 128 + wc * 64 + n * 16 + l15) * 8;
      bf16x8 bhn = *(const bf16x8*)&Bs[idx];
      bf16x8 bln;
      if (LO) bln = *(const bf16x8*)&Bls[idx];
#pragma unroll
      for (int m = 0; m < 4; ++m) {
        acc[m][n] =
            __builtin_amdgcn_mfma_f32_16x16x32_bf16(ah[m], bhn, acc[m][n], 0, 0, 0);
        if (LO) {
          acc[m][n] = __builtin_amdgcn_mfma_f32_16x16x32_bf16(al[m], bhn,
                                                              acc[m][n], 0, 0, 0);
          acc[m][n] = __builtin_amdgcn_mfma_f32_16x16x32_bf16(ah[m], bln,
                                                              acc[m][n], 0, 0, 0);
        }
      }
    }
    __syncthreads();
  }
  if (gridDim.z > 1) {
    // split-K: write fp32 partials (bias applied in reduce)
#pragma unroll
    for (int m = 0; m < 4; ++m) {
      int row = m0 + wr * 64 + m * 16 + l4 * 4;
#pragma unroll
      for (int n = 0; n < 4; ++n) {
        int col = n0 + wc * 64 + n * 16 + l15;
#pragma unroll
        for (int q = 0; q < 4; ++q)
          part[((size_t)kz * partM + row + q) * N + col] = acc[m][n][q];
      }
    }
    return;
  }
  float* outf = (float*)Cout;
  short* outb = (short*)Cout;
#pragma unroll
  for (int m = 0; m < 4; ++m) {
    int row = m0 + wr * 64 + m * 16 + l4 * 4;
#pragma unroll
    for (int n = 0; n < 4; ++n) {
      int col = n0 + wc * 64 + n * 16 + l15;
      float bv = biasb[col];
#pragma unroll
      for (int q = 0; q < 4; ++q) {
        float v = acc[m][n][q] + bv;
        if (silu) v = v / (1.f + __expf(-v));
        if (outbf) outb[(size_t)(row + q) * N + col] = f2bf(v);
        else outf[(size_t)(row + q) * N + col] = v;
      }
    }
  }
}

// split-K reduce: out[row][c] = sum_z part[z][row][c] + bias (+res). fp32 out.
__global__ __launch_bounds__(256) void reduce_splitk_kernel(
    const float* __restrict__ part, int partM, int nz,
    const float* __restrict__ bias, const int* __restrict__ tile_e,
    const float* __restrict__ res, float* __restrict__ outp, int N,
    const int* __restrict__ total_rows) {
  int row = blockIdx.x;
  if (total_rows && row >= *total_rows) return;
  const float* bb = bias;
  if (tile_e) bb = bias + (size_t)tile_e[row >> 7] * N;
  for (int c = threadIdx.x * 4; c < N; c += 1024) {
    float4 s = *(const float4*)(part + (size_t)row * N + c);
    for (int z = 1; z < nz; ++z) {
      float4 p = *(const float4*)(part + ((size_t)z * partM + row) * N + c);
      s.x += p.x; s.y += p.y; s.z += p.z; s.w += p.w;
    }
    s.x += bb[c]; s.y += bb[c + 1]; s.z += bb[c + 2]; s.w += bb[c + 3];
    if (res) {
      float4 r = *(const float4*)(res + (size_t)row * N + c);
      s.x += r.x; s.y += r.y; s.z += r.z; s.w += r.w;
    }
    *(float4*)(outp + (size_t)row * N + c) = s;
  }
}

// ---------------------------------------------------------------------------
// Attention scores: S_tile[64q][64k] = Q Kt / 8 per (b,h); packed qkv input.
__global__ __launch_bounds__(256) void scores_kernel(
    const float* __restrict__ qkv, float* __restrict__ scores) {
  int kt = blockIdx.x, qt = blockIdx.y, bh = blockIdx.z;
  if (kt > qt) return;
  int b = bh / CH, h = bh % CH;
  __shared__ float Qs[64][68];
  __shared__ float Ks[64][68];
  int tid = threadIdx.x;
#pragma unroll
  for (int i = 0; i < 4; ++i) {
    int row = (tid >> 4) + i * 16;
    int col = (tid & 15) * 4;
    *(float4*)&Qs[row][col] =
        *(const float4*)(qkv + (size_t)(b * CS + qt * 64 + row) * QKVP + h * CHD + col);
    *(float4*)&Ks[row][col] =
        *(const float4*)(qkv + (size_t)(b * CS + kt * 64 + row) * QKVP + 1024 + h * CHD + col);
  }
  __syncthreads();
  int tx = tid & 15, ty = tid >> 4;
  float acc[4][4] = {};
#pragma unroll 16
  for (int d = 0; d < 64; ++d) {
    float ra[4], rb[4];
#pragma unroll
    for (int i = 0; i < 4; ++i) ra[i] = Qs[ty * 4 + i][d];
#pragma unroll
    for (int j = 0; j < 4; ++j) rb[j] = Ks[tx * 4 + j][d];
#pragma unroll
    for (int i = 0; i < 4; ++i)
#pragma unroll
      for (int j = 0; j < 4; ++j) acc[i][j] += ra[i] * rb[j];
  }
  size_t base = (size_t)bh * CS * CS;
#pragma unroll
  for (int i = 0; i < 4; ++i) {
    int r = qt * 64 + ty * 4 + i;
#pragma unroll
    for (int j = 0; j < 4; ++j) {
      int c = kt * 64 + tx * 4 + j;
      scores[base + (size_t)r * CS + c] = acc[i][j] * 0.125f;
    }
  }
}

// Causal row softmax in-place: row r uses cols 0..r, writes 0 for c>r.
__global__ __launch_bounds__(256) void softmax_kernel(float* __restrict__ scores) {
  int row = blockIdx.x;
  int bh = row / CS, r = row % CS;
  float* p = scores + (size_t)bh * CS * CS + (size_t)r * CS;
  int n = r + 1;
  int tid = threadIdx.x;
  __shared__ float buf[CS];
  __shared__ float redm[4], reds[4], sbc[2];
  float m = -1e30f;
  for (int c = tid; c < n; c += 256) {
    float v = p[c];
    buf[c] = v;
    m = fmaxf(m, v);
  }
  for (int off = 32; off > 0; off >>= 1) m = fmaxf(m, __shfl_down(m, off));
  int lane = tid & 63, wid = tid >> 6;
  if (lane == 0) redm[wid] = m;
  __syncthreads();
  if (tid == 0) sbc[0] = fmaxf(fmaxf(redm[0], redm[1]), fmaxf(redm[2], redm[3]));
  __syncthreads();
  float mmax = sbc[0];
  float s = 0.f;
  for (int c = tid; c < n; c += 256) {
    float e = __expf(buf[c] - mmax);
    buf[c] = e;
    s += e;
  }
  for (int off = 32; off > 0; off >>= 1) s += __shfl_down(s, off);
  if (lane == 0) reds[wid] = s;
  __syncthreads();
  if (tid == 0) sbc[1] = reds[0] + reds[1] + reds[2] + reds[3];
  __syncthreads();
  float inv = 1.0f / sbc[1];
  for (int c = tid; c < CS; c += 256) p[c] = (c < n) ? buf[c] * inv : 0.f;
}

// ctx hi/lo planes = P[64q][S] @ V[S][64d] per (qt, bh); kt<=qt only.
__global__ __launch_bounds__(256) void pv_kernel(
    const float* __restrict__ scores, const float* __restrict__ qkv,
    short* __restrict__ ctxh, short* __restrict__ ctxl) {
  int qt = blockIdx.x, bh = blockIdx.y;
  int b = bh / CH, h = bh % CH;
  __shared__ float Ps[64][68];
  __shared__ float Vs[64][68];
  int tid = threadIdx.x;
  int tx = tid & 15, ty = tid >> 4;
  float acc[4][4] = {};
  size_t base = (size_t)bh * CS * CS;
  for (int kt = 0; kt <= qt; ++kt) {
#pragma unroll
    for (int i = 0; i < 4; ++i) {
      int row = (tid >> 4) + i * 16;
      int col = (tid & 15) * 4;
      *(float4*)&Ps[row][col] =
          *(const float4*)(scores + base + (size_t)(qt * 64 + row) * CS + kt * 64 + col);
      *(float4*)&Vs[row][col] =
          *(const float4*)(qkv + (size_t)(b * CS + kt * 64 + row) * QKVP + 2048 + h * CHD + col);
    }
    __syncthreads();
#pragma unroll 16
    for (int kk = 0; kk < 64; ++kk) {
      float ra[4];
#pragma unroll
      for (int i = 0; i < 4; ++i) ra[i] = Ps[ty * 4 + i][kk];
      float4 rb4 = *(const float4*)&Vs[kk][tx * 4];
      float rb[4] = {rb4.x, rb4.y, rb4.z, rb4.w};
#pragma unroll
      for (int i = 0; i < 4; ++i)
#pragma unroll
        for (int j = 0; j < 4; ++j) acc[i][j] += ra[i] * rb[j];
    }
    __syncthreads();
  }
#pragma unroll
  for (int i = 0; i < 4; ++i)
#pragma unroll
    for (int j = 0; j < 4; ++j) {
      size_t oi =
          (size_t)(b * CS + qt * 64 + ty * 4 + i) * CD + h * CHD + tx * 4 + j;
      float v = acc[i][j];
      short hi = f2bf(v);
      ctxh[oi] = hi;
      ctxl[oi] = f2bf(v - bf2f(hi));
    }
}

// ---------------------------------------------------------------------------
__global__ void zero_kernel(int* counts, int* cursor, float* psum) {
  int i = threadIdx.x;
  if (i < CE) { counts[i] = 0; cursor[i] = 0; psum[i] = 0.f; }
}

__global__ __launch_bounds__(256) void router_kernel(
    const float* __restrict__ h2, const float* __restrict__ wr,
    const float* __restrict__ br, int* __restrict__ top_i,
    float* __restrict__ top_p, int* __restrict__ counts,
    float* __restrict__ psum) {
  int t = blockIdx.x;
  int tid = threadIdx.x;
  float a[CE] = {};
  float4 hv = ((const float4*)(h2 + (size_t)t * CD))[tid];
  const float* wrow = wr + (size_t)tid * 4 * CE;
  float hvv[4] = {hv.x, hv.y, hv.z, hv.w};
#pragma unroll
  for (int i = 0; i < 4; ++i)
#pragma unroll
    for (int e = 0; e < CE; ++e) a[e] += hvv[i] * wrow[i * CE + e];
  __shared__ float red[256][CE];
#pragma unroll
  for (int e = 0; e < CE; ++e) red[tid][e] = a[e];
  __syncthreads();
  for (int s = 128; s > 0; s >>= 1) {
    if (tid < s) {
#pragma unroll
      for (int e = 0; e < CE; ++e) red[tid][e] += red[tid + s][e];
    }
    __syncthreads();
  }
  if (tid == 0) {
    float logits[CE], probs[CE];
    float mx = -1e30f;
#pragma unroll
    for (int e = 0; e < CE; ++e) {
      logits[e] = red[0][e] + br[e];
      mx = fmaxf(mx, logits[e]);
    }
    float sum = 0.f;
#pragma unroll
    for (int e = 0; e < CE; ++e) { probs[e] = __expf(logits[e] - mx); sum += probs[e]; }
    float inv = 1.0f / sum;
#pragma unroll
    for (int e = 0; e < CE; ++e) probs[e] *= inv;
    int i1 = 0;
#pragma unroll
    for (int e = 1; e < CE; ++e) if (probs[e] > probs[i1]) i1 = e;
    int i2 = (i1 == 0) ? 1 : 0;
#pragma unroll
    for (int e = 0; e < CE; ++e)
      if (e != i1 && probs[e] > probs[i2]) i2 = e;
    float p1 = probs[i1], p2 = probs[i2];
    float s12 = p1 + p2;
    top_i[t * 2 + 0] = i1;
    top_i[t * 2 + 1] = i2;
    top_p[t * 2 + 0] = p1 / s12;
    top_p[t * 2 + 1] = p2 / s12;
    atomicAdd(&counts[i1], 1);
    atomicAdd(&counts[i2], 1);
#pragma unroll
    for (int e = 0; e < CE; ++e) atomicAdd(&psum[e], probs[e]);
  }
}

// Finalize: 128-aligned per-expert offsets, tile->expert map, aux loss.
__global__ void finalize_kernel(const int* __restrict__ counts,
                                const float* __restrict__ psum,
                                int* __restrict__ offs, int* __restrict__ tile_e,
                                int* __restrict__ total_padded,
                                int* __restrict__ row_map,
                                float* __restrict__ aux_out) {
  int tid = threadIdx.x;
  __shared__ int s_off[CE + 1];
  if (tid == 0) {
    int o = 0;
    for (int e = 0; e < CE; ++e) {
      s_off[e] = o;
      offs[e] = o;
      o += ((counts[e] + 127) >> 7) << 7;
    }
    s_off[CE] = o;
    offs[CE] = o;
    *total_padded = o;
    int nt = o >> 7;
    for (int i = 0; i < nt; ++i) {
      int e = 0;
      while (e < CE - 1 && i * 128 >= s_off[e + 1]) e++;
      tile_e[i] = e;
    }
    float aux = 0.f;
    for (int e = 0; e < CE; ++e)
      aux += ((float)counts[e] / (float)(CT * CK)) * (psum[e] / (float)CT);
    aux_out[0] = aux * (float)CE;
  }
  __syncthreads();
  for (int i = tid; i < MAXROWS; i += blockDim.x) row_map[i] = -1;
}

__global__ void gather_kernel(const int* __restrict__ top_i,
                              const int* __restrict__ offs,
                              int* __restrict__ cursor, int* __restrict__ row_map,
                              int* __restrict__ row_of) {
  int idx = blockIdx.x * blockDim.x + threadIdx.x;
  if (idx >= CT * CK) return;
  int e = top_i[idx];
  int pos = offs[e] + atomicAdd(&cursor[e], 1);
  row_map[pos] = idx >> 1;
  row_of[idx] = pos;
}

// Xg[row] = bf16(h2[row_map[row]]) or zeros for pad rows.
__global__ __launch_bounds__(256) void gatherx_kernel(
    const float* __restrict__ h2, const int* __restrict__ row_map,
    short* __restrict__ Xg) {
  int row = blockIdx.x;
  int tid = threadIdx.x;
  int tok = row_map[row];
  short4 o;
  if (tok < 0) {
    o = make_short4(0, 0, 0, 0);
  } else {
    float4 v = ((const float4*)(h2 + (size_t)tok * CD))[tid];
    o = make_short4(f2bf(v.x), f2bf(v.y), f2bf(v.z), f2bf(v.w));
  }
  ((short4*)(Xg + (size_t)row * CD))[tid] = o;
}

// out[t] = x1[t] + sum_k top_p[t,k] * ff_rows[row_of[t,k]]
__global__ __launch_bounds__(256) void combine_kernel(
    const float* __restrict__ x1, const float* __restrict__ ff_rows,
    const int* __restrict__ row_of, const float* __restrict__ top_p,
    float* __restrict__ out) {
  int t = blockIdx.x;
  int tid = threadIdx.x;
  float4 r = ((const float4*)(x1 + (size_t)t * CD))[tid];
#pragma unroll
  for (int s = 0; s < CK; ++s) {
    float w = top_p[t * 2 + s];
    int row = row_of[t * 2 + s];
    float4 f = ((const float4*)(ff_rows + (size_t)row * CD))[tid];
    r.x += w * f.x; r.y += w * f.y; r.z += w * f.z; r.w += w * f.w;
  }
  ((float4*)(out + (size_t)t * CD))[tid] = r;
}

// ---------------------------------------------------------------------------
extern "C" void kernel_launch(void* const* d_in, const int* in_sizes, int n_in,
                              void* d_out, int out_size, void* d_ws,
                              size_t ws_size, hipStream_t stream) {
  const float* x   = (const float*)d_in[0];
  const float* n1w = (const float*)d_in[1];
  const float* n2w = (const float*)d_in[2];
  const float* wq  = (const float*)d_in[3];
  const float* bq  = (const float*)d_in[4];
  const float* wk  = (const float*)d_in[5];
  const float* bk  = (const float*)d_in[6];
  const float* wv  = (const float*)d_in[7];
  const float* bv  = (const float*)d_in[8];
  const float* wo  = (const float*)d_in[9];
  const float* bo  = (const float*)d_in[10];
  const float* wr  = (const float*)d_in[11];
  const float* br  = (const float*)d_in[12];
  const float* w1  = (const float*)d_in[13];
  const float* b1  = (const float*)d_in[14];
  const float* w2  = (const float*)d_in[15];
  const float* b2  = (const float*)d_in[16];
  float* out = (float*)d_out;

  char* base = (char*)d_ws;
  size_t off = 0;
  auto alloc = [&](size_t bytes) -> void* {
    void* p = base + off;
    off += (bytes + 255) & ~(size_t)255;
    return p;
  };
  float* f_x1   = (float*)alloc((size_t)CT * CD * 4);
  float* f_h2   = (float*)alloc((size_t)CT * CD * 4);
  short* f_xg   = (short*)alloc((size_t)MAXROWS * CD * 2);
  short* f_hid  = (short*)alloc((size_t)MAXROWS * CF * 2);
  float* f_ff   = (float*)alloc((size_t)MAXROWS * CD * 4);
  // attention-phase buffers (hi/lo planes)
  short* f_hh   = (short*)alloc((size_t)CT * CD * 2);
  short* f_hl   = (short*)alloc((size_t)CT * CD * 2);
  short* f_wqkvh = (short*)alloc((size_t)QKVP * CD * 2);
  short* f_wqkvl = (short*)alloc((size_t)QKVP * CD * 2);
  float* f_qkv  = (float*)alloc((size_t)CT * QKVP * 4);
  short* f_ctxh = (short*)alloc((size_t)CT * CD * 2);
  short* f_ctxl = (short*)alloc((size_t)CT * CD * 2);
  short* f_woth = (short*)alloc((size_t)CD * CD * 2);
  short* f_wotl = (short*)alloc((size_t)CD * CD * 2);
  float* f_bqkv = (float*)alloc(QKVP * 4);
  float* f_topp = (float*)alloc(CT * CK * 4);
  float* f_psum = (float*)alloc(CE * 4);
  int* i_topi   = (int*)alloc(CT * CK * 4);
  int* i_rowof  = (int*)alloc(CT * CK * 4);
  int* i_rowmap = (int*)alloc(MAXROWS * 4);
  int* i_counts = (int*)alloc(CE * 4);
  int* i_cursor = (int*)alloc(CE * 4);
  int* i_offs   = (int*)alloc((CE + 1) * 4);
  int* i_tile   = (int*)alloc(MAXTILES * 4);
  int* i_total  = (int*)alloc(4);
  // G (64MB): w1t -> w2t (sequential reuse)
  short* f_wG = (short*)alloc((size_t)CE * CD * CF * 2);
  short* f_w1t = f_wG;
  short* f_w2t = f_wG;
  // Rs (32MB): scores -> WO partials (4x1024x1024 f32) -> GEMM2 partials (2x3072x1024 f32)
  void* Rs = alloc((size_t)CBH * CS * CS * 4);
  float* f_scores = (float*)Rs;
  float* f_partwo = (float*)Rs;
  float* f_partg2 = (float*)Rs;

  dim3 b256(256);

  zero_kernel<<<1, 64, 0, stream>>>(i_counts, i_cursor, f_psum);
  pack_bias_kernel<<<QKVP / 256, b256, 0, stream>>>(bq, bk, bv, f_bqkv);
  // weight preprocessing (hi/lo planes for attention, hi-only for experts' w1)
  transpose_convert_kernel<<<dim3(32, 32, 1), b256, 0, stream>>>(
      wq, f_wqkvh + 0 * (size_t)CD * CD, f_wqkvl + 0 * (size_t)CD * CD, CD, CD);
  transpose_convert_kernel<<<dim3(32, 32, 1), b256, 0, stream>>>(
      wk, f_wqkvh + 1 * (size_t)CD * CD, f_wqkvl + 1 * (size_t)CD * CD, CD, CD);
  transpose_convert_kernel<<<dim3(32, 32, 1), b256, 0, stream>>>(
      wv, f_wqkvh + 2 * (size_t)CD * CD, f_wqkvl + 2 * (size_t)CD * CD, CD, CD);
  transpose_convert_kernel<<<dim3(32, 32, 1), b256, 0, stream>>>(
      wo, f_woth, f_wotl, CD, CD);
  transpose_convert_kernel<<<dim3(CF / 32, CD / 32, CE), b256, 0, stream>>>(
      w1, f_w1t, nullptr, CD, CF);

  // ---- attention (hi/lo MFMA projections; fp32 scores/softmax/pv) ----
  rmsnorm_kernel<2><<<CT, b256, 0, stream>>>(x, n1w, f_hh, f_hl);
  // fused QKV: [1024,1024] @ [1024,3072] -> f_qkv fp32
  mfma_gemm_kernel<1, 0><<<dim3(QKVP / 128, CT / 128, 1), b256, 0, stream>>>(
      f_hh, f_hl, f_wqkvh, f_wqkvl, f_bqkv, f_qkv, nullptr, 0, QKVP, CD, 0, 0,
      nullptr, nullptr);
  scores_kernel<<<dim3(CS / 64, CS / 64, CBH), b256, 0, stream>>>(f_qkv, f_scores);
  softmax_kernel<<<CBH * CS, b256, 0, stream>>>(f_scores);
  pv_kernel<<<dim3(CS / 64, CBH), b256, 0, stream>>>(f_scores, f_qkv, f_ctxh,
                                                     f_ctxl);
  // WO: split-K=4 partials (scores now dead), reduce adds bo + residual x
  mfma_gemm_kernel<1, 0><<<dim3(CD / 128, CT / 128, 4), b256, 0, stream>>>(
      f_ctxh, f_ctxl, f_woth, f_wotl, nullptr, nullptr, f_partwo, CT, CD, CD,
      0, 0, nullptr, nullptr);
  reduce_splitk_kernel<<<CT, b256, 0, stream>>>(f_partwo, CT, 4, bo, nullptr, x,
                                                f_x1, CD, nullptr);

  // ---- MoE ----
  rmsnorm_kernel<0><<<CT, b256, 0, stream>>>(f_x1, n2w, f_h2, nullptr);
  router_kernel<<<CT, b256, 0, stream>>>(f_h2, wr, br, i_topi, f_topp, i_counts,
                                         f_psum);
  finalize_kernel<<<1, 256, 0, stream>>>(i_counts, f_psum, i_offs, i_tile,
                                         i_total, i_rowmap, out + (size_t)CT * CD);
  gather_kernel<<<(CT * CK + 255) / 256, b256, 0, stream>>>(i_topi, i_offs,
                                                            i_cursor, i_rowmap,
                                                            i_rowof);
  gatherx_kernel<<<MAXROWS, b256, 0, stream>>>(f_h2, i_rowmap, f_xg);

  // expert GEMM1: hid = silu(Xg @ w1[e] + b1[e])  (bf16 out, no split)
  mfma_gemm_kernel<0, 1><<<dim3(CF / 128, MAXTILES, 1), b256, 0, stream>>>(
      f_xg, nullptr, f_w1t, nullptr, b1, f_hid, nullptr, 0, CF, CD, 1, 1,
      i_tile, i_total);
  // expert GEMM2: split-K=2 partials, reduce adds b2[e]
  transpose_convert_kernel<<<dim3(CD / 32, CF / 32, CE), b256, 0, stream>>>(
      w2, f_w2t, nullptr, CF, CD);
  mfma_gemm_kernel<0, 1><<<dim3(CD / 128, MAXTILES, 2), b256, 0, stream>>>(
      f_hid, nullptr, f_w2t, nullptr, nullptr, nullptr, f_partg2, MAXROWS, CD,
      CF, 0, 0, i_tile, i_total);
  reduce_splitk_kernel<<<MAXROWS, b256, 0, stream>>>(f_partg2, MAXROWS, 2, b2,
                                                     i_tile, nullptr, f_ff, CD,
                                                     i_total);

  combine_kernel<<<CT, b256, 0, stream>>>(f_x1, f_ff, i_rowof, f_topp, out);
}

// Round 5
// 467.272 us; speedup vs baseline: 2.4509x; 1.2224x over previous
//
#include <hip/hip_runtime.h>
#include <math.h>

// Problem constants
#define CB 2
#define CS 512
#define CD 1024
#define CH 16
#define CHD 64
#define CF 4096
#define CE 8
#define CK 2
#define CT (CB*CS)      // 1024 tokens
#define CBH (CB*CH)     // 32 (batch*heads)
#define CEPS 1e-6f
#define QKVP 3072       // packed q|k|v row pitch
#define MAXROWS 3072    // 2048 + 8*127 padded to 128
#define MAXTILES (MAXROWS/128)

typedef __attribute__((ext_vector_type(8))) short bf16x8;
typedef __attribute__((ext_vector_type(4))) float f32x4;

__device__ __forceinline__ short f2bf(float f) {
  unsigned u = __float_as_uint(f);
  unsigned r = (u + 0x7FFF + ((u >> 16) & 1)) >> 16;
  return (short)r;
}
__device__ __forceinline__ float bf2f(short h) {
  return __uint_as_float(((unsigned)(unsigned short)h) << 16);
}

__device__ __forceinline__ void gload_lds16(const void* g, void* l) {
  __builtin_amdgcn_global_load_lds(
      (const __attribute__((address_space(1))) unsigned int*)g,
      (__attribute__((address_space(3))) unsigned int*)l, 16, 0, 0);
}

// ---------------------------------------------------------------------------
// RMSNorm. MODE 0: fp32 out (outA). MODE 2: hi/lo bf16 planes (outA=hi, outB=lo)
template <int MODE>
__global__ __launch_bounds__(256) void rmsnorm_kernel(
    const float* __restrict__ x, const float* __restrict__ w,
    void* __restrict__ outA, void* __restrict__ outB) {
  int t = blockIdx.x;
  int tid = threadIdx.x;
  float4 xv = ((const float4*)(x + (size_t)t * CD))[tid];
  float ss = xv.x*xv.x + xv.y*xv.y + xv.z*xv.z + xv.w*xv.w;
  for (int off = 32; off > 0; off >>= 1) ss += __shfl_down(ss, off);
  __shared__ float red[4];
  __shared__ float s_scale;
  int lane = tid & 63, wid = tid >> 6;
  if (lane == 0) red[wid] = ss;
  __syncthreads();
  if (tid == 0) {
    float tot = red[0] + red[1] + red[2] + red[3];
    s_scale = rsqrtf(tot / (float)CD + CEPS);
  }
  __syncthreads();
  float sc = s_scale;
  float4 wv = ((const float4*)w)[tid];
  float o[4] = {xv.x * sc * wv.x, xv.y * sc * wv.y,
                xv.z * sc * wv.z, xv.w * sc * wv.w};
  if (MODE == 0) {
    ((float4*)((float*)outA + (size_t)t * CD))[tid] =
        make_float4(o[0], o[1], o[2], o[3]);
  } else {
    short4 hi, lo;
    short* hp = (short*)&hi; short* lp = (short*)&lo;
#pragma unroll
    for (int i = 0; i < 4; ++i) {
      short h = f2bf(o[i]);
      hp[i] = h;
      lp[i] = f2bf(o[i] - bf2f(h));
    }
    ((short4*)((short*)outA + (size_t)t * CD))[tid] = hi;
    ((short4*)((short*)outB + (size_t)t * CD))[tid] = lo;
  }
}

// ---------------------------------------------------------------------------
// Tiled transpose: W[e][Kd][Nd] f32 -> Wth[e][Nd][Kd] bf16 (+ optional lo plane)
__global__ __launch_bounds__(256) void transpose_convert_kernel(
    const float* __restrict__ W, short* __restrict__ Wth,
    short* __restrict__ Wtl, int Kd, int Nd) {
  int e = blockIdx.z;
  const float* Wb = W + (size_t)e * Kd * Nd;
  size_t obase = (size_t)e * Kd * Nd;
  int n0 = blockIdx.x * 32, k0 = blockIdx.y * 32;
  __shared__ float tile[32][33];
  int tx = threadIdx.x & 31, ty = threadIdx.x >> 5;
#pragma unroll
  for (int i = 0; i < 4; ++i)
    tile[ty + i * 8][tx] = Wb[(size_t)(k0 + ty + i * 8) * Nd + n0 + tx];
  __syncthreads();
#pragma unroll
  for (int i = 0; i < 4; ++i) {
    float v = tile[tx][ty + i * 8];
    short hi = f2bf(v);
    size_t oi = obase + (size_t)(n0 + ty + i * 8) * Kd + k0 + tx;
    Wth[oi] = hi;
    if (Wtl) Wtl[oi] = f2bf(v - bf2f(hi));
  }
}

__global__ void pack_bias_kernel(const float* __restrict__ bq,
                                 const float* __restrict__ bk,
                                 const float* __restrict__ bv,
                                 float* __restrict__ out) {
  int i = blockIdx.x * 256 + threadIdx.x;
  if (i < QKVP)
    out[i] = (i < 1024) ? bq[i] : (i < 2048 ? bk[i - 1024] : bv[i - 2048]);
}

// ---------------------------------------------------------------------------
// Unified bf16 MFMA GEMM, 128x128 tile, BK=32, 4 waves (2x2), 4x4 frags/wave.
// LO=1: A/B given as hi+lo bf16 planes; acc += ah*bh + ah*bl + al*bh (~fp32).
// GROUPED=1: expert-grouped B/bias via tile_e (rows 128-padded per expert).
// gridDim.z>1: split-K -> fp32 partials at part[z][partM][N], no epilogue.
__device__ __forceinline__ void stage_tile(const short* __restrict__ gbase,
                                           int ldK, int row0, int k0,
                                           short* lds, int tid) {
  int wbase = tid & 192;  // wave-uniform chunk base
#pragma unroll
  for (int ic = 0; ic < 2; ++ic) {
    int c = ic * 256 + tid;
    int g = c >> 7, r = c & 127;
    const short* gsrc = gbase + (size_t)(row0 + r) * ldK + k0 + g * 8;
    short* ldst = lds + (size_t)(ic * 256 + wbase) * 8;
    gload_lds16(gsrc, ldst);
  }
}

template <int LO, int GROUPED>
__global__ __launch_bounds__(256) void mfma_gemm_kernel(
    const short* __restrict__ Ah, const short* __restrict__ Al,
    const short* __restrict__ Bh, const short* __restrict__ Bl,
    const float* __restrict__ bias, void* __restrict__ Cout,
    float* __restrict__ part, int partM, int N, int K, int silu, int outbf,
    const int* __restrict__ tile_e, const int* __restrict__ total_rows) {
  __shared__ short As[4096];
  __shared__ short Bs[4096];
  __shared__ short Als[LO ? 4096 : 64];
  __shared__ short Bls[LO ? 4096 : 64];
  int tid = threadIdx.x;
  int m0 = blockIdx.y * 128, n0 = blockIdx.x * 128;
  const short* Bhb = Bh;
  const short* Blb = Bl;
  const float* biasb = bias;
  if (GROUPED) {
    if (m0 >= *total_rows) return;
    int e = tile_e[blockIdx.y];
    Bhb = Bh + (size_t)e * N * K;
    biasb = bias + (size_t)e * N;
  }
  int kz = blockIdx.z;
  int kchunk = K / gridDim.z;
  int kbeg = kz * kchunk, kend = kbeg + kchunk;
  int lane = tid & 63, w = tid >> 6;
  int wr = w >> 1, wc = w & 1;
  int l15 = lane & 15, l4 = lane >> 4;
  f32x4 acc[4][4] = {};
  for (int k0 = kbeg; k0 < kend; k0 += 32) {
    stage_tile(Ah, K, m0, k0, As, tid);
    stage_tile(Bhb, K, n0, k0, Bs, tid);
    if (LO) {
      stage_tile(Al, K, m0, k0, Als, tid);
      stage_tile(Blb, K, n0, k0, Bls, tid);
    }
    __syncthreads();
    bf16x8 ah[4], al[4];
#pragma unroll
    for (int m = 0; m < 4; ++m) {
      int idx = (l4 * 128 + wr * 64 + m * 16 + l15) * 8;
      ah[m] = *(const bf16x8*)&As[idx];
      if (LO) al[m] = *(const bf16x8*)&Als[idx];
    }
#pragma unroll
    for (int n = 0; n < 4; ++n) {
      int idx = (l4 * 128 + wc * 64 + n * 16 + l15) * 8;
      bf16x8 bhn = *(const bf16x8*)&Bs[idx];
      bf16x8 bln;
      if (LO) bln = *(const bf16x8*)&Bls[idx];
#pragma unroll
      for (int m = 0; m < 4; ++m) {
        acc[m][n] =
            __builtin_amdgcn_mfma_f32_16x16x32_bf16(ah[m], bhn, acc[m][n], 0, 0, 0);
        if (LO) {
          acc[m][n] = __builtin_amdgcn_mfma_f32_16x16x32_bf16(al[m], bhn,
                                                              acc[m][n], 0, 0, 0);
          acc[m][n] = __builtin_amdgcn_mfma_f32_16x16x32_bf16(ah[m], bln,
                                                              acc[m][n], 0, 0, 0);
        }
      }
    }
    __syncthreads();
  }
  if (gridDim.z > 1) {
    // split-K: write fp32 partials (bias applied in reduce)
#pragma unroll
    for (int m = 0; m < 4; ++m) {
      int row = m0 + wr * 64 + m * 16 + l4 * 4;
#pragma unroll
      for (int n = 0; n < 4; ++n) {
        int col = n0 + wc * 64 + n * 16 + l15;
#pragma unroll
        for (int q = 0; q < 4; ++q)
          part[((size_t)kz * partM + row + q) * N + col] = acc[m][n][q];
      }
    }
    return;
  }
  float* outf = (float*)Cout;
  short* outb = (short*)Cout;
#pragma unroll
  for (int m = 0; m < 4; ++m) {
    int row = m0 + wr * 64 + m * 16 + l4 * 4;
#pragma unroll
    for (int n = 0; n < 4; ++n) {
      int col = n0 + wc * 64 + n * 16 + l15;
      float bv = biasb[col];
#pragma unroll
      for (int q = 0; q < 4; ++q) {
        float v = acc[m][n][q] + bv;
        if (silu) v = v / (1.f + __expf(-v));
        if (outbf) outb[(size_t)(row + q) * N + col] = f2bf(v);
        else outf[(size_t)(row + q) * N + col] = v;
      }
    }
  }
}

// split-K reduce: out[row][c] = sum_z part[z][row][c] + bias (+res). fp32 out.
__global__ __launch_bounds__(256) void reduce_splitk_kernel(
    const float* __restrict__ part, int partM, int nz,
    const float* __restrict__ bias, const int* __restrict__ tile_e,
    const float* __restrict__ res, float* __restrict__ outp, int N,
    const int* __restrict__ total_rows) {
  int row = blockIdx.x;
  if (total_rows && row >= *total_rows) return;
  const float* bb = bias;
  if (tile_e) bb = bias + (size_t)tile_e[row >> 7] * N;
  for (int c = threadIdx.x * 4; c < N; c += 1024) {
    float4 s = *(const float4*)(part + (size_t)row * N + c);
    for (int z = 1; z < nz; ++z) {
      float4 p = *(const float4*)(part + ((size_t)z * partM + row) * N + c);
      s.x += p.x; s.y += p.y; s.z += p.z; s.w += p.w;
    }
    s.x += bb[c]; s.y += bb[c + 1]; s.z += bb[c + 2]; s.w += bb[c + 3];
    if (res) {
      float4 r = *(const float4*)(res + (size_t)row * N + c);
      s.x += r.x; s.y += r.y; s.z += r.z; s.w += r.w;
    }
    *(float4*)(outp + (size_t)row * N + c) = s;
  }
}

// ---------------------------------------------------------------------------
// Attention scores: S_tile[64q][64k] = Q Kt / 8 per (b,h); packed qkv input.
__global__ __launch_bounds__(256) void scores_kernel(
    const float* __restrict__ qkv, float* __restrict__ scores) {
  int kt = blockIdx.x, qt = blockIdx.y, bh = blockIdx.z;
  if (kt > qt) return;
  int b = bh / CH, h = bh % CH;
  __shared__ float Qs[64][68];
  __shared__ float Ks[64][68];
  int tid = threadIdx.x;
#pragma unroll
  for (int i = 0; i < 4; ++i) {
    int row = (tid >> 4) + i * 16;
    int col = (tid & 15) * 4;
    *(float4*)&Qs[row][col] =
        *(const float4*)(qkv + (size_t)(b * CS + qt * 64 + row) * QKVP + h * CHD + col);
    *(float4*)&Ks[row][col] =
        *(const float4*)(qkv + (size_t)(b * CS + kt * 64 + row) * QKVP + 1024 + h * CHD + col);
  }
  __syncthreads();
  int tx = tid & 15, ty = tid >> 4;
  float acc[4][4] = {};
#pragma unroll 16
  for (int d = 0; d < 64; ++d) {
    float ra[4], rb[4];
#pragma unroll
    for (int i = 0; i < 4; ++i) ra[i] = Qs[ty * 4 + i][d];
#pragma unroll
    for (int j = 0; j < 4; ++j) rb[j] = Ks[tx * 4 + j][d];
#pragma unroll
    for (int i = 0; i < 4; ++i)
#pragma unroll
      for (int j = 0; j < 4; ++j) acc[i][j] += ra[i] * rb[j];
  }
  size_t base = (size_t)bh * CS * CS;
#pragma unroll
  for (int i = 0; i < 4; ++i) {
    int r = qt * 64 + ty * 4 + i;
#pragma unroll
    for (int j = 0; j < 4; ++j) {
      int c = kt * 64 + tx * 4 + j;
      scores[base + (size_t)r * CS + c] = acc[i][j] * 0.125f;
    }
  }
}

// Causal row softmax in-place: row r uses cols 0..r, writes 0 for c>r.
__global__ __launch_bounds__(256) void softmax_kernel(float* __restrict__ scores) {
  int row = blockIdx.x;
  int bh = row / CS, r = row % CS;
  float* p = scores + (size_t)bh * CS * CS + (size_t)r * CS;
  int n = r + 1;
  int tid = threadIdx.x;
  __shared__ float buf[CS];
  __shared__ float redm[4], reds[4], sbc[2];
  float m = -1e30f;
  for (int c = tid; c < n; c += 256) {
    float v = p[c];
    buf[c] = v;
    m = fmaxf(m, v);
  }
  for (int off = 32; off > 0; off >>= 1) m = fmaxf(m, __shfl_down(m, off));
  int lane = tid & 63, wid = tid >> 6;
  if (lane == 0) redm[wid] = m;
  __syncthreads();
  if (tid == 0) sbc[0] = fmaxf(fmaxf(redm[0], redm[1]), fmaxf(redm[2], redm[3]));
  __syncthreads();
  float mmax = sbc[0];
  float s = 0.f;
  for (int c = tid; c < n; c += 256) {
    float e = __expf(buf[c] - mmax);
    buf[c] = e;
    s += e;
  }
  for (int off = 32; off > 0; off >>= 1) s += __shfl_down(s, off);
  if (lane == 0) reds[wid] = s;
  __syncthreads();
  if (tid == 0) sbc[1] = reds[0] + reds[1] + reds[2] + reds[3];
  __syncthreads();
  float inv = 1.0f / sbc[1];
  for (int c = tid; c < CS; c += 256) p[c] = (c < n) ? buf[c] * inv : 0.f;
}

// ctx hi/lo planes = P[64q][S] @ V[S][64d] per (qt, bh); kt<=qt only.
__global__ __launch_bounds__(256) void pv_kernel(
    const float* __restrict__ scores, const float* __restrict__ qkv,
    short* __restrict__ ctxh, short* __restrict__ ctxl) {
  int qt = blockIdx.x, bh = blockIdx.y;
  int b = bh / CH, h = bh % CH;
  __shared__ float Ps[64][68];
  __shared__ float Vs[64][68];
  int tid = threadIdx.x;
  int tx = tid & 15, ty = tid >> 4;
  float acc[4][4] = {};
  size_t base = (size_t)bh * CS * CS;
  for (int kt = 0; kt <= qt; ++kt) {
#pragma unroll
    for (int i = 0; i < 4; ++i) {
      int row = (tid >> 4) + i * 16;
      int col = (tid & 15) * 4;
      *(float4*)&Ps[row][col] =
          *(const float4*)(scores + base + (size_t)(qt * 64 + row) * CS + kt * 64 + col);
      *(float4*)&Vs[row][col] =
          *(const float4*)(qkv + (size_t)(b * CS + kt * 64 + row) * QKVP + 2048 + h * CHD + col);
    }
    __syncthreads();
#pragma unroll 16
    for (int kk = 0; kk < 64; ++kk) {
      float ra[4];
#pragma unroll
      for (int i = 0; i < 4; ++i) ra[i] = Ps[ty * 4 + i][kk];
      float4 rb4 = *(const float4*)&Vs[kk][tx * 4];
      float rb[4] = {rb4.x, rb4.y, rb4.z, rb4.w};
#pragma unroll
      for (int i = 0; i < 4; ++i)
#pragma unroll
        for (int j = 0; j < 4; ++j) acc[i][j] += ra[i] * rb[j];
    }
    __syncthreads();
  }
#pragma unroll
  for (int i = 0; i < 4; ++i)
#pragma unroll
    for (int j = 0; j < 4; ++j) {
      size_t oi =
          (size_t)(b * CS + qt * 64 + ty * 4 + i) * CD + h * CHD + tx * 4 + j;
      float v = acc[i][j];
      short hi = f2bf(v);
      ctxh[oi] = hi;
      ctxl[oi] = f2bf(v - bf2f(hi));
    }
}

// ---------------------------------------------------------------------------
__global__ void zero_kernel(int* cursor) {
  int i = threadIdx.x;
  if (i < CE) cursor[i] = 0;
}

// Router: one WAVE per token. Shuffle-reduce 8 logits; lane 0 does softmax +
// top-2 and writes per-token outputs. NO global atomics (stats in finalize).
__global__ __launch_bounds__(64) void router_kernel(
    const float* __restrict__ h2, const float* __restrict__ wr,
    const float* __restrict__ br, int* __restrict__ top_i,
    float* __restrict__ top_p, float* __restrict__ probs_out) {
  int t = blockIdx.x;
  int lane = threadIdx.x;
  float a[CE] = {};
  const float4* hv4 = (const float4*)(h2 + (size_t)t * CD);
#pragma unroll
  for (int i = 0; i < 4; ++i) {
    float4 hv = hv4[lane * 4 + i];
    const float* wrow = wr + (size_t)(lane * 16 + i * 4) * CE;
    float hh[4] = {hv.x, hv.y, hv.z, hv.w};
#pragma unroll
    for (int j = 0; j < 4; ++j)
#pragma unroll
      for (int e = 0; e < CE; ++e) a[e] += hh[j] * wrow[j * CE + e];
  }
#pragma unroll
  for (int e = 0; e < CE; ++e)
    for (int off = 32; off > 0; off >>= 1) a[e] += __shfl_down(a[e], off);
  if (lane == 0) {
    float probs[CE];
    float mx = -1e30f;
#pragma unroll
    for (int e = 0; e < CE; ++e) {
      a[e] += br[e];
      mx = fmaxf(mx, a[e]);
    }
    float sum = 0.f;
#pragma unroll
    for (int e = 0; e < CE; ++e) { probs[e] = __expf(a[e] - mx); sum += probs[e]; }
    float inv = 1.0f / sum;
#pragma unroll
    for (int e = 0; e < CE; ++e) {
      probs[e] *= inv;
      probs_out[t * CE + e] = probs[e];
    }
    int i1 = 0;
#pragma unroll
    for (int e = 1; e < CE; ++e) if (probs[e] > probs[i1]) i1 = e;
    int i2 = (i1 == 0) ? 1 : 0;
#pragma unroll
    for (int e = 0; e < CE; ++e)
      if (e != i1 && probs[e] > probs[i2]) i2 = e;
    float p1 = probs[i1], p2 = probs[i2];
    float s12 = p1 + p2;
    top_i[t * 2 + 0] = i1;
    top_i[t * 2 + 1] = i2;
    top_p[t * 2 + 0] = p1 / s12;
    top_p[t * 2 + 1] = p2 / s12;
  }
}

// Finalize (1 block): deterministic counts/psum reduction from top_i/probs,
// then 128-aligned per-expert offsets, tile->expert map, aux loss, row_map init.
__global__ __launch_bounds__(256) void finalize_kernel(
    const int* __restrict__ top_i, const float* __restrict__ probs,
    int* __restrict__ offs, int* __restrict__ tile_e,
    int* __restrict__ total_padded, int* __restrict__ row_map,
    float* __restrict__ aux_out) {
  int tid = threadIdx.x;
  __shared__ float redp[256][CE];
  __shared__ int redc[256][CE];
  float lp[CE] = {};
  int lc[CE] = {};
  for (int t = tid; t < CT; t += 256) {
    lc[top_i[t * 2 + 0]]++;
    lc[top_i[t * 2 + 1]]++;
#pragma unroll
    for (int e = 0; e < CE; ++e) lp[e] += probs[t * CE + e];
  }
#pragma unroll
  for (int e = 0; e < CE; ++e) { redp[tid][e] = lp[e]; redc[tid][e] = lc[e]; }
  __syncthreads();
  for (int s = 128; s > 0; s >>= 1) {
    if (tid < s) {
#pragma unroll
      for (int e = 0; e < CE; ++e) {
        redp[tid][e] += redp[tid + s][e];
        redc[tid][e] += redc[tid + s][e];
      }
    }
    __syncthreads();
  }
  __shared__ int s_off[CE + 1];
  if (tid == 0) {
    int o = 0;
    for (int e = 0; e < CE; ++e) {
      s_off[e] = o;
      offs[e] = o;
      o += ((redc[0][e] + 127) >> 7) << 7;
    }
    s_off[CE] = o;
    offs[CE] = o;
    *total_padded = o;
    int nt = o >> 7;
    for (int i = 0; i < nt; ++i) {
      int e = 0;
      while (e < CE - 1 && i * 128 >= s_off[e + 1]) e++;
      tile_e[i] = e;
    }
    float aux = 0.f;
    for (int e = 0; e < CE; ++e)
      aux += ((float)redc[0][e] / (float)(CT * CK)) * (redp[0][e] / (float)CT);
    aux_out[0] = aux * (float)CE;
  }
  __syncthreads();
  for (int i = tid; i < MAXROWS; i += blockDim.x) row_map[i] = -1;
}

__global__ void gather_kernel(const int* __restrict__ top_i,
                              const int* __restrict__ offs,
                              int* __restrict__ cursor, int* __restrict__ row_map,
                              int* __restrict__ row_of) {
  int idx = blockIdx.x * blockDim.x + threadIdx.x;
  if (idx >= CT * CK) return;
  int e = top_i[idx];
  int pos = offs[e] + atomicAdd(&cursor[e], 1);
  row_map[pos] = idx >> 1;
  row_of[idx] = pos;
}

// Xg[row] = bf16(h2[row_map[row]]) or zeros for pad rows.
__global__ __launch_bounds__(256) void gatherx_kernel(
    const float* __restrict__ h2, const int* __restrict__ row_map,
    short* __restrict__ Xg) {
  int row = blockIdx.x;
  int tid = threadIdx.x;
  int tok = row_map[row];
  short4 o;
  if (tok < 0) {
    o = make_short4(0, 0, 0, 0);
  } else {
    float4 v = ((const float4*)(h2 + (size_t)tok * CD))[tid];
    o = make_short4(f2bf(v.x), f2bf(v.y), f2bf(v.z), f2bf(v.w));
  }
  ((short4*)(Xg + (size_t)row * CD))[tid] = o;
}

// out[t] = x1[t] + sum_k top_p[t,k] * ff_rows[row_of[t,k]]
__global__ __launch_bounds__(256) void combine_kernel(
    const float* __restrict__ x1, const float* __restrict__ ff_rows,
    const int* __restrict__ row_of, const float* __restrict__ top_p,
    float* __restrict__ out) {
  int t = blockIdx.x;
  int tid = threadIdx.x;
  float4 r = ((const float4*)(x1 + (size_t)t * CD))[tid];
#pragma unroll
  for (int s = 0; s < CK; ++s) {
    float w = top_p[t * 2 + s];
    int row = row_of[t * 2 + s];
    float4 f = ((const float4*)(ff_rows + (size_t)row * CD))[tid];
    r.x += w * f.x; r.y += w * f.y; r.z += w * f.z; r.w += w * f.w;
  }
  ((float4*)(out + (size_t)t * CD))[tid] = r;
}

// ---------------------------------------------------------------------------
extern "C" void kernel_launch(void* const* d_in, const int* in_sizes, int n_in,
                              void* d_out, int out_size, void* d_ws,
                              size_t ws_size, hipStream_t stream) {
  const float* x   = (const float*)d_in[0];
  const float* n1w = (const float*)d_in[1];
  const float* n2w = (const float*)d_in[2];
  const float* wq  = (const float*)d_in[3];
  const float* bq  = (const float*)d_in[4];
  const float* wk  = (const float*)d_in[5];
  const float* bk  = (const float*)d_in[6];
  const float* wv  = (const float*)d_in[7];
  const float* bv  = (const float*)d_in[8];
  const float* wo  = (const float*)d_in[9];
  const float* bo  = (const float*)d_in[10];
  const float* wr  = (const float*)d_in[11];
  const float* br  = (const float*)d_in[12];
  const float* w1  = (const float*)d_in[13];
  const float* b1  = (const float*)d_in[14];
  const float* w2  = (const float*)d_in[15];
  const float* b2  = (const float*)d_in[16];
  float* out = (float*)d_out;

  char* base = (char*)d_ws;
  size_t off = 0;
  auto alloc = [&](size_t bytes) -> void* {
    void* p = base + off;
    off += (bytes + 255) & ~(size_t)255;
    return p;
  };
  float* f_x1   = (float*)alloc((size_t)CT * CD * 4);
  float* f_h2   = (float*)alloc((size_t)CT * CD * 4);
  short* f_xg   = (short*)alloc((size_t)MAXROWS * CD * 2);
  short* f_hid  = (short*)alloc((size_t)MAXROWS * CF * 2);
  float* f_ff   = (float*)alloc((size_t)MAXROWS * CD * 4);
  // attention-phase buffers (hi/lo planes)
  short* f_hh   = (short*)alloc((size_t)CT * CD * 2);
  short* f_hl   = (short*)alloc((size_t)CT * CD * 2);
  short* f_wqkvh = (short*)alloc((size_t)QKVP * CD * 2);
  short* f_wqkvl = (short*)alloc((size_t)QKVP * CD * 2);
  float* f_qkv  = (float*)alloc((size_t)CT * QKVP * 4);
  short* f_ctxh = (short*)alloc((size_t)CT * CD * 2);
  short* f_ctxl = (short*)alloc((size_t)CT * CD * 2);
  short* f_woth = (short*)alloc((size_t)CD * CD * 2);
  short* f_wotl = (short*)alloc((size_t)CD * CD * 2);
  float* f_bqkv = (float*)alloc(QKVP * 4);
  float* f_topp = (float*)alloc(CT * CK * 4);
  float* f_probs = (float*)alloc(CT * CE * 4);
  int* i_topi   = (int*)alloc(CT * CK * 4);
  int* i_rowof  = (int*)alloc(CT * CK * 4);
  int* i_rowmap = (int*)alloc(MAXROWS * 4);
  int* i_cursor = (int*)alloc(CE * 4);
  int* i_offs   = (int*)alloc((CE + 1) * 4);
  int* i_tile   = (int*)alloc(MAXTILES * 4);
  int* i_total  = (int*)alloc(4);
  // G (64MB): w1t -> w2t (sequential reuse)
  short* f_wG = (short*)alloc((size_t)CE * CD * CF * 2);
  short* f_w1t = f_wG;
  short* f_w2t = f_wG;
  // Rs (32MB): scores -> WO partials (4x1024x1024 f32) -> GEMM2 partials (2x3072x1024 f32)
  void* Rs = alloc((size_t)CBH * CS * CS * 4);
  float* f_scores = (float*)Rs;
  float* f_partwo = (float*)Rs;
  float* f_partg2 = (float*)Rs;

  dim3 b256(256);

  zero_kernel<<<1, 64, 0, stream>>>(i_cursor);
  pack_bias_kernel<<<QKVP / 256, b256, 0, stream>>>(bq, bk, bv, f_bqkv);
  // weight preprocessing (hi/lo planes for attention, hi-only for experts' w1)
  transpose_convert_kernel<<<dim3(32, 32, 1), b256, 0, stream>>>(
      wq, f_wqkvh + 0 * (size_t)CD * CD, f_wqkvl + 0 * (size_t)CD * CD, CD, CD);
  transpose_convert_kernel<<<dim3(32, 32, 1), b256, 0, stream>>>(
      wk, f_wqkvh + 1 * (size_t)CD * CD, f_wqkvl + 1 * (size_t)CD * CD, CD, CD);
  transpose_convert_kernel<<<dim3(32, 32, 1), b256, 0, stream>>>(
      wv, f_wqkvh + 2 * (size_t)CD * CD, f_wqkvl + 2 * (size_t)CD * CD, CD, CD);
  transpose_convert_kernel<<<dim3(32, 32, 1), b256, 0, stream>>>(
      wo, f_woth, f_wotl, CD, CD);
  transpose_convert_kernel<<<dim3(CF / 32, CD / 32, CE), b256, 0, stream>>>(
      w1, f_w1t, nullptr, CD, CF);

  // ---- attention (hi/lo MFMA projections; fp32 scores/softmax/pv) ----
  rmsnorm_kernel<2><<<CT, b256, 0, stream>>>(x, n1w, f_hh, f_hl);
  // fused QKV: [1024,1024] @ [1024,3072] -> f_qkv fp32
  mfma_gemm_kernel<1, 0><<<dim3(QKVP / 128, CT / 128, 1), b256, 0, stream>>>(
      f_hh, f_hl, f_wqkvh, f_wqkvl, f_bqkv, f_qkv, nullptr, 0, QKVP, CD, 0, 0,
      nullptr, nullptr);
  scores_kernel<<<dim3(CS / 64, CS / 64, CBH), b256, 0, stream>>>(f_qkv, f_scores);
  softmax_kernel<<<CBH * CS, b256, 0, stream>>>(f_scores);
  pv_kernel<<<dim3(CS / 64, CBH), b256, 0, stream>>>(f_scores, f_qkv, f_ctxh,
                                                     f_ctxl);
  // WO: split-K=4 partials (scores now dead), reduce adds bo + residual x
  mfma_gemm_kernel<1, 0><<<dim3(CD / 128, CT / 128, 4), b256, 0, stream>>>(
      f_ctxh, f_ctxl, f_woth, f_wotl, nullptr, nullptr, f_partwo, CT, CD, CD,
      0, 0, nullptr, nullptr);
  reduce_splitk_kernel<<<CT, b256, 0, stream>>>(f_partwo, CT, 4, bo, nullptr, x,
                                                f_x1, CD, nullptr);

  // ---- MoE ----
  rmsnorm_kernel<0><<<CT, b256, 0, stream>>>(f_x1, n2w, f_h2, nullptr);
  router_kernel<<<CT, dim3(64), 0, stream>>>(f_h2, wr, br, i_topi, f_topp,
                                             f_probs);
  finalize_kernel<<<1, 256, 0, stream>>>(i_topi, f_probs, i_offs, i_tile,
                                         i_total, i_rowmap,
                                         out + (size_t)CT * CD);
  gather_kernel<<<(CT * CK + 255) / 256, b256, 0, stream>>>(i_topi, i_offs,
                                                            i_cursor, i_rowmap,
                                                            i_rowof);
  gatherx_kernel<<<MAXROWS, b256, 0, stream>>>(f_h2, i_rowmap, f_xg);

  // expert GEMM1: hid = silu(Xg @ w1[e] + b1[e])  (bf16 out, no split)
  mfma_gemm_kernel<0, 1><<<dim3(CF / 128, MAXTILES, 1), b256, 0, stream>>>(
      f_xg, nullptr, f_w1t, nullptr, b1, f_hid, nullptr, 0, CF, CD, 1, 1,
      i_tile, i_total);
  // expert GEMM2: split-K=2 partials, reduce adds b2[e]
  transpose_convert_kernel<<<dim3(CD / 32, CF / 32, CE), b256, 0, stream>>>(
      w2, f_w2t, nullptr, CF, CD);
  mfma_gemm_kernel<0, 1><<<dim3(CD / 128, MAXTILES, 2), b256, 0, stream>>>(
      f_hid, nullptr, f_w2t, nullptr, nullptr, nullptr, f_partg2, MAXROWS, CD,
      CF, 0, 0, i_tile, i_total);
  reduce_splitk_kernel<<<MAXROWS, b256, 0, stream>>>(f_partg2, MAXROWS, 2, b2,
                                                     i_tile, nullptr, f_ff, CD,
                                                     i_total);

  combine_kernel<<<CT, b256, 0, stream>>>(f_x1, f_ff, i_rowof, f_topp, out);
}

// Round 6
// 462.753 us; speedup vs baseline: 2.4749x; 1.0098x over previous
//
#include <hip/hip_runtime.h>
#include <math.h>

// Problem constants
#define CB 2
#define CS 512
#define CD 1024
#define CH 16
#define CHD 64
#define CF 4096
#define CE 8
#define CK 2
#define CT (CB*CS)      // 1024 tokens
#define CBH (CB*CH)     // 32 (batch*heads)
#define CEPS 1e-6f
#define QKVP 3072       // packed q|k|v row pitch
#define MAXROWS 3072    // 2048 + 8*127 padded to 128
#define MAXTILES (MAXROWS/128)

typedef __attribute__((ext_vector_type(8))) short bf16x8;
typedef __attribute__((ext_vector_type(4))) float f32x4;

__device__ __forceinline__ short f2bf(float f) {
  unsigned u = __float_as_uint(f);
  unsigned r = (u + 0x7FFF + ((u >> 16) & 1)) >> 16;
  return (short)r;
}
__device__ __forceinline__ float bf2f(short h) {
  return __uint_as_float(((unsigned)(unsigned short)h) << 16);
}

__device__ __forceinline__ void gload_lds16(const void* g, void* l) {
  __builtin_amdgcn_global_load_lds(
      (const __attribute__((address_space(1))) unsigned int*)g,
      (__attribute__((address_space(3))) unsigned int*)l, 16, 0, 0);
}

// ---------------------------------------------------------------------------
// RMSNorm. MODE 0: fp32 out (outA). MODE 2: hi/lo bf16 planes (outA=hi, outB=lo)
template <int MODE>
__global__ __launch_bounds__(256) void rmsnorm_kernel(
    const float* __restrict__ x, const float* __restrict__ w,
    void* __restrict__ outA, void* __restrict__ outB) {
  int t = blockIdx.x;
  int tid = threadIdx.x;
  float4 xv = ((const float4*)(x + (size_t)t * CD))[tid];
  float ss = xv.x*xv.x + xv.y*xv.y + xv.z*xv.z + xv.w*xv.w;
  for (int off = 32; off > 0; off >>= 1) ss += __shfl_down(ss, off);
  __shared__ float red[4];
  __shared__ float s_scale;
  int lane = tid & 63, wid = tid >> 6;
  if (lane == 0) red[wid] = ss;
  __syncthreads();
  if (tid == 0) {
    float tot = red[0] + red[1] + red[2] + red[3];
    s_scale = rsqrtf(tot / (float)CD + CEPS);
  }
  __syncthreads();
  float sc = s_scale;
  float4 wv = ((const float4*)w)[tid];
  float o[4] = {xv.x * sc * wv.x, xv.y * sc * wv.y,
                xv.z * sc * wv.z, xv.w * sc * wv.w};
  if (MODE == 0) {
    ((float4*)((float*)outA + (size_t)t * CD))[tid] =
        make_float4(o[0], o[1], o[2], o[3]);
  } else {
    short4 hi, lo;
    short* hp = (short*)&hi; short* lp = (short*)&lo;
#pragma unroll
    for (int i = 0; i < 4; ++i) {
      short h = f2bf(o[i]);
      hp[i] = h;
      lp[i] = f2bf(o[i] - bf2f(h));
    }
    ((short4*)((short*)outA + (size_t)t * CD))[tid] = hi;
    ((short4*)((short*)outB + (size_t)t * CD))[tid] = lo;
  }
}

// ---------------------------------------------------------------------------
// Tiled transpose: W[e][Kd][Nd] f32 -> Wth[e][Nd][Kd] bf16 (+ optional lo plane)
__global__ __launch_bounds__(256) void transpose_convert_kernel(
    const float* __restrict__ W, short* __restrict__ Wth,
    short* __restrict__ Wtl, int Kd, int Nd) {
  int e = blockIdx.z;
  const float* Wb = W + (size_t)e * Kd * Nd;
  size_t obase = (size_t)e * Kd * Nd;
  int n0 = blockIdx.x * 32, k0 = blockIdx.y * 32;
  __shared__ float tile[32][33];
  int tx = threadIdx.x & 31, ty = threadIdx.x >> 5;
#pragma unroll
  for (int i = 0; i < 4; ++i)
    tile[ty + i * 8][tx] = Wb[(size_t)(k0 + ty + i * 8) * Nd + n0 + tx];
  __syncthreads();
#pragma unroll
  for (int i = 0; i < 4; ++i) {
    float v = tile[tx][ty + i * 8];
    short hi = f2bf(v);
    size_t oi = obase + (size_t)(n0 + ty + i * 8) * Kd + k0 + tx;
    Wth[oi] = hi;
    if (Wtl) Wtl[oi] = f2bf(v - bf2f(hi));
  }
}

__global__ void pack_bias_kernel(const float* __restrict__ bq,
                                 const float* __restrict__ bk,
                                 const float* __restrict__ bv,
                                 float* __restrict__ out) {
  int i = blockIdx.x * 256 + threadIdx.x;
  if (i < QKVP)
    out[i] = (i < 1024) ? bq[i] : (i < 2048 ? bk[i - 1024] : bv[i - 2048]);
}

// ---------------------------------------------------------------------------
// Unified bf16 MFMA GEMM, 128x128 tile, BK=32, 4 waves (2x2), 4x4 frags/wave.
// Double-buffered LDS: next K-step's global_load_lds issued BEFORE computing
// the current step, so HBM latency overlaps ds_read+MFMA; one barrier/K-step.
// Buffers are statically distinct arrays (loop unrolled x2) so the compiler
// can disambiguate prefetch writes from current-tile ds_reads.
// LO=1: A/B given as hi+lo bf16 planes; acc += ah*bh + ah*bl + al*bh (~fp32).
// GROUPED=1: expert-grouped B/bias via tile_e (rows 128-padded per expert).
// gridDim.z>1: split-K -> fp32 partials at part[z][partM][N], no epilogue.
__device__ __forceinline__ void stage_tile(const short* __restrict__ gbase,
                                           int ldK, int row0, int k0,
                                           short* lds, int tid) {
  int wbase = tid & 192;  // wave-uniform chunk base
#pragma unroll
  for (int ic = 0; ic < 2; ++ic) {
    int c = ic * 256 + tid;
    int g = c >> 7, r = c & 127;
    const short* gsrc = gbase + (size_t)(row0 + r) * ldK + k0 + g * 8;
    short* ldst = lds + (size_t)(ic * 256 + wbase) * 8;
    gload_lds16(gsrc, ldst);
  }
}

template <int LO, int GROUPED>
__global__ __launch_bounds__(256) void mfma_gemm_kernel(
    const short* __restrict__ Ah, const short* __restrict__ Al,
    const short* __restrict__ Bh, const short* __restrict__ Bl,
    const float* __restrict__ bias, void* __restrict__ Cout,
    float* __restrict__ part, int partM, int N, int K, int silu, int outbf,
    const int* __restrict__ tile_e, const int* __restrict__ total_rows) {
  __shared__ short As0[4096], Bs0[4096], As1[4096], Bs1[4096];
  __shared__ short Als0[LO ? 4096 : 64], Bls0[LO ? 4096 : 64];
  __shared__ short Als1[LO ? 4096 : 64], Bls1[LO ? 4096 : 64];
  int tid = threadIdx.x;
  int m0 = blockIdx.y * 128, n0 = blockIdx.x * 128;
  const short* Bhb = Bh;
  const short* Blb = Bl;
  const float* biasb = bias;
  if (GROUPED) {
    if (m0 >= *total_rows) return;
    int e = tile_e[blockIdx.y];
    Bhb = Bh + (size_t)e * N * K;
    biasb = bias + (size_t)e * N;
  }
  int kz = blockIdx.z;
  int kchunk = K / gridDim.z;
  int kbeg = kz * kchunk;
  int nsteps = kchunk >> 5;  // always even in this pipeline (8..64)
  int lane = tid & 63, w = tid >> 6;
  int wr = w >> 1, wc = w & 1;
  int l15 = lane & 15, l4 = lane >> 4;
  f32x4 acc[4][4] = {};

#define STAGE_SET(AS_, BS_, ALS_, BLS_, KK)                                   \
  {                                                                           \
    stage_tile(Ah, K, m0, (KK), AS_, tid);                                    \
    stage_tile(Bhb, K, n0, (KK), BS_, tid);                                   \
    if (LO) {                                                                 \
      stage_tile(Al, K, m0, (KK), ALS_, tid);                                 \
      stage_tile(Blb, K, n0, (KK), BLS_, tid);                                \
    }                                                                         \
  }

#define COMPUTE_SET(AS_, BS_, ALS_, BLS_)                                     \
  {                                                                           \
    bf16x8 ah[4], al[4];                                                      \
    _Pragma("unroll") for (int m = 0; m < 4; ++m) {                           \
      int idx = (l4 * 128 + wr * 64 + m * 16 + l15) * 8;                      \
      ah[m] = *(const bf16x8*)&AS_[idx];                                      \
      if (LO) al[m] = *(const bf16x8*)&ALS_[idx];                             \
    }                                                                         \
    _Pragma("unroll") for (int n = 0; n < 4; ++n) {                           \
      int idx = (l4 * 128 + wc * 64 + n * 16 + l15) * 8;                      \
      bf16x8 bhn = *(const bf16x8*)&BS_[idx];                                 \
      bf16x8 bln;                                                             \
      if (LO) bln = *(const bf16x8*)&BLS_[idx];                               \
      _Pragma("unroll") for (int m = 0; m < 4; ++m) {                         \
        acc[m][n] = __builtin_amdgcn_mfma_f32_16x16x32_bf16(ah[m], bhn,       \
                                                            acc[m][n], 0, 0, 0); \
        if (LO) {                                                             \
          acc[m][n] = __builtin_amdgcn_mfma_f32_16x16x32_bf16(al[m], bhn,     \
                                                              acc[m][n], 0, 0, 0); \
          acc[m][n] = __builtin_amdgcn_mfma_f32_16x16x32_bf16(ah[m], bln,     \
                                                              acc[m][n], 0, 0, 0); \
        }                                                                     \
      }                                                                       \
    }                                                                         \
  }

  STAGE_SET(As0, Bs0, Als0, Bls0, kbeg);
  __syncthreads();
  for (int s = 0; s < nsteps; s += 2) {
    int k0 = kbeg + (s << 5);
    if (s + 1 < nsteps) STAGE_SET(As1, Bs1, Als1, Bls1, k0 + 32);
    COMPUTE_SET(As0, Bs0, Als0, Bls0);
    __syncthreads();
    if (s + 1 < nsteps) {
      if (s + 2 < nsteps) STAGE_SET(As0, Bs0, Als0, Bls0, k0 + 64);
      COMPUTE_SET(As1, Bs1, Als1, Bls1);
      __syncthreads();
    }
  }
#undef STAGE_SET
#undef COMPUTE_SET

  if (gridDim.z > 1) {
    // split-K: write fp32 partials (bias applied in reduce)
#pragma unroll
    for (int m = 0; m < 4; ++m) {
      int row = m0 + wr * 64 + m * 16 + l4 * 4;
#pragma unroll
      for (int n = 0; n < 4; ++n) {
        int col = n0 + wc * 64 + n * 16 + l15;
#pragma unroll
        for (int q = 0; q < 4; ++q)
          part[((size_t)kz * partM + row + q) * N + col] = acc[m][n][q];
      }
    }
    return;
  }
  float* outf = (float*)Cout;
  short* outb = (short*)Cout;
#pragma unroll
  for (int m = 0; m < 4; ++m) {
    int row = m0 + wr * 64 + m * 16 + l4 * 4;
#pragma unroll
    for (int n = 0; n < 4; ++n) {
      int col = n0 + wc * 64 + n * 16 + l15;
      float bv = biasb[col];
#pragma unroll
      for (int q = 0; q < 4; ++q) {
        float v = acc[m][n][q] + bv;
        if (silu) v = v / (1.f + __expf(-v));
        if (outbf) outb[(size_t)(row + q) * N + col] = f2bf(v);
        else outf[(size_t)(row + q) * N + col] = v;
      }
    }
  }
}

// split-K reduce: out[row][c] = sum_z part[z][row][c] + bias (+res). fp32 out.
__global__ __launch_bounds__(256) void reduce_splitk_kernel(
    const float* __restrict__ part, int partM, int nz,
    const float* __restrict__ bias, const int* __restrict__ tile_e,
    const float* __restrict__ res, float* __restrict__ outp, int N,
    const int* __restrict__ total_rows) {
  int row = blockIdx.x;
  if (total_rows && row >= *total_rows) return;
  const float* bb = bias;
  if (tile_e) bb = bias + (size_t)tile_e[row >> 7] * N;
  for (int c = threadIdx.x * 4; c < N; c += 1024) {
    float4 s = *(const float4*)(part + (size_t)row * N + c);
    for (int z = 1; z < nz; ++z) {
      float4 p = *(const float4*)(part + ((size_t)z * partM + row) * N + c);
      s.x += p.x; s.y += p.y; s.z += p.z; s.w += p.w;
    }
    s.x += bb[c]; s.y += bb[c + 1]; s.z += bb[c + 2]; s.w += bb[c + 3];
    if (res) {
      float4 r = *(const float4*)(res + (size_t)row * N + c);
      s.x += r.x; s.y += r.y; s.z += r.z; s.w += r.w;
    }
    *(float4*)(outp + (size_t)row * N + c) = s;
  }
}

// ---------------------------------------------------------------------------
// Attention scores: S_tile[64q][64k] = Q Kt / 8 per (b,h); packed qkv input.
__global__ __launch_bounds__(256) void scores_kernel(
    const float* __restrict__ qkv, float* __restrict__ scores) {
  int kt = blockIdx.x, qt = blockIdx.y, bh = blockIdx.z;
  if (kt > qt) return;
  int b = bh / CH, h = bh % CH;
  __shared__ float Qs[64][68];
  __shared__ float Ks[64][68];
  int tid = threadIdx.x;
#pragma unroll
  for (int i = 0; i < 4; ++i) {
    int row = (tid >> 4) + i * 16;
    int col = (tid & 15) * 4;
    *(float4*)&Qs[row][col] =
        *(const float4*)(qkv + (size_t)(b * CS + qt * 64 + row) * QKVP + h * CHD + col);
    *(float4*)&Ks[row][col] =
        *(const float4*)(qkv + (size_t)(b * CS + kt * 64 + row) * QKVP + 1024 + h * CHD + col);
  }
  __syncthreads();
  int tx = tid & 15, ty = tid >> 4;
  float acc[4][4] = {};
#pragma unroll 16
  for (int d = 0; d < 64; ++d) {
    float ra[4], rb[4];
#pragma unroll
    for (int i = 0; i < 4; ++i) ra[i] = Qs[ty * 4 + i][d];
#pragma unroll
    for (int j = 0; j < 4; ++j) rb[j] = Ks[tx * 4 + j][d];
#pragma unroll
    for (int i = 0; i < 4; ++i)
#pragma unroll
      for (int j = 0; j < 4; ++j) acc[i][j] += ra[i] * rb[j];
  }
  size_t base = (size_t)bh * CS * CS;
#pragma unroll
  for (int i = 0; i < 4; ++i) {
    int r = qt * 64 + ty * 4 + i;
#pragma unroll
    for (int j = 0; j < 4; ++j) {
      int c = kt * 64 + tx * 4 + j;
      scores[base + (size_t)r * CS + c] = acc[i][j] * 0.125f;
    }
  }
}

// Causal row softmax in-place: row r uses cols 0..r, writes 0 for c>r.
__global__ __launch_bounds__(256) void softmax_kernel(float* __restrict__ scores) {
  int row = blockIdx.x;
  int bh = row / CS, r = row % CS;
  float* p = scores + (size_t)bh * CS * CS + (size_t)r * CS;
  int n = r + 1;
  int tid = threadIdx.x;
  __shared__ float buf[CS];
  __shared__ float redm[4], reds[4], sbc[2];
  float m = -1e30f;
  for (int c = tid; c < n; c += 256) {
    float v = p[c];
    buf[c] = v;
    m = fmaxf(m, v);
  }
  for (int off = 32; off > 0; off >>= 1) m = fmaxf(m, __shfl_down(m, off));
  int lane = tid & 63, wid = tid >> 6;
  if (lane == 0) redm[wid] = m;
  __syncthreads();
  if (tid == 0) sbc[0] = fmaxf(fmaxf(redm[0], redm[1]), fmaxf(redm[2], redm[3]));
  __syncthreads();
  float mmax = sbc[0];
  float s = 0.f;
  for (int c = tid; c < n; c += 256) {
    float e = __expf(buf[c] - mmax);
    buf[c] = e;
    s += e;
  }
  for (int off = 32; off > 0; off >>= 1) s += __shfl_down(s, off);
  if (lane == 0) reds[wid] = s;
  __syncthreads();
  if (tid == 0) sbc[1] = reds[0] + reds[1] + reds[2] + reds[3];
  __syncthreads();
  float inv = 1.0f / sbc[1];
  for (int c = tid; c < CS; c += 256) p[c] = (c < n) ? buf[c] * inv : 0.f;
}

// ctx hi/lo planes = P[64q][S] @ V[S][64d] per (qt, bh); kt<=qt only.
__global__ __launch_bounds__(256) void pv_kernel(
    const float* __restrict__ scores, const float* __restrict__ qkv,
    short* __restrict__ ctxh, short* __restrict__ ctxl) {
  int qt = blockIdx.x, bh = blockIdx.y;
  int b = bh / CH, h = bh % CH;
  __shared__ float Ps[64][68];
  __shared__ float Vs[64][68];
  int tid = threadIdx.x;
  int tx = tid & 15, ty = tid >> 4;
  float acc[4][4] = {};
  size_t base = (size_t)bh * CS * CS;
  for (int kt = 0; kt <= qt; ++kt) {
#pragma unroll
    for (int i = 0; i < 4; ++i) {
      int row = (tid >> 4) + i * 16;
      int col = (tid & 15) * 4;
      *(float4*)&Ps[row][col] =
          *(const float4*)(scores + base + (size_t)(qt * 64 + row) * CS + kt * 64 + col);
      *(float4*)&Vs[row][col] =
          *(const float4*)(qkv + (size_t)(b * CS + kt * 64 + row) * QKVP + 2048 + h * CHD + col);
    }
    __syncthreads();
#pragma unroll 16
    for (int kk = 0; kk < 64; ++kk) {
      float ra[4];
#pragma unroll
      for (int i = 0; i < 4; ++i) ra[i] = Ps[ty * 4 + i][kk];
      float4 rb4 = *(const float4*)&Vs[kk][tx * 4];
      float rb[4] = {rb4.x, rb4.y, rb4.z, rb4.w};
#pragma unroll
      for (int i = 0; i < 4; ++i)
#pragma unroll
        for (int j = 0; j < 4; ++j) acc[i][j] += ra[i] * rb[j];
    }
    __syncthreads();
  }
#pragma unroll
  for (int i = 0; i < 4; ++i)
#pragma unroll
    for (int j = 0; j < 4; ++j) {
      size_t oi =
          (size_t)(b * CS + qt * 64 + ty * 4 + i) * CD + h * CHD + tx * 4 + j;
      float v = acc[i][j];
      short hi = f2bf(v);
      ctxh[oi] = hi;
      ctxl[oi] = f2bf(v - bf2f(hi));
    }
}

// ---------------------------------------------------------------------------
__global__ void zero_kernel(int* cursor) {
  int i = threadIdx.x;
  if (i < CE) cursor[i] = 0;
}

// Router: one WAVE per token. Shuffle-reduce 8 logits; lane 0 does softmax +
// top-2 and writes per-token outputs. NO global atomics (stats in finalize).
__global__ __launch_bounds__(64) void router_kernel(
    const float* __restrict__ h2, const float* __restrict__ wr,
    const float* __restrict__ br, int* __restrict__ top_i,
    float* __restrict__ top_p, float* __restrict__ probs_out) {
  int t = blockIdx.x;
  int lane = threadIdx.x;
  float a[CE] = {};
  const float4* hv4 = (const float4*)(h2 + (size_t)t * CD);
#pragma unroll
  for (int i = 0; i < 4; ++i) {
    float4 hv = hv4[lane * 4 + i];
    const float* wrow = wr + (size_t)(lane * 16 + i * 4) * CE;
    float hh[4] = {hv.x, hv.y, hv.z, hv.w};
#pragma unroll
    for (int j = 0; j < 4; ++j)
#pragma unroll
      for (int e = 0; e < CE; ++e) a[e] += hh[j] * wrow[j * CE + e];
  }
#pragma unroll
  for (int e = 0; e < CE; ++e)
    for (int off = 32; off > 0; off >>= 1) a[e] += __shfl_down(a[e], off);
  if (lane == 0) {
    float probs[CE];
    float mx = -1e30f;
#pragma unroll
    for (int e = 0; e < CE; ++e) {
      a[e] += br[e];
      mx = fmaxf(mx, a[e]);
    }
    float sum = 0.f;
#pragma unroll
    for (int e = 0; e < CE; ++e) { probs[e] = __expf(a[e] - mx); sum += probs[e]; }
    float inv = 1.0f / sum;
#pragma unroll
    for (int e = 0; e < CE; ++e) {
      probs[e] *= inv;
      probs_out[t * CE + e] = probs[e];
    }
    int i1 = 0;
#pragma unroll
    for (int e = 1; e < CE; ++e) if (probs[e] > probs[i1]) i1 = e;
    int i2 = (i1 == 0) ? 1 : 0;
#pragma unroll
    for (int e = 0; e < CE; ++e)
      if (e != i1 && probs[e] > probs[i2]) i2 = e;
    float p1 = probs[i1], p2 = probs[i2];
    float s12 = p1 + p2;
    top_i[t * 2 + 0] = i1;
    top_i[t * 2 + 1] = i2;
    top_p[t * 2 + 0] = p1 / s12;
    top_p[t * 2 + 1] = p2 / s12;
  }
}

// Finalize (1 block): deterministic counts/psum reduction from top_i/probs,
// then 128-aligned per-expert offsets, tile->expert map, aux loss, row_map init.
__global__ __launch_bounds__(256) void finalize_kernel(
    const int* __restrict__ top_i, const float* __restrict__ probs,
    int* __restrict__ offs, int* __restrict__ tile_e,
    int* __restrict__ total_padded, int* __restrict__ row_map,
    float* __restrict__ aux_out) {
  int tid = threadIdx.x;
  __shared__ float redp[256][CE];
  __shared__ int redc[256][CE];
  float lp[CE] = {};
  int lc[CE] = {};
  for (int t = tid; t < CT; t += 256) {
    lc[top_i[t * 2 + 0]]++;
    lc[top_i[t * 2 + 1]]++;
#pragma unroll
    for (int e = 0; e < CE; ++e) lp[e] += probs[t * CE + e];
  }
#pragma unroll
  for (int e = 0; e < CE; ++e) { redp[tid][e] = lp[e]; redc[tid][e] = lc[e]; }
  __syncthreads();
  for (int s = 128; s > 0; s >>= 1) {
    if (tid < s) {
#pragma unroll
      for (int e = 0; e < CE; ++e) {
        redp[tid][e] += redp[tid + s][e];
        redc[tid][e] += redc[tid + s][e];
      }
    }
    __syncthreads();
  }
  __shared__ int s_off[CE + 1];
  if (tid == 0) {
    int o = 0;
    for (int e = 0; e < CE; ++e) {
      s_off[e] = o;
      offs[e] = o;
      o += ((redc[0][e] + 127) >> 7) << 7;
    }
    s_off[CE] = o;
    offs[CE] = o;
    *total_padded = o;
    int nt = o >> 7;
    for (int i = 0; i < nt; ++i) {
      int e = 0;
      while (e < CE - 1 && i * 128 >= s_off[e + 1]) e++;
      tile_e[i] = e;
    }
    float aux = 0.f;
    for (int e = 0; e < CE; ++e)
      aux += ((float)redc[0][e] / (float)(CT * CK)) * (redp[0][e] / (float)CT);
    aux_out[0] = aux * (float)CE;
  }
  __syncthreads();
  for (int i = tid; i < MAXROWS; i += blockDim.x) row_map[i] = -1;
}

__global__ void gather_kernel(const int* __restrict__ top_i,
                              const int* __restrict__ offs,
                              int* __restrict__ cursor, int* __restrict__ row_map,
                              int* __restrict__ row_of) {
  int idx = blockIdx.x * blockDim.x + threadIdx.x;
  if (idx >= CT * CK) return;
  int e = top_i[idx];
  int pos = offs[e] + atomicAdd(&cursor[e], 1);
  row_map[pos] = idx >> 1;
  row_of[idx] = pos;
}

// Xg[row] = bf16(h2[row_map[row]]) or zeros for pad rows.
__global__ __launch_bounds__(256) void gatherx_kernel(
    const float* __restrict__ h2, const int* __restrict__ row_map,
    short* __restrict__ Xg) {
  int row = blockIdx.x;
  int tid = threadIdx.x;
  int tok = row_map[row];
  short4 o;
  if (tok < 0) {
    o = make_short4(0, 0, 0, 0);
  } else {
    float4 v = ((const float4*)(h2 + (size_t)tok * CD))[tid];
    o = make_short4(f2bf(v.x), f2bf(v.y), f2bf(v.z), f2bf(v.w));
  }
  ((short4*)(Xg + (size_t)row * CD))[tid] = o;
}

// out[t] = x1[t] + sum_k top_p[t,k] * ff_rows[row_of[t,k]]
__global__ __launch_bounds__(256) void combine_kernel(
    const float* __restrict__ x1, const float* __restrict__ ff_rows,
    const int* __restrict__ row_of, const float* __restrict__ top_p,
    float* __restrict__ out) {
  int t = blockIdx.x;
  int tid = threadIdx.x;
  float4 r = ((const float4*)(x1 + (size_t)t * CD))[tid];
#pragma unroll
  for (int s = 0; s < CK; ++s) {
    float w = top_p[t * 2 + s];
    int row = row_of[t * 2 + s];
    float4 f = ((const float4*)(ff_rows + (size_t)row * CD))[tid];
    r.x += w * f.x; r.y += w * f.y; r.z += w * f.z; r.w += w * f.w;
  }
  ((float4*)(out + (size_t)t * CD))[tid] = r;
}

// ---------------------------------------------------------------------------
extern "C" void kernel_launch(void* const* d_in, const int* in_sizes, int n_in,
                              void* d_out, int out_size, void* d_ws,
                              size_t ws_size, hipStream_t stream) {
  const float* x   = (const float*)d_in[0];
  const float* n1w = (const float*)d_in[1];
  const float* n2w = (const float*)d_in[2];
  const float* wq  = (const float*)d_in[3];
  const float* bq  = (const float*)d_in[4];
  const float* wk  = (const float*)d_in[5];
  const float* bk  = (const float*)d_in[6];
  const float* wv  = (const float*)d_in[7];
  const float* bv  = (const float*)d_in[8];
  const float* wo  = (const float*)d_in[9];
  const float* bo  = (const float*)d_in[10];
  const float* wr  = (const float*)d_in[11];
  const float* br  = (const float*)d_in[12];
  const float* w1  = (const float*)d_in[13];
  const float* b1  = (const float*)d_in[14];
  const float* w2  = (const float*)d_in[15];
  const float* b2  = (const float*)d_in[16];
  float* out = (float*)d_out;

  char* base = (char*)d_ws;
  size_t off = 0;
  auto alloc = [&](size_t bytes) -> void* {
    void* p = base + off;
    off += (bytes + 255) & ~(size_t)255;
    return p;
  };
  float* f_x1   = (float*)alloc((size_t)CT * CD * 4);
  float* f_h2   = (float*)alloc((size_t)CT * CD * 4);
  short* f_xg   = (short*)alloc((size_t)MAXROWS * CD * 2);
  short* f_hid  = (short*)alloc((size_t)MAXROWS * CF * 2);
  float* f_ff   = (float*)alloc((size_t)MAXROWS * CD * 4);
  // attention-phase buffers (hi/lo planes)
  short* f_hh   = (short*)alloc((size_t)CT * CD * 2);
  short* f_hl   = (short*)alloc((size_t)CT * CD * 2);
  short* f_wqkvh = (short*)alloc((size_t)QKVP * CD * 2);
  short* f_wqkvl = (short*)alloc((size_t)QKVP * CD * 2);
  float* f_qkv  = (float*)alloc((size_t)CT * QKVP * 4);
  short* f_ctxh = (short*)alloc((size_t)CT * CD * 2);
  short* f_ctxl = (short*)alloc((size_t)CT * CD * 2);
  short* f_woth = (short*)alloc((size_t)CD * CD * 2);
  short* f_wotl = (short*)alloc((size_t)CD * CD * 2);
  float* f_bqkv = (float*)alloc(QKVP * 4);
  float* f_topp = (float*)alloc(CT * CK * 4);
  float* f_probs = (float*)alloc(CT * CE * 4);
  int* i_topi   = (int*)alloc(CT * CK * 4);
  int* i_rowof  = (int*)alloc(CT * CK * 4);
  int* i_rowmap = (int*)alloc(MAXROWS * 4);
  int* i_cursor = (int*)alloc(CE * 4);
  int* i_offs   = (int*)alloc((CE + 1) * 4);
  int* i_tile   = (int*)alloc(MAXTILES * 4);
  int* i_total  = (int*)alloc(4);
  // G (64MB): w1t -> w2t (sequential reuse)
  short* f_wG = (short*)alloc((size_t)CE * CD * CF * 2);
  short* f_w1t = f_wG;
  short* f_w2t = f_wG;
  // Rs (32MB): QKV partials (2x1024x3072) -> scores -> WO partials (4x1024x1024)
  //            -> GEMM2 partials (2x3072x1024), all disjoint lifetimes
  void* Rs = alloc((size_t)CBH * CS * CS * 4);
  float* f_partqkv = (float*)Rs;
  float* f_scores = (float*)Rs;
  float* f_partwo = (float*)Rs;
  float* f_partg2 = (float*)Rs;

  dim3 b256(256);

  zero_kernel<<<1, 64, 0, stream>>>(i_cursor);
  pack_bias_kernel<<<QKVP / 256, b256, 0, stream>>>(bq, bk, bv, f_bqkv);
  // weight preprocessing (hi/lo planes for attention, hi-only for experts' w1)
  transpose_convert_kernel<<<dim3(32, 32, 1), b256, 0, stream>>>(
      wq, f_wqkvh + 0 * (size_t)CD * CD, f_wqkvl + 0 * (size_t)CD * CD, CD, CD);
  transpose_convert_kernel<<<dim3(32, 32, 1), b256, 0, stream>>>(
      wk, f_wqkvh + 1 * (size_t)CD * CD, f_wqkvl + 1 * (size_t)CD * CD, CD, CD);
  transpose_convert_kernel<<<dim3(32, 32, 1), b256, 0, stream>>>(
      wv, f_wqkvh + 2 * (size_t)CD * CD, f_wqkvl + 2 * (size_t)CD * CD, CD, CD);
  transpose_convert_kernel<<<dim3(32, 32, 1), b256, 0, stream>>>(
      wo, f_woth, f_wotl, CD, CD);
  transpose_convert_kernel<<<dim3(CF / 32, CD / 32, CE), b256, 0, stream>>>(
      w1, f_w1t, nullptr, CD, CF);

  // ---- attention (hi/lo MFMA projections; fp32 scores/softmax/pv) ----
  rmsnorm_kernel<2><<<CT, b256, 0, stream>>>(x, n1w, f_hh, f_hl);
  // fused QKV: [1024,1024] @ [1024,3072], split-K=2 partials + reduce
  mfma_gemm_kernel<1, 0><<<dim3(QKVP / 128, CT / 128, 2), b256, 0, stream>>>(
      f_hh, f_hl, f_wqkvh, f_wqkvl, nullptr, nullptr, f_partqkv, CT, QKVP, CD,
      0, 0, nullptr, nullptr);
  reduce_splitk_kernel<<<CT, b256, 0, stream>>>(f_partqkv, CT, 2, f_bqkv,
                                                nullptr, nullptr, f_qkv, QKVP,
                                                nullptr);
  scores_kernel<<<dim3(CS / 64, CS / 64, CBH), b256, 0, stream>>>(f_qkv, f_scores);
  softmax_kernel<<<CBH * CS, b256, 0, stream>>>(f_scores);
  pv_kernel<<<dim3(CS / 64, CBH), b256, 0, stream>>>(f_scores, f_qkv, f_ctxh,
                                                     f_ctxl);
  // WO: split-K=4 partials (scores now dead), reduce adds bo + residual x
  mfma_gemm_kernel<1, 0><<<dim3(CD / 128, CT / 128, 4), b256, 0, stream>>>(
      f_ctxh, f_ctxl, f_woth, f_wotl, nullptr, nullptr, f_partwo, CT, CD, CD,
      0, 0, nullptr, nullptr);
  reduce_splitk_kernel<<<CT, b256, 0, stream>>>(f_partwo, CT, 4, bo, nullptr, x,
                                                f_x1, CD, nullptr);

  // ---- MoE ----
  rmsnorm_kernel<0><<<CT, b256, 0, stream>>>(f_x1, n2w, f_h2, nullptr);
  router_kernel<<<CT, dim3(64), 0, stream>>>(f_h2, wr, br, i_topi, f_topp,
                                             f_probs);
  finalize_kernel<<<1, 256, 0, stream>>>(i_topi, f_probs, i_offs, i_tile,
                                         i_total, i_rowmap,
                                         out + (size_t)CT * CD);
  gather_kernel<<<(CT * CK + 255) / 256, b256, 0, stream>>>(i_topi, i_offs,
                                                            i_cursor, i_rowmap,
                                                            i_rowof);
  gatherx_kernel<<<MAXROWS, b256, 0, stream>>>(f_h2, i_rowmap, f_xg);

  // expert GEMM1: hid = silu(Xg @ w1[e] + b1[e])  (bf16 out, no split)
  mfma_gemm_kernel<0, 1><<<dim3(CF / 128, MAXTILES, 1), b256, 0, stream>>>(
      f_xg, nullptr, f_w1t, nullptr, b1, f_hid, nullptr, 0, CF, CD, 1, 1,
      i_tile, i_total);
  // expert GEMM2: split-K=2 partials, reduce adds b2[e]
  transpose_convert_kernel<<<dim3(CD / 32, CF / 32, CE), b256, 0, stream>>>(
      w2, f_w2t, nullptr, CF, CD);
  mfma_gemm_kernel<0, 1><<<dim3(CD / 128, MAXTILES, 2), b256, 0, stream>>>(
      f_hid, nullptr, f_w2t, nullptr, nullptr, nullptr, f_partg2, MAXROWS, CD,
      CF, 0, 0, i_tile, i_total);
  reduce_splitk_kernel<<<MAXROWS, b256, 0, stream>>>(f_partg2, MAXROWS, 2, b2,
                                                     i_tile, nullptr, f_ff, CD,
                                                     i_total);

  combine_kernel<<<CT, b256, 0, stream>>>(f_x1, f_ff, i_rowof, f_topp, out);
}

// Round 7
// 425.465 us; speedup vs baseline: 2.6918x; 1.0876x over previous
//
#include <hip/hip_runtime.h>
#include <math.h>

// Problem constants
#define CB 2
#define CS 512
#define CD 1024
#define CH 16
#define CHD 64
#define CF 4096
#define CE 8
#define CK 2
#define CT (CB*CS)      // 1024 tokens
#define CBH (CB*CH)     // 32 (batch*heads)
#define CEPS 1e-6f
#define QKVP 3072       // packed q|k|v row pitch
#define MAXROWS 3072    // 2048 + 8*127 padded to 128
#define MAXTILES (MAXROWS/128)

typedef __attribute__((ext_vector_type(8))) short bf16x8;
typedef __attribute__((ext_vector_type(4))) float f32x4;

__device__ __forceinline__ short f2bf(float f) {
  unsigned u = __float_as_uint(f);
  unsigned r = (u + 0x7FFF + ((u >> 16) & 1)) >> 16;
  return (short)r;
}
__device__ __forceinline__ float bf2f(short h) {
  return __uint_as_float(((unsigned)(unsigned short)h) << 16);
}

// ---------------------------------------------------------------------------
// RMSNorm. MODE 0: fp32 out (outA). MODE 2: hi/lo bf16 planes (outA=hi, outB=lo)
template <int MODE>
__global__ __launch_bounds__(256) void rmsnorm_kernel(
    const float* __restrict__ x, const float* __restrict__ w,
    void* __restrict__ outA, void* __restrict__ outB) {
  int t = blockIdx.x;
  int tid = threadIdx.x;
  float4 xv = ((const float4*)(x + (size_t)t * CD))[tid];
  float ss = xv.x*xv.x + xv.y*xv.y + xv.z*xv.z + xv.w*xv.w;
  for (int off = 32; off > 0; off >>= 1) ss += __shfl_down(ss, off);
  __shared__ float red[4];
  __shared__ float s_scale;
  int lane = tid & 63, wid = tid >> 6;
  if (lane == 0) red[wid] = ss;
  __syncthreads();
  if (tid == 0) {
    float tot = red[0] + red[1] + red[2] + red[3];
    s_scale = rsqrtf(tot / (float)CD + CEPS);
  }
  __syncthreads();
  float sc = s_scale;
  float4 wv = ((const float4*)w)[tid];
  float o[4] = {xv.x * sc * wv.x, xv.y * sc * wv.y,
                xv.z * sc * wv.z, xv.w * sc * wv.w};
  if (MODE == 0) {
    ((float4*)((float*)outA + (size_t)t * CD))[tid] =
        make_float4(o[0], o[1], o[2], o[3]);
  } else {
    short4 hi, lo;
    short* hp = (short*)&hi; short* lp = (short*)&lo;
#pragma unroll
    for (int i = 0; i < 4; ++i) {
      short h = f2bf(o[i]);
      hp[i] = h;
      lp[i] = f2bf(o[i] - bf2f(h));
    }
    ((short4*)((short*)outA + (size_t)t * CD))[tid] = hi;
    ((short4*)((short*)outB + (size_t)t * CD))[tid] = lo;
  }
}

// ---------------------------------------------------------------------------
// Tiled transpose: W[e][Kd][Nd] f32 -> Wth[e][Nd][Kd] bf16 (+ optional lo plane)
__global__ __launch_bounds__(256) void transpose_convert_kernel(
    const float* __restrict__ W, short* __restrict__ Wth,
    short* __restrict__ Wtl, int Kd, int Nd) {
  int e = blockIdx.z;
  const float* Wb = W + (size_t)e * Kd * Nd;
  size_t obase = (size_t)e * Kd * Nd;
  int n0 = blockIdx.x * 32, k0 = blockIdx.y * 32;
  __shared__ float tile[32][33];
  int tx = threadIdx.x & 31, ty = threadIdx.x >> 5;
#pragma unroll
  for (int i = 0; i < 4; ++i)
    tile[ty + i * 8][tx] = Wb[(size_t)(k0 + ty + i * 8) * Nd + n0 + tx];
  __syncthreads();
#pragma unroll
  for (int i = 0; i < 4; ++i) {
    float v = tile[tx][ty + i * 8];
    short hi = f2bf(v);
    size_t oi = obase + (size_t)(n0 + ty + i * 8) * Kd + k0 + tx;
    Wth[oi] = hi;
    if (Wtl) Wtl[oi] = f2bf(v - bf2f(hi));
  }
}

__global__ void pack_bias_kernel(const float* __restrict__ bq,
                                 const float* __restrict__ bk,
                                 const float* __restrict__ bv,
                                 float* __restrict__ out) {
  int i = blockIdx.x * 256 + threadIdx.x;
  if (i < QKVP)
    out[i] = (i < 1024) ? bq[i] : (i < 2048 ? bk[i - 1024] : bv[i - 2048]);
}

// ---------------------------------------------------------------------------
// Unified bf16 MFMA GEMM, 128x128 tile, BK=32, 4 waves (2x2), 4x4 frags/wave.
// Staging = reg-staged, k-first coalesced global loads (4 lanes share one 64B
// line) + fragment-ordered LDS writes with XOR bank spread (write side 1KB
// contiguous per wave = conflict-free; read side 2-way = free).
// Double-buffered: loads for step t+1 issued before compute(t); one barrier
// per K-step.
// LO=1: A/B given as hi+lo bf16 planes; acc += ah*bh + ah*bl + al*bh (~fp32).
// GROUPED=1: expert-grouped B/bias via tile_e (rows 128-padded per expert).
// gridDim.z>1: split-K -> fp32 partials at part[z][partM][N], no epilogue.
template <int LO, int GROUPED>
__global__ __launch_bounds__(256) void mfma_gemm_kernel(
    const short* __restrict__ Ah, const short* __restrict__ Al,
    const short* __restrict__ Bh, const short* __restrict__ Bl,
    const float* __restrict__ bias, void* __restrict__ Cout,
    float* __restrict__ part, int partM, int N, int K, int silu, int outbf,
    const int* __restrict__ tile_e, const int* __restrict__ total_rows) {
  __shared__ short As0[4096], Bs0[4096], As1[4096], Bs1[4096];
  __shared__ short Als0[LO ? 4096 : 64], Bls0[LO ? 4096 : 64];
  __shared__ short Als1[LO ? 4096 : 64], Bls1[LO ? 4096 : 64];
  int tid = threadIdx.x;
  int m0 = blockIdx.y * 128, n0 = blockIdx.x * 128;
  const short* Bhb = Bh;
  const short* Blb = Bl;
  const float* biasb = bias;
  if (GROUPED) {
    if (m0 >= *total_rows) return;
    int e = tile_e[blockIdx.y];
    Bhb = Bh + (size_t)e * N * K;
    biasb = bias + (size_t)e * N;
  }
  int kz = blockIdx.z;
  int kchunk = K / gridDim.z;
  int kbeg = kz * kchunk;
  int nsteps = kchunk >> 5;  // always even in this pipeline (8..64)
  int lane = tid & 63, w = tid >> 6;
  int wr = w >> 1, wc = w & 1;
  int l15 = lane & 15, l4 = lane >> 4;
  // per-lane XOR constant for fragment-ordered LDS reads
  int xorl = (l15 & 3) ^ ((l15 >> 2) & 3);
  f32x4 acc[4][4] = {};
  bf16x8 vA0[2], vB0[2], vAl0[2], vBl0[2];
  bf16x8 vA1[2], vB1[2], vAl1[2], vBl1[2];

#define LOAD_SET(VA, VB, VAL, VBL, KK)                                        \
  {                                                                           \
    _Pragma("unroll") for (int ic = 0; ic < 2; ++ic) {                        \
      int c = ic * 256 + tid;                                                 \
      int r = c >> 2, g = c & 3;                                              \
      size_t ao = (size_t)(m0 + r) * K + (KK) + g * 8;                        \
      size_t bo = (size_t)(n0 + r) * K + (KK) + g * 8;                        \
      VA[ic] = *(const bf16x8*)(Ah + ao);                                     \
      VB[ic] = *(const bf16x8*)(Bhb + bo);                                    \
      if (LO) {                                                               \
        VAL[ic] = *(const bf16x8*)(Al + ao);                                  \
        VBL[ic] = *(const bf16x8*)(Blb + bo);                                 \
      }                                                                       \
    }                                                                         \
  }

#define WRITE_SET(AS_, BS_, ALS_, BLS_, VA, VB, VAL, VBL)                     \
  {                                                                           \
    _Pragma("unroll") for (int ic = 0; ic < 2; ++ic) {                        \
      int c = ic * 256 + tid;                                                 \
      int r = c >> 2, g = c & 3;                                              \
      int ch = (r * 4 + (g ^ (r & 3) ^ ((r >> 2) & 3))) * 8;                  \
      *(bf16x8*)&AS_[ch] = VA[ic];                                            \
      *(bf16x8*)&BS_[ch] = VB[ic];                                            \
      if (LO) {                                                               \
        *(bf16x8*)&ALS_[ch] = VAL[ic];                                        \
        *(bf16x8*)&BLS_[ch] = VBL[ic];                                        \
      }                                                                       \
    }                                                                         \
  }

#define COMPUTE_SET(AS_, BS_, ALS_, BLS_)                                     \
  {                                                                           \
    bf16x8 ah[4], al[4];                                                      \
    _Pragma("unroll") for (int m = 0; m < 4; ++m) {                           \
      int row = wr * 64 + m * 16 + l15;                                       \
      int idx = (row * 4 + (l4 ^ xorl)) * 8;                                  \
      ah[m] = *(const bf16x8*)&AS_[idx];                                      \
      if (LO) al[m] = *(const bf16x8*)&ALS_[idx];                             \
    }                                                                         \
    _Pragma("unroll") for (int n = 0; n < 4; ++n) {                           \
      int row = wc * 64 + n * 16 + l15;                                       \
      int idx = (row * 4 + (l4 ^ xorl)) * 8;                                  \
      bf16x8 bhn = *(const bf16x8*)&BS_[idx];                                 \
      bf16x8 bln;                                                             \
      if (LO) bln = *(const bf16x8*)&BLS_[idx];                               \
      _Pragma("unroll") for (int m = 0; m < 4; ++m) {                         \
        acc[m][n] = __builtin_amdgcn_mfma_f32_16x16x32_bf16(ah[m], bhn,       \
                                                            acc[m][n], 0, 0, 0); \
        if (LO) {                                                             \
          acc[m][n] = __builtin_amdgcn_mfma_f32_16x16x32_bf16(al[m], bhn,     \
                                                              acc[m][n], 0, 0, 0); \
          acc[m][n] = __builtin_amdgcn_mfma_f32_16x16x32_bf16(ah[m], bln,     \
                                                              acc[m][n], 0, 0, 0); \
        }                                                                     \
      }                                                                       \
    }                                                                         \
  }

  LOAD_SET(vA0, vB0, vAl0, vBl0, kbeg);
  WRITE_SET(As0, Bs0, Als0, Bls0, vA0, vB0, vAl0, vBl0);
  __syncthreads();
  for (int s = 0; s < nsteps; s += 2) {
    int k0 = kbeg + (s << 5);
    bool has1 = (s + 1 < nsteps), has2 = (s + 2 < nsteps);
    if (has1) LOAD_SET(vA1, vB1, vAl1, vBl1, k0 + 32);
    COMPUTE_SET(As0, Bs0, Als0, Bls0);
    if (has1) WRITE_SET(As1, Bs1, Als1, Bls1, vA1, vB1, vAl1, vBl1);
    __syncthreads();
    if (has1) {
      if (has2) LOAD_SET(vA0, vB0, vAl0, vBl0, k0 + 64);
      COMPUTE_SET(As1, Bs1, Als1, Bls1);
      if (has2) WRITE_SET(As0, Bs0, Als0, Bls0, vA0, vB0, vAl0, vBl0);
      __syncthreads();
    }
  }
#undef LOAD_SET
#undef WRITE_SET
#undef COMPUTE_SET

  if (gridDim.z > 1) {
    // split-K: write fp32 partials (bias applied in reduce)
#pragma unroll
    for (int m = 0; m < 4; ++m) {
      int row = m0 + wr * 64 + m * 16 + l4 * 4;
#pragma unroll
      for (int n = 0; n < 4; ++n) {
        int col = n0 + wc * 64 + n * 16 + l15;
#pragma unroll
        for (int q = 0; q < 4; ++q)
          part[((size_t)kz * partM + row + q) * N + col] = acc[m][n][q];
      }
    }
    return;
  }
  float* outf = (float*)Cout;
  short* outb = (short*)Cout;
#pragma unroll
  for (int m = 0; m < 4; ++m) {
    int row = m0 + wr * 64 + m * 16 + l4 * 4;
#pragma unroll
    for (int n = 0; n < 4; ++n) {
      int col = n0 + wc * 64 + n * 16 + l15;
      float bv = biasb[col];
#pragma unroll
      for (int q = 0; q < 4; ++q) {
        float v = acc[m][n][q] + bv;
        if (silu) v = v / (1.f + __expf(-v));
        if (outbf) outb[(size_t)(row + q) * N + col] = f2bf(v);
        else outf[(size_t)(row + q) * N + col] = v;
      }
    }
  }
}

// split-K reduce: out[row][c] = sum_z part[z][row][c] + bias (+res). fp32 out.
__global__ __launch_bounds__(256) void reduce_splitk_kernel(
    const float* __restrict__ part, int partM, int nz,
    const float* __restrict__ bias, const int* __restrict__ tile_e,
    const float* __restrict__ res, float* __restrict__ outp, int N,
    const int* __restrict__ total_rows) {
  int row = blockIdx.x;
  if (total_rows && row >= *total_rows) return;
  const float* bb = bias;
  if (tile_e) bb = bias + (size_t)tile_e[row >> 7] * N;
  for (int c = threadIdx.x * 4; c < N; c += 1024) {
    float4 s = *(const float4*)(part + (size_t)row * N + c);
    for (int z = 1; z < nz; ++z) {
      float4 p = *(const float4*)(part + ((size_t)z * partM + row) * N + c);
      s.x += p.x; s.y += p.y; s.z += p.z; s.w += p.w;
    }
    s.x += bb[c]; s.y += bb[c + 1]; s.z += bb[c + 2]; s.w += bb[c + 3];
    if (res) {
      float4 r = *(const float4*)(res + (size_t)row * N + c);
      s.x += r.x; s.y += r.y; s.z += r.z; s.w += r.w;
    }
    *(float4*)(outp + (size_t)row * N + c) = s;
  }
}

// ---------------------------------------------------------------------------
// Attention scores: S_tile[64q][64k] = Q Kt / 8 per (b,h); packed qkv input.
__global__ __launch_bounds__(256) void scores_kernel(
    const float* __restrict__ qkv, float* __restrict__ scores) {
  int kt = blockIdx.x, qt = blockIdx.y, bh = blockIdx.z;
  if (kt > qt) return;
  int b = bh / CH, h = bh % CH;
  __shared__ float Qs[64][68];
  __shared__ float Ks[64][68];
  int tid = threadIdx.x;
#pragma unroll
  for (int i = 0; i < 4; ++i) {
    int row = (tid >> 4) + i * 16;
    int col = (tid & 15) * 4;
    *(float4*)&Qs[row][col] =
        *(const float4*)(qkv + (size_t)(b * CS + qt * 64 + row) * QKVP + h * CHD + col);
    *(float4*)&Ks[row][col] =
        *(const float4*)(qkv + (size_t)(b * CS + kt * 64 + row) * QKVP + 1024 + h * CHD + col);
  }
  __syncthreads();
  int tx = tid & 15, ty = tid >> 4;
  float acc[4][4] = {};
#pragma unroll 16
  for (int d = 0; d < 64; ++d) {
    float ra[4], rb[4];
#pragma unroll
    for (int i = 0; i < 4; ++i) ra[i] = Qs[ty * 4 + i][d];
#pragma unroll
    for (int j = 0; j < 4; ++j) rb[j] = Ks[tx * 4 + j][d];
#pragma unroll
    for (int i = 0; i < 4; ++i)
#pragma unroll
      for (int j = 0; j < 4; ++j) acc[i][j] += ra[i] * rb[j];
  }
  size_t base = (size_t)bh * CS * CS;
#pragma unroll
  for (int i = 0; i < 4; ++i) {
    int r = qt * 64 + ty * 4 + i;
#pragma unroll
    for (int j = 0; j < 4; ++j) {
      int c = kt * 64 + tx * 4 + j;
      scores[base + (size_t)r * CS + c] = acc[i][j] * 0.125f;
    }
  }
}

// Causal row softmax in-place: row r uses cols 0..r, writes 0 for c>r.
__global__ __launch_bounds__(256) void softmax_kernel(float* __restrict__ scores) {
  int row = blockIdx.x;
  int bh = row / CS, r = row % CS;
  float* p = scores + (size_t)bh * CS * CS + (size_t)r * CS;
  int n = r + 1;
  int tid = threadIdx.x;
  __shared__ float buf[CS];
  __shared__ float redm[4], reds[4], sbc[2];
  float m = -1e30f;
  for (int c = tid; c < n; c += 256) {
    float v = p[c];
    buf[c] = v;
    m = fmaxf(m, v);
  }
  for (int off = 32; off > 0; off >>= 1) m = fmaxf(m, __shfl_down(m, off));
  int lane = tid & 63, wid = tid >> 6;
  if (lane == 0) redm[wid] = m;
  __syncthreads();
  if (tid == 0) sbc[0] = fmaxf(fmaxf(redm[0], redm[1]), fmaxf(redm[2], redm[3]));
  __syncthreads();
  float mmax = sbc[0];
  float s = 0.f;
  for (int c = tid; c < n; c += 256) {
    float e = __expf(buf[c] - mmax);
    buf[c] = e;
    s += e;
  }
  for (int off = 32; off > 0; off >>= 1) s += __shfl_down(s, off);
  if (lane == 0) reds[wid] = s;
  __syncthreads();
  if (tid == 0) sbc[1] = reds[0] + reds[1] + reds[2] + reds[3];
  __syncthreads();
  float inv = 1.0f / sbc[1];
  for (int c = tid; c < CS; c += 256) p[c] = (c < n) ? buf[c] * inv : 0.f;
}

// ctx hi/lo planes = P[64q][S] @ V[S][64d] per (qt, bh); kt<=qt only.
__global__ __launch_bounds__(256) void pv_kernel(
    const float* __restrict__ scores, const float* __restrict__ qkv,
    short* __restrict__ ctxh, short* __restrict__ ctxl) {
  int qt = blockIdx.x, bh = blockIdx.y;
  int b = bh / CH, h = bh % CH;
  __shared__ float Ps[64][68];
  __shared__ float Vs[64][68];
  int tid = threadIdx.x;
  int tx = tid & 15, ty = tid >> 4;
  float acc[4][4] = {};
  size_t base = (size_t)bh * CS * CS;
  for (int kt = 0; kt <= qt; ++kt) {
#pragma unroll
    for (int i = 0; i < 4; ++i) {
      int row = (tid >> 4) + i * 16;
      int col = (tid & 15) * 4;
      *(float4*)&Ps[row][col] =
          *(const float4*)(scores + base + (size_t)(qt * 64 + row) * CS + kt * 64 + col);
      *(float4*)&Vs[row][col] =
          *(const float4*)(qkv + (size_t)(b * CS + kt * 64 + row) * QKVP + 2048 + h * CHD + col);
    }
    __syncthreads();
#pragma unroll 16
    for (int kk = 0; kk < 64; ++kk) {
      float ra[4];
#pragma unroll
      for (int i = 0; i < 4; ++i) ra[i] = Ps[ty * 4 + i][kk];
      float4 rb4 = *(const float4*)&Vs[kk][tx * 4];
      float rb[4] = {rb4.x, rb4.y, rb4.z, rb4.w};
#pragma unroll
      for (int i = 0; i < 4; ++i)
#pragma unroll
        for (int j = 0; j < 4; ++j) acc[i][j] += ra[i] * rb[j];
    }
    __syncthreads();
  }
#pragma unroll
  for (int i = 0; i < 4; ++i)
#pragma unroll
    for (int j = 0; j < 4; ++j) {
      size_t oi =
          (size_t)(b * CS + qt * 64 + ty * 4 + i) * CD + h * CHD + tx * 4 + j;
      float v = acc[i][j];
      short hi = f2bf(v);
      ctxh[oi] = hi;
      ctxl[oi] = f2bf(v - bf2f(hi));
    }
}

// ---------------------------------------------------------------------------
__global__ void zero_kernel(int* cursor) {
  int i = threadIdx.x;
  if (i < CE) cursor[i] = 0;
}

// Router: one WAVE per token. Shuffle-reduce 8 logits; lane 0 does softmax +
// top-2 and writes per-token outputs. NO global atomics (stats in finalize).
__global__ __launch_bounds__(64) void router_kernel(
    const float* __restrict__ h2, const float* __restrict__ wr,
    const float* __restrict__ br, int* __restrict__ top_i,
    float* __restrict__ top_p, float* __restrict__ probs_out) {
  int t = blockIdx.x;
  int lane = threadIdx.x;
  float a[CE] = {};
  const float4* hv4 = (const float4*)(h2 + (size_t)t * CD);
#pragma unroll
  for (int i = 0; i < 4; ++i) {
    float4 hv = hv4[lane * 4 + i];
    const float* wrow = wr + (size_t)(lane * 16 + i * 4) * CE;
    float hh[4] = {hv.x, hv.y, hv.z, hv.w};
#pragma unroll
    for (int j = 0; j < 4; ++j)
#pragma unroll
      for (int e = 0; e < CE; ++e) a[e] += hh[j] * wrow[j * CE + e];
  }
#pragma unroll
  for (int e = 0; e < CE; ++e)
    for (int off = 32; off > 0; off >>= 1) a[e] += __shfl_down(a[e], off);
  if (lane == 0) {
    float probs[CE];
    float mx = -1e30f;
#pragma unroll
    for (int e = 0; e < CE; ++e) {
      a[e] += br[e];
      mx = fmaxf(mx, a[e]);
    }
    float sum = 0.f;
#pragma unroll
    for (int e = 0; e < CE; ++e) { probs[e] = __expf(a[e] - mx); sum += probs[e]; }
    float inv = 1.0f / sum;
#pragma unroll
    for (int e = 0; e < CE; ++e) {
      probs[e] *= inv;
      probs_out[t * CE + e] = probs[e];
    }
    int i1 = 0;
#pragma unroll
    for (int e = 1; e < CE; ++e) if (probs[e] > probs[i1]) i1 = e;
    int i2 = (i1 == 0) ? 1 : 0;
#pragma unroll
    for (int e = 0; e < CE; ++e)
      if (e != i1 && probs[e] > probs[i2]) i2 = e;
    float p1 = probs[i1], p2 = probs[i2];
    float s12 = p1 + p2;
    top_i[t * 2 + 0] = i1;
    top_i[t * 2 + 1] = i2;
    top_p[t * 2 + 0] = p1 / s12;
    top_p[t * 2 + 1] = p2 / s12;
  }
}

// Finalize (1 block): deterministic counts/psum reduction from top_i/probs,
// then 128-aligned per-expert offsets, tile->expert map, aux loss, row_map init.
__global__ __launch_bounds__(256) void finalize_kernel(
    const int* __restrict__ top_i, const float* __restrict__ probs,
    int* __restrict__ offs, int* __restrict__ tile_e,
    int* __restrict__ total_padded, int* __restrict__ row_map,
    float* __restrict__ aux_out) {
  int tid = threadIdx.x;
  __shared__ float redp[256][CE];
  __shared__ int redc[256][CE];
  float lp[CE] = {};
  int lc[CE] = {};
  for (int t = tid; t < CT; t += 256) {
    lc[top_i[t * 2 + 0]]++;
    lc[top_i[t * 2 + 1]]++;
#pragma unroll
    for (int e = 0; e < CE; ++e) lp[e] += probs[t * CE + e];
  }
#pragma unroll
  for (int e = 0; e < CE; ++e) { redp[tid][e] = lp[e]; redc[tid][e] = lc[e]; }
  __syncthreads();
  for (int s = 128; s > 0; s >>= 1) {
    if (tid < s) {
#pragma unroll
      for (int e = 0; e < CE; ++e) {
        redp[tid][e] += redp[tid + s][e];
        redc[tid][e] += redc[tid + s][e];
      }
    }
    __syncthreads();
  }
  __shared__ int s_off[CE + 1];
  if (tid == 0) {
    int o = 0;
    for (int e = 0; e < CE; ++e) {
      s_off[e] = o;
      offs[e] = o;
      o += ((redc[0][e] + 127) >> 7) << 7;
    }
    s_off[CE] = o;
    offs[CE] = o;
    *total_padded = o;
    int nt = o >> 7;
    for (int i = 0; i < nt; ++i) {
      int e = 0;
      while (e < CE - 1 && i * 128 >= s_off[e + 1]) e++;
      tile_e[i] = e;
    }
    float aux = 0.f;
    for (int e = 0; e < CE; ++e)
      aux += ((float)redc[0][e] / (float)(CT * CK)) * (redp[0][e] / (float)CT);
    aux_out[0] = aux * (float)CE;
  }
  __syncthreads();
  for (int i = tid; i < MAXROWS; i += blockDim.x) row_map[i] = -1;
}

__global__ void gather_kernel(const int* __restrict__ top_i,
                              const int* __restrict__ offs,
                              int* __restrict__ cursor, int* __restrict__ row_map,
                              int* __restrict__ row_of) {
  int idx = blockIdx.x * blockDim.x + threadIdx.x;
  if (idx >= CT * CK) return;
  int e = top_i[idx];
  int pos = offs[e] + atomicAdd(&cursor[e], 1);
  row_map[pos] = idx >> 1;
  row_of[idx] = pos;
}

// Xg[row] = bf16(h2[row_map[row]]) or zeros for pad rows.
__global__ __launch_bounds__(256) void gatherx_kernel(
    const float* __restrict__ h2, const int* __restrict__ row_map,
    short* __restrict__ Xg) {
  int row = blockIdx.x;
  int tid = threadIdx.x;
  int tok = row_map[row];
  short4 o;
  if (tok < 0) {
    o = make_short4(0, 0, 0, 0);
  } else {
    float4 v = ((const float4*)(h2 + (size_t)tok * CD))[tid];
    o = make_short4(f2bf(v.x), f2bf(v.y), f2bf(v.z), f2bf(v.w));
  }
  ((short4*)(Xg + (size_t)row * CD))[tid] = o;
}

// out[t] = x1[t] + sum_k top_p[t,k] * ff_rows[row_of[t,k]]
__global__ __launch_bounds__(256) void combine_kernel(
    const float* __restrict__ x1, const float* __restrict__ ff_rows,
    const int* __restrict__ row_of, const float* __restrict__ top_p,
    float* __restrict__ out) {
  int t = blockIdx.x;
  int tid = threadIdx.x;
  float4 r = ((const float4*)(x1 + (size_t)t * CD))[tid];
#pragma unroll
  for (int s = 0; s < CK; ++s) {
    float w = top_p[t * 2 + s];
    int row = row_of[t * 2 + s];
    float4 f = ((const float4*)(ff_rows + (size_t)row * CD))[tid];
    r.x += w * f.x; r.y += w * f.y; r.z += w * f.z; r.w += w * f.w;
  }
  ((float4*)(out + (size_t)t * CD))[tid] = r;
}

// ---------------------------------------------------------------------------
extern "C" void kernel_launch(void* const* d_in, const int* in_sizes, int n_in,
                              void* d_out, int out_size, void* d_ws,
                              size_t ws_size, hipStream_t stream) {
  const float* x   = (const float*)d_in[0];
  const float* n1w = (const float*)d_in[1];
  const float* n2w = (const float*)d_in[2];
  const float* wq  = (const float*)d_in[3];
  const float* bq  = (const float*)d_in[4];
  const float* wk  = (const float*)d_in[5];
  const float* bk  = (const float*)d_in[6];
  const float* wv  = (const float*)d_in[7];
  const float* bv  = (const float*)d_in[8];
  const float* wo  = (const float*)d_in[9];
  const float* bo  = (const float*)d_in[10];
  const float* wr  = (const float*)d_in[11];
  const float* br  = (const float*)d_in[12];
  const float* w1  = (const float*)d_in[13];
  const float* b1  = (const float*)d_in[14];
  const float* w2  = (const float*)d_in[15];
  const float* b2  = (const float*)d_in[16];
  float* out = (float*)d_out;

  char* base = (char*)d_ws;
  size_t off = 0;
  auto alloc = [&](size_t bytes) -> void* {
    void* p = base + off;
    off += (bytes + 255) & ~(size_t)255;
    return p;
  };
  float* f_x1   = (float*)alloc((size_t)CT * CD * 4);
  float* f_h2   = (float*)alloc((size_t)CT * CD * 4);
  short* f_xg   = (short*)alloc((size_t)MAXROWS * CD * 2);
  short* f_hid  = (short*)alloc((size_t)MAXROWS * CF * 2);
  float* f_ff   = (float*)alloc((size_t)MAXROWS * CD * 4);
  // attention-phase buffers (hi/lo planes)
  short* f_hh   = (short*)alloc((size_t)CT * CD * 2);
  short* f_hl   = (short*)alloc((size_t)CT * CD * 2);
  short* f_wqkvh = (short*)alloc((size_t)QKVP * CD * 2);
  short* f_wqkvl = (short*)alloc((size_t)QKVP * CD * 2);
  float* f_qkv  = (float*)alloc((size_t)CT * QKVP * 4);
  short* f_ctxh = (short*)alloc((size_t)CT * CD * 2);
  short* f_ctxl = (short*)alloc((size_t)CT * CD * 2);
  short* f_woth = (short*)alloc((size_t)CD * CD * 2);
  short* f_wotl = (short*)alloc((size_t)CD * CD * 2);
  float* f_bqkv = (float*)alloc(QKVP * 4);
  float* f_topp = (float*)alloc(CT * CK * 4);
  float* f_probs = (float*)alloc(CT * CE * 4);
  int* i_topi   = (int*)alloc(CT * CK * 4);
  int* i_rowof  = (int*)alloc(CT * CK * 4);
  int* i_rowmap = (int*)alloc(MAXROWS * 4);
  int* i_cursor = (int*)alloc(CE * 4);
  int* i_offs   = (int*)alloc((CE + 1) * 4);
  int* i_tile   = (int*)alloc(MAXTILES * 4);
  int* i_total  = (int*)alloc(4);
  // G (64MB): w1t -> w2t (sequential reuse)
  short* f_wG = (short*)alloc((size_t)CE * CD * CF * 2);
  short* f_w1t = f_wG;
  short* f_w2t = f_wG;
  // Rs (32MB): QKV partials (2x1024x3072) -> scores -> WO partials (4x1024x1024)
  //            -> GEMM2 partials (2x3072x1024), all disjoint lifetimes
  void* Rs = alloc((size_t)CBH * CS * CS * 4);
  float* f_partqkv = (float*)Rs;
  float* f_scores = (float*)Rs;
  float* f_partwo = (float*)Rs;
  float* f_partg2 = (float*)Rs;

  dim3 b256(256);

  zero_kernel<<<1, 64, 0, stream>>>(i_cursor);
  pack_bias_kernel<<<QKVP / 256, b256, 0, stream>>>(bq, bk, bv, f_bqkv);
  // weight preprocessing (hi/lo planes for attention, hi-only for experts' w1)
  transpose_convert_kernel<<<dim3(32, 32, 1), b256, 0, stream>>>(
      wq, f_wqkvh + 0 * (size_t)CD * CD, f_wqkvl + 0 * (size_t)CD * CD, CD, CD);
  transpose_convert_kernel<<<dim3(32, 32, 1), b256, 0, stream>>>(
      wk, f_wqkvh + 1 * (size_t)CD * CD, f_wqkvl + 1 * (size_t)CD * CD, CD, CD);
  transpose_convert_kernel<<<dim3(32, 32, 1), b256, 0, stream>>>(
      wv, f_wqkvh + 2 * (size_t)CD * CD, f_wqkvl + 2 * (size_t)CD * CD, CD, CD);
  transpose_convert_kernel<<<dim3(32, 32, 1), b256, 0, stream>>>(
      wo, f_woth, f_wotl, CD, CD);
  transpose_convert_kernel<<<dim3(CF / 32, CD / 32, CE), b256, 0, stream>>>(
      w1, f_w1t, nullptr, CD, CF);

  // ---- attention (hi/lo MFMA projections; fp32 scores/softmax/pv) ----
  rmsnorm_kernel<2><<<CT, b256, 0, stream>>>(x, n1w, f_hh, f_hl);
  // fused QKV: [1024,1024] @ [1024,3072], split-K=2 partials + reduce
  mfma_gemm_kernel<1, 0><<<dim3(QKVP / 128, CT / 128, 2), b256, 0, stream>>>(
      f_hh, f_hl, f_wqkvh, f_wqkvl, nullptr, nullptr, f_partqkv, CT, QKVP, CD,
      0, 0, nullptr, nullptr);
  reduce_splitk_kernel<<<CT, b256, 0, stream>>>(f_partqkv, CT, 2, f_bqkv,
                                                nullptr, nullptr, f_qkv, QKVP,
                                                nullptr);
  scores_kernel<<<dim3(CS / 64, CS / 64, CBH), b256, 0, stream>>>(f_qkv, f_scores);
  softmax_kernel<<<CBH * CS, b256, 0, stream>>>(f_scores);
  pv_kernel<<<dim3(CS / 64, CBH), b256, 0, stream>>>(f_scores, f_qkv, f_ctxh,
                                                     f_ctxl);
  // WO: split-K=4 partials (scores now dead), reduce adds bo + residual x
  mfma_gemm_kernel<1, 0><<<dim3(CD / 128, CT / 128, 4), b256, 0, stream>>>(
      f_ctxh, f_ctxl, f_woth, f_wotl, nullptr, nullptr, f_partwo, CT, CD, CD,
      0, 0, nullptr, nullptr);
  reduce_splitk_kernel<<<CT, b256, 0, stream>>>(f_partwo, CT, 4, bo, nullptr, x,
                                                f_x1, CD, nullptr);

  // ---- MoE ----
  rmsnorm_kernel<0><<<CT, b256, 0, stream>>>(f_x1, n2w, f_h2, nullptr);
  router_kernel<<<CT, dim3(64), 0, stream>>>(f_h2, wr, br, i_topi, f_topp,
                                             f_probs);
  finalize_kernel<<<1, 256, 0, stream>>>(i_topi, f_probs, i_offs, i_tile,
                                         i_total, i_rowmap,
                                         out + (size_t)CT * CD);
  gather_kernel<<<(CT * CK + 255) / 256, b256, 0, stream>>>(i_topi, i_offs,
                                                            i_cursor, i_rowmap,
                                                            i_rowof);
  gatherx_kernel<<<MAXROWS, b256, 0, stream>>>(f_h2, i_rowmap, f_xg);

  // expert GEMM1: hid = silu(Xg @ w1[e] + b1[e])  (bf16 out, no split)
  mfma_gemm_kernel<0, 1><<<dim3(CF / 128, MAXTILES, 1), b256, 0, stream>>>(
      f_xg, nullptr, f_w1t, nullptr, b1, f_hid, nullptr, 0, CF, CD, 1, 1,
      i_tile, i_total);
  // expert GEMM2: split-K=2 partials, reduce adds b2[e]
  transpose_convert_kernel<<<dim3(CD / 32, CF / 32, CE), b256, 0, stream>>>(
      w2, f_w2t, nullptr, CF, CD);
  mfma_gemm_kernel<0, 1><<<dim3(CD / 128, MAXTILES, 2), b256, 0, stream>>>(
      f_hid, nullptr, f_w2t, nullptr, nullptr, nullptr, f_partg2, MAXROWS, CD,
      CF, 0, 0, i_tile, i_total);
  reduce_splitk_kernel<<<MAXROWS, b256, 0, stream>>>(f_partg2, MAXROWS, 2, b2,
                                                     i_tile, nullptr, f_ff, CD,
                                                     i_total);

  combine_kernel<<<CT, b256, 0, stream>>>(f_x1, f_ff, i_rowof, f_topp, out);
}

// Round 8
// 399.948 us; speedup vs baseline: 2.8635x; 1.0638x over previous
//
#include <hip/hip_runtime.h>
#include <math.h>

// Problem constants
#define CB 2
#define CS 512
#define CD 1024
#define CH 16
#define CHD 64
#define CF 4096
#define CE 8
#define CK 2
#define CT (CB*CS)      // 1024 tokens
#define CBH (CB*CH)     // 32 (batch*heads)
#define CEPS 1e-6f
#define QKVP 3072       // packed q|k|v row pitch
#define MAXROWS 3072    // 2048 + 8*127 padded to 128
#define MAXTILES (MAXROWS/128)

typedef __attribute__((ext_vector_type(8))) short bf16x8;
typedef __attribute__((ext_vector_type(4))) float f32x4;

__device__ __forceinline__ short f2bf(float f) {
  unsigned u = __float_as_uint(f);
  unsigned r = (u + 0x7FFF + ((u >> 16) & 1)) >> 16;
  return (short)r;
}
__device__ __forceinline__ float bf2f(short h) {
  return __uint_as_float(((unsigned)(unsigned short)h) << 16);
}

__device__ __forceinline__ void gload_lds16(const void* g, void* l) {
  __builtin_amdgcn_global_load_lds(
      (const __attribute__((address_space(1))) unsigned int*)g,
      (__attribute__((address_space(3))) unsigned int*)l, 16, 0, 0);
}

// ---------------------------------------------------------------------------
// RMSNorm. MODE 0: fp32 out (outA). MODE 2: hi/lo bf16 planes (outA=hi, outB=lo)
template <int MODE>
__global__ __launch_bounds__(256) void rmsnorm_kernel(
    const float* __restrict__ x, const float* __restrict__ w,
    void* __restrict__ outA, void* __restrict__ outB) {
  int t = blockIdx.x;
  int tid = threadIdx.x;
  float4 xv = ((const float4*)(x + (size_t)t * CD))[tid];
  float ss = xv.x*xv.x + xv.y*xv.y + xv.z*xv.z + xv.w*xv.w;
  for (int off = 32; off > 0; off >>= 1) ss += __shfl_down(ss, off);
  __shared__ float red[4];
  __shared__ float s_scale;
  int lane = tid & 63, wid = tid >> 6;
  if (lane == 0) red[wid] = ss;
  __syncthreads();
  if (tid == 0) {
    float tot = red[0] + red[1] + red[2] + red[3];
    s_scale = rsqrtf(tot / (float)CD + CEPS);
  }
  __syncthreads();
  float sc = s_scale;
  float4 wv = ((const float4*)w)[tid];
  float o[4] = {xv.x * sc * wv.x, xv.y * sc * wv.y,
                xv.z * sc * wv.z, xv.w * sc * wv.w};
  if (MODE == 0) {
    ((float4*)((float*)outA + (size_t)t * CD))[tid] =
        make_float4(o[0], o[1], o[2], o[3]);
  } else {
    short4 hi, lo;
    short* hp = (short*)&hi; short* lp = (short*)&lo;
#pragma unroll
    for (int i = 0; i < 4; ++i) {
      short h = f2bf(o[i]);
      hp[i] = h;
      lp[i] = f2bf(o[i] - bf2f(h));
    }
    ((short4*)((short*)outA + (size_t)t * CD))[tid] = hi;
    ((short4*)((short*)outB + (size_t)t * CD))[tid] = lo;
  }
}

// ---------------------------------------------------------------------------
// Tiled transpose: W[e][Kd][Nd] f32 -> Wth[e][Nd][Kd] bf16 (+ optional lo plane)
__global__ __launch_bounds__(256) void transpose_convert_kernel(
    const float* __restrict__ W, short* __restrict__ Wth,
    short* __restrict__ Wtl, int Kd, int Nd) {
  int e = blockIdx.z;
  const float* Wb = W + (size_t)e * Kd * Nd;
  size_t obase = (size_t)e * Kd * Nd;
  int n0 = blockIdx.x * 32, k0 = blockIdx.y * 32;
  __shared__ float tile[32][33];
  int tx = threadIdx.x & 31, ty = threadIdx.x >> 5;
#pragma unroll
  for (int i = 0; i < 4; ++i)
    tile[ty + i * 8][tx] = Wb[(size_t)(k0 + ty + i * 8) * Nd + n0 + tx];
  __syncthreads();
#pragma unroll
  for (int i = 0; i < 4; ++i) {
    float v = tile[tx][ty + i * 8];
    short hi = f2bf(v);
    size_t oi = obase + (size_t)(n0 + ty + i * 8) * Kd + k0 + tx;
    Wth[oi] = hi;
    if (Wtl) Wtl[oi] = f2bf(v - bf2f(hi));
  }
}

__global__ void pack_bias_kernel(const float* __restrict__ bq,
                                 const float* __restrict__ bk,
                                 const float* __restrict__ bv,
                                 float* __restrict__ out) {
  int i = blockIdx.x * 256 + threadIdx.x;
  if (i < QKVP)
    out[i] = (i < 1024) ? bq[i] : (i < 2048 ? bk[i - 1024] : bv[i - 2048]);
}

// ---------------------------------------------------------------------------
// MoE grouped GEMM, m248-2ph geometry: BM=128, BN=256, BK=64, 8 waves (2x4),
// per-wave 64x64 out (4x4 16x16x32 frags, 2 k-slices -> 32 MFMA/wave/step).
// Staging via global_load_lds, k-contiguous chunk order (chunk=row*8+slot):
// 8 lanes share a 128B-contiguous global row segment. Source-XOR swizzle
// g = slot ^ (row&7) with matching read-XOR -> 2-way LDS read aliasing (free).
// 2-phase: STAGE(next) issued before COMPUTE(cur); one barrier per K-step.
// gridDim.z>1: split-K partials (bias applied in reduce).
template <int SILU, int OUTBF>
__global__ __launch_bounds__(512) void moe_gemm_kernel(
    const short* __restrict__ A, const short* __restrict__ Bt,
    const float* __restrict__ bias, void* __restrict__ Cout,
    float* __restrict__ part, int partM, int N, int K,
    const int* __restrict__ tile_e, const int* __restrict__ total_rows) {
  __shared__ __align__(16) short A0[128 * 64], A1[128 * 64];
  __shared__ __align__(16) short B0[256 * 64], B1[256 * 64];
  int tid = threadIdx.x;
  int m0 = blockIdx.y * 128, n0 = blockIdx.x * 256;
  if (m0 >= *total_rows) return;
  int e = tile_e[blockIdx.y];
  const short* Bb = Bt + (size_t)e * N * K;
  const float* biasb = bias ? bias + (size_t)e * N : nullptr;
  int kz = blockIdx.z;
  int kchunk = K / gridDim.z;
  int kbeg = kz * kchunk;
  int nsteps = kchunk >> 6;  // BK=64; 16 steps for kchunk=1024
  int lane = tid & 63, w = tid >> 6;
  int wr = w >> 2, wc = w & 3;  // 2 x 4 wave grid
  int l15 = lane & 15, l4 = lane >> 4;
  f32x4 acc[4][4] = {};

  // A: 128 rows x 8 slots = 1024 chunks; 2 insts/thread.
  // B: 256 rows x 8 slots = 2048 chunks; 4 insts/thread.
#define STAGE(AS_, BS_, KK)                                                   \
  {                                                                           \
    _Pragma("unroll") for (int i = 0; i < 2; ++i) {                           \
      int c = i * 512 + tid;                                                  \
      int r = c >> 3, gs = c & 7;                                             \
      int g = gs ^ (r & 7);                                                   \
      gload_lds16(A + (size_t)(m0 + r) * K + (KK) + g * 8, &AS_[c * 8]);      \
    }                                                                         \
    _Pragma("unroll") for (int i = 0; i < 4; ++i) {                           \
      int c = i * 512 + tid;                                                  \
      int r = c >> 3, gs = c & 7;                                             \
      int g = gs ^ (r & 7);                                                   \
      gload_lds16(Bb + (size_t)(n0 + r) * K + (KK) + g * 8, &BS_[c * 8]);     \
    }                                                                         \
  }

#define COMPUTE(AS_, BS_)                                                     \
  {                                                                           \
    _Pragma("unroll") for (int ks = 0; ks < 2; ++ks) {                        \
      bf16x8 a[4], b[4];                                                      \
      _Pragma("unroll") for (int m = 0; m < 4; ++m) {                         \
        int row = wr * 64 + m * 16 + l15;                                     \
        int slot = (ks * 4 + l4) ^ (row & 7);                                 \
        a[m] = *(const bf16x8*)&AS_[(row * 8 + slot) * 8];                    \
      }                                                                       \
      _Pragma("unroll") for (int n = 0; n < 4; ++n) {                         \
        int row = wc * 64 + n * 16 + l15;                                     \
        int slot = (ks * 4 + l4) ^ (row & 7);                                 \
        b[n] = *(const bf16x8*)&BS_[(row * 8 + slot) * 8];                    \
      }                                                                       \
      _Pragma("unroll") for (int m = 0; m < 4; ++m)                           \
      _Pragma("unroll") for (int n = 0; n < 4; ++n)                           \
        acc[m][n] = __builtin_amdgcn_mfma_f32_16x16x32_bf16(a[m], b[n],       \
                                                            acc[m][n], 0, 0, 0); \
    }                                                                         \
  }

  STAGE(A0, B0, kbeg);
  __syncthreads();
  for (int s = 0; s < nsteps; s += 2) {
    int k0 = kbeg + (s << 6);
    bool has1 = (s + 1 < nsteps), has2 = (s + 2 < nsteps);
    if (has1) STAGE(A1, B1, k0 + 64);
    COMPUTE(A0, B0);
    __syncthreads();
    if (has1) {
      if (has2) STAGE(A0, B0, k0 + 128);
      COMPUTE(A1, B1);
      __syncthreads();
    }
  }
#undef STAGE
#undef COMPUTE

  if (gridDim.z > 1) {
#pragma unroll
    for (int m = 0; m < 4; ++m) {
      int row = m0 + wr * 64 + m * 16 + l4 * 4;
#pragma unroll
      for (int n = 0; n < 4; ++n) {
        int col = n0 + wc * 64 + n * 16 + l15;
#pragma unroll
        for (int q = 0; q < 4; ++q)
          part[((size_t)kz * partM + row + q) * N + col] = acc[m][n][q];
      }
    }
    return;
  }
  float* outf = (float*)Cout;
  short* outb = (short*)Cout;
#pragma unroll
  for (int m = 0; m < 4; ++m) {
    int row = m0 + wr * 64 + m * 16 + l4 * 4;
#pragma unroll
    for (int n = 0; n < 4; ++n) {
      int col = n0 + wc * 64 + n * 16 + l15;
      float bv = biasb[col];
#pragma unroll
      for (int q = 0; q < 4; ++q) {
        float v = acc[m][n][q] + bv;
        if (SILU) v = v / (1.f + __expf(-v));
        if (OUTBF) outb[(size_t)(row + q) * N + col] = f2bf(v);
        else outf[(size_t)(row + q) * N + col] = v;
      }
    }
  }
}

// ---------------------------------------------------------------------------
// Attention MFMA GEMM (unchanged from round 7): 128x128 tile, BK=32, 4 waves,
// reg-staged hi/lo bf16 planes (LO=1), split-K partials.
template <int LO>
__global__ __launch_bounds__(256) void mfma_gemm_kernel(
    const short* __restrict__ Ah, const short* __restrict__ Al,
    const short* __restrict__ Bh, const short* __restrict__ Bl,
    float* __restrict__ part, int partM, int N, int K) {
  __shared__ short As0[4096], Bs0[4096], As1[4096], Bs1[4096];
  __shared__ short Als0[LO ? 4096 : 64], Bls0[LO ? 4096 : 64];
  __shared__ short Als1[LO ? 4096 : 64], Bls1[LO ? 4096 : 64];
  int tid = threadIdx.x;
  int m0 = blockIdx.y * 128, n0 = blockIdx.x * 128;
  int kz = blockIdx.z;
  int kchunk = K / gridDim.z;
  int kbeg = kz * kchunk;
  int nsteps = kchunk >> 5;
  int lane = tid & 63, w = tid >> 6;
  int wr = w >> 1, wc = w & 1;
  int l15 = lane & 15, l4 = lane >> 4;
  int xorl = (l15 & 3) ^ ((l15 >> 2) & 3);
  f32x4 acc[4][4] = {};
  bf16x8 vA0[2], vB0[2], vAl0[2], vBl0[2];
  bf16x8 vA1[2], vB1[2], vAl1[2], vBl1[2];

#define LOAD_SET(VA, VB, VAL, VBL, KK)                                        \
  {                                                                           \
    _Pragma("unroll") for (int ic = 0; ic < 2; ++ic) {                        \
      int c = ic * 256 + tid;                                                 \
      int r = c >> 2, g = c & 3;                                              \
      size_t ao = (size_t)(m0 + r) * K + (KK) + g * 8;                        \
      size_t bo = (size_t)(n0 + r) * K + (KK) + g * 8;                        \
      VA[ic] = *(const bf16x8*)(Ah + ao);                                     \
      VB[ic] = *(const bf16x8*)(Bh + bo);                                     \
      if (LO) {                                                               \
        VAL[ic] = *(const bf16x8*)(Al + ao);                                  \
        VBL[ic] = *(const bf16x8*)(Bl + bo);                                  \
      }                                                                       \
    }                                                                         \
  }

#define WRITE_SET(AS_, BS_, ALS_, BLS_, VA, VB, VAL, VBL)                     \
  {                                                                           \
    _Pragma("unroll") for (int ic = 0; ic < 2; ++ic) {                        \
      int c = ic * 256 + tid;                                                 \
      int r = c >> 2, g = c & 3;                                              \
      int ch = (r * 4 + (g ^ (r & 3) ^ ((r >> 2) & 3))) * 8;                  \
      *(bf16x8*)&AS_[ch] = VA[ic];                                            \
      *(bf16x8*)&BS_[ch] = VB[ic];                                            \
      if (LO) {                                                               \
        *(bf16x8*)&ALS_[ch] = VAL[ic];                                        \
        *(bf16x8*)&BLS_[ch] = VBL[ic];                                        \
      }                                                                       \
    }                                                                         \
  }

#define COMPUTE_SET(AS_, BS_, ALS_, BLS_)                                     \
  {                                                                           \
    bf16x8 ah[4], al[4];                                                      \
    _Pragma("unroll") for (int m = 0; m < 4; ++m) {                           \
      int row = wr * 64 + m * 16 + l15;                                       \
      int idx = (row * 4 + (l4 ^ xorl)) * 8;                                  \
      ah[m] = *(const bf16x8*)&AS_[idx];                                      \
      if (LO) al[m] = *(const bf16x8*)&ALS_[idx];                             \
    }                                                                         \
    _Pragma("unroll") for (int n = 0; n < 4; ++n) {                           \
      int row = wc * 64 + n * 16 + l15;                                       \
      int idx = (row * 4 + (l4 ^ xorl)) * 8;                                  \
      bf16x8 bhn = *(const bf16x8*)&BS_[idx];                                 \
      bf16x8 bln;                                                             \
      if (LO) bln = *(const bf16x8*)&BLS_[idx];                               \
      _Pragma("unroll") for (int m = 0; m < 4; ++m) {                         \
        acc[m][n] = __builtin_amdgcn_mfma_f32_16x16x32_bf16(ah[m], bhn,       \
                                                            acc[m][n], 0, 0, 0); \
        if (LO) {                                                             \
          acc[m][n] = __builtin_amdgcn_mfma_f32_16x16x32_bf16(al[m], bhn,     \
                                                              acc[m][n], 0, 0, 0); \
          acc[m][n] = __builtin_amdgcn_mfma_f32_16x16x32_bf16(ah[m], bln,     \
                                                              acc[m][n], 0, 0, 0); \
        }                                                                     \
      }                                                                       \
    }                                                                         \
  }

  LOAD_SET(vA0, vB0, vAl0, vBl0, kbeg);
  WRITE_SET(As0, Bs0, Als0, Bls0, vA0, vB0, vAl0, vBl0);
  __syncthreads();
  for (int s = 0; s < nsteps; s += 2) {
    int k0 = kbeg + (s << 5);
    bool has1 = (s + 1 < nsteps), has2 = (s + 2 < nsteps);
    if (has1) LOAD_SET(vA1, vB1, vAl1, vBl1, k0 + 32);
    COMPUTE_SET(As0, Bs0, Als0, Bls0);
    if (has1) WRITE_SET(As1, Bs1, Als1, Bls1, vA1, vB1, vAl1, vBl1);
    __syncthreads();
    if (has1) {
      if (has2) LOAD_SET(vA0, vB0, vAl0, vBl0, k0 + 64);
      COMPUTE_SET(As1, Bs1, Als1, Bls1);
      if (has2) WRITE_SET(As0, Bs0, Als0, Bls0, vA0, vB0, vAl0, vBl0);
      __syncthreads();
    }
  }
#undef LOAD_SET
#undef WRITE_SET
#undef COMPUTE_SET

#pragma unroll
  for (int m = 0; m < 4; ++m) {
    int row = m0 + wr * 64 + m * 16 + l4 * 4;
#pragma unroll
    for (int n = 0; n < 4; ++n) {
      int col = n0 + wc * 64 + n * 16 + l15;
#pragma unroll
      for (int q = 0; q < 4; ++q)
        part[((size_t)kz * partM + row + q) * N + col] = acc[m][n][q];
    }
  }
}

// split-K reduce: out[row][c] = sum_z part[z][row][c] + bias (+res). fp32 out.
__global__ __launch_bounds__(256) void reduce_splitk_kernel(
    const float* __restrict__ part, int partM, int nz,
    const float* __restrict__ bias, const int* __restrict__ tile_e,
    const float* __restrict__ res, float* __restrict__ outp, int N,
    const int* __restrict__ total_rows) {
  int row = blockIdx.x;
  if (total_rows && row >= *total_rows) return;
  const float* bb = bias;
  if (tile_e) bb = bias + (size_t)tile_e[row >> 7] * N;
  for (int c = threadIdx.x * 4; c < N; c += 1024) {
    float4 s = *(const float4*)(part + (size_t)row * N + c);
    for (int z = 1; z < nz; ++z) {
      float4 p = *(const float4*)(part + ((size_t)z * partM + row) * N + c);
      s.x += p.x; s.y += p.y; s.z += p.z; s.w += p.w;
    }
    s.x += bb[c]; s.y += bb[c + 1]; s.z += bb[c + 2]; s.w += bb[c + 3];
    if (res) {
      float4 r = *(const float4*)(res + (size_t)row * N + c);
      s.x += r.x; s.y += r.y; s.z += r.z; s.w += r.w;
    }
    *(float4*)(outp + (size_t)row * N + c) = s;
  }
}

// ---------------------------------------------------------------------------
// Attention scores: S_tile[64q][64k] = Q Kt / 8 per (b,h); packed qkv input.
__global__ __launch_bounds__(256) void scores_kernel(
    const float* __restrict__ qkv, float* __restrict__ scores) {
  int kt = blockIdx.x, qt = blockIdx.y, bh = blockIdx.z;
  if (kt > qt) return;
  int b = bh / CH, h = bh % CH;
  __shared__ float Qs[64][68];
  __shared__ float Ks[64][68];
  int tid = threadIdx.x;
#pragma unroll
  for (int i = 0; i < 4; ++i) {
    int row = (tid >> 4) + i * 16;
    int col = (tid & 15) * 4;
    *(float4*)&Qs[row][col] =
        *(const float4*)(qkv + (size_t)(b * CS + qt * 64 + row) * QKVP + h * CHD + col);
    *(float4*)&Ks[row][col] =
        *(const float4*)(qkv + (size_t)(b * CS + kt * 64 + row) * QKVP + 1024 + h * CHD + col);
  }
  __syncthreads();
  int tx = tid & 15, ty = tid >> 4;
  float acc[4][4] = {};
#pragma unroll 16
  for (int d = 0; d < 64; ++d) {
    float ra[4], rb[4];
#pragma unroll
    for (int i = 0; i < 4; ++i) ra[i] = Qs[ty * 4 + i][d];
#pragma unroll
    for (int j = 0; j < 4; ++j) rb[j] = Ks[tx * 4 + j][d];
#pragma unroll
    for (int i = 0; i < 4; ++i)
#pragma unroll
      for (int j = 0; j < 4; ++j) acc[i][j] += ra[i] * rb[j];
  }
  size_t base = (size_t)bh * CS * CS;
#pragma unroll
  for (int i = 0; i < 4; ++i) {
    int r = qt * 64 + ty * 4 + i;
#pragma unroll
    for (int j = 0; j < 4; ++j) {
      int c = kt * 64 + tx * 4 + j;
      scores[base + (size_t)r * CS + c] = acc[i][j] * 0.125f;
    }
  }
}

// Causal row softmax in-place: row r uses cols 0..r, writes 0 for c>r.
__global__ __launch_bounds__(256) void softmax_kernel(float* __restrict__ scores) {
  int row = blockIdx.x;
  int bh = row / CS, r = row % CS;
  float* p = scores + (size_t)bh * CS * CS + (size_t)r * CS;
  int n = r + 1;
  int tid = threadIdx.x;
  __shared__ float buf[CS];
  __shared__ float redm[4], reds[4], sbc[2];
  float m = -1e30f;
  for (int c = tid; c < n; c += 256) {
    float v = p[c];
    buf[c] = v;
    m = fmaxf(m, v);
  }
  for (int off = 32; off > 0; off >>= 1) m = fmaxf(m, __shfl_down(m, off));
  int lane = tid & 63, wid = tid >> 6;
  if (lane == 0) redm[wid] = m;
  __syncthreads();
  if (tid == 0) sbc[0] = fmaxf(fmaxf(redm[0], redm[1]), fmaxf(redm[2], redm[3]));
  __syncthreads();
  float mmax = sbc[0];
  float s = 0.f;
  for (int c = tid; c < n; c += 256) {
    float e = __expf(buf[c] - mmax);
    buf[c] = e;
    s += e;
  }
  for (int off = 32; off > 0; off >>= 1) s += __shfl_down(s, off);
  if (lane == 0) reds[wid] = s;
  __syncthreads();
  if (tid == 0) sbc[1] = reds[0] + reds[1] + reds[2] + reds[3];
  __syncthreads();
  float inv = 1.0f / sbc[1];
  for (int c = tid; c < CS; c += 256) p[c] = (c < n) ? buf[c] * inv : 0.f;
}

// ctx hi/lo planes = P[64q][S] @ V[S][64d] per (qt, bh); kt<=qt only.
__global__ __launch_bounds__(256) void pv_kernel(
    const float* __restrict__ scores, const float* __restrict__ qkv,
    short* __restrict__ ctxh, short* __restrict__ ctxl) {
  int qt = blockIdx.x, bh = blockIdx.y;
  int b = bh / CH, h = bh % CH;
  __shared__ float Ps[64][68];
  __shared__ float Vs[64][68];
  int tid = threadIdx.x;
  int tx = tid & 15, ty = tid >> 4;
  float acc[4][4] = {};
  size_t base = (size_t)bh * CS * CS;
  for (int kt = 0; kt <= qt; ++kt) {
#pragma unroll
    for (int i = 0; i < 4; ++i) {
      int row = (tid >> 4) + i * 16;
      int col = (tid & 15) * 4;
      *(float4*)&Ps[row][col] =
          *(const float4*)(scores + base + (size_t)(qt * 64 + row) * CS + kt * 64 + col);
      *(float4*)&Vs[row][col] =
          *(const float4*)(qkv + (size_t)(b * CS + kt * 64 + row) * QKVP + 2048 + h * CHD + col);
    }
    __syncthreads();
#pragma unroll 16
    for (int kk = 0; kk < 64; ++kk) {
      float ra[4];
#pragma unroll
      for (int i = 0; i < 4; ++i) ra[i] = Ps[ty * 4 + i][kk];
      float4 rb4 = *(const float4*)&Vs[kk][tx * 4];
      float rb[4] = {rb4.x, rb4.y, rb4.z, rb4.w};
#pragma unroll
      for (int i = 0; i < 4; ++i)
#pragma unroll
        for (int j = 0; j < 4; ++j) acc[i][j] += ra[i] * rb[j];
    }
    __syncthreads();
  }
#pragma unroll
  for (int i = 0; i < 4; ++i)
#pragma unroll
    for (int j = 0; j < 4; ++j) {
      size_t oi =
          (size_t)(b * CS + qt * 64 + ty * 4 + i) * CD + h * CHD + tx * 4 + j;
      float v = acc[i][j];
      short hi = f2bf(v);
      ctxh[oi] = hi;
      ctxl[oi] = f2bf(v - bf2f(hi));
    }
}

// ---------------------------------------------------------------------------
__global__ void zero_kernel(int* cursor) {
  int i = threadIdx.x;
  if (i < CE) cursor[i] = 0;
}

// Router: one WAVE per token. Shuffle-reduce 8 logits; lane 0 does softmax +
// top-2 and writes per-token outputs. NO global atomics (stats in finalize).
__global__ __launch_bounds__(64) void router_kernel(
    const float* __restrict__ h2, const float* __restrict__ wr,
    const float* __restrict__ br, int* __restrict__ top_i,
    float* __restrict__ top_p, float* __restrict__ probs_out) {
  int t = blockIdx.x;
  int lane = threadIdx.x;
  float a[CE] = {};
  const float4* hv4 = (const float4*)(h2 + (size_t)t * CD);
#pragma unroll
  for (int i = 0; i < 4; ++i) {
    float4 hv = hv4[lane * 4 + i];
    const float* wrow = wr + (size_t)(lane * 16 + i * 4) * CE;
    float hh[4] = {hv.x, hv.y, hv.z, hv.w};
#pragma unroll
    for (int j = 0; j < 4; ++j)
#pragma unroll
      for (int e = 0; e < CE; ++e) a[e] += hh[j] * wrow[j * CE + e];
  }
#pragma unroll
  for (int e = 0; e < CE; ++e)
    for (int off = 32; off > 0; off >>= 1) a[e] += __shfl_down(a[e], off);
  if (lane == 0) {
    float probs[CE];
    float mx = -1e30f;
#pragma unroll
    for (int e = 0; e < CE; ++e) {
      a[e] += br[e];
      mx = fmaxf(mx, a[e]);
    }
    float sum = 0.f;
#pragma unroll
    for (int e = 0; e < CE; ++e) { probs[e] = __expf(a[e] - mx); sum += probs[e]; }
    float inv = 1.0f / sum;
#pragma unroll
    for (int e = 0; e < CE; ++e) {
      probs[e] *= inv;
      probs_out[t * CE + e] = probs[e];
    }
    int i1 = 0;
#pragma unroll
    for (int e = 1; e < CE; ++e) if (probs[e] > probs[i1]) i1 = e;
    int i2 = (i1 == 0) ? 1 : 0;
#pragma unroll
    for (int e = 0; e < CE; ++e)
      if (e != i1 && probs[e] > probs[i2]) i2 = e;
    float p1 = probs[i1], p2 = probs[i2];
    float s12 = p1 + p2;
    top_i[t * 2 + 0] = i1;
    top_i[t * 2 + 1] = i2;
    top_p[t * 2 + 0] = p1 / s12;
    top_p[t * 2 + 1] = p2 / s12;
  }
}

// Finalize (1 block): deterministic counts/psum reduction from top_i/probs,
// then 128-aligned per-expert offsets, tile->expert map, aux loss, row_map init.
__global__ __launch_bounds__(256) void finalize_kernel(
    const int* __restrict__ top_i, const float* __restrict__ probs,
    int* __restrict__ offs, int* __restrict__ tile_e,
    int* __restrict__ total_padded, int* __restrict__ row_map,
    float* __restrict__ aux_out) {
  int tid = threadIdx.x;
  __shared__ float redp[256][CE];
  __shared__ int redc[256][CE];
  float lp[CE] = {};
  int lc[CE] = {};
  for (int t = tid; t < CT; t += 256) {
    lc[top_i[t * 2 + 0]]++;
    lc[top_i[t * 2 + 1]]++;
#pragma unroll
    for (int e = 0; e < CE; ++e) lp[e] += probs[t * CE + e];
  }
#pragma unroll
  for (int e = 0; e < CE; ++e) { redp[tid][e] = lp[e]; redc[tid][e] = lc[e]; }
  __syncthreads();
  for (int s = 128; s > 0; s >>= 1) {
    if (tid < s) {
#pragma unroll
      for (int e = 0; e < CE; ++e) {
        redp[tid][e] += redp[tid + s][e];
        redc[tid][e] += redc[tid + s][e];
      }
    }
    __syncthreads();
  }
  __shared__ int s_off[CE + 1];
  if (tid == 0) {
    int o = 0;
    for (int e = 0; e < CE; ++e) {
      s_off[e] = o;
      offs[e] = o;
      o += ((redc[0][e] + 127) >> 7) << 7;
    }
    s_off[CE] = o;
    offs[CE] = o;
    *total_padded = o;
    int nt = o >> 7;
    for (int i = 0; i < nt; ++i) {
      int e = 0;
      while (e < CE - 1 && i * 128 >= s_off[e + 1]) e++;
      tile_e[i] = e;
    }
    float aux = 0.f;
    for (int e = 0; e < CE; ++e)
      aux += ((float)redc[0][e] / (float)(CT * CK)) * (redp[0][e] / (float)CT);
    aux_out[0] = aux * (float)CE;
  }
  __syncthreads();
  for (int i = tid; i < MAXROWS; i += blockDim.x) row_map[i] = -1;
}

__global__ void gather_kernel(const int* __restrict__ top_i,
                              const int* __restrict__ offs,
                              int* __restrict__ cursor, int* __restrict__ row_map,
                              int* __restrict__ row_of) {
  int idx = blockIdx.x * blockDim.x + threadIdx.x;
  if (idx >= CT * CK) return;
  int e = top_i[idx];
  int pos = offs[e] + atomicAdd(&cursor[e], 1);
  row_map[pos] = idx >> 1;
  row_of[idx] = pos;
}

// Xg[row] = bf16(h2[row_map[row]]) or zeros for pad rows.
__global__ __launch_bounds__(256) void gatherx_kernel(
    const float* __restrict__ h2, const int* __restrict__ row_map,
    short* __restrict__ Xg) {
  int row = blockIdx.x;
  int tid = threadIdx.x;
  int tok = row_map[row];
  short4 o;
  if (tok < 0) {
    o = make_short4(0, 0, 0, 0);
  } else {
    float4 v = ((const float4*)(h2 + (size_t)tok * CD))[tid];
    o = make_short4(f2bf(v.x), f2bf(v.y), f2bf(v.z), f2bf(v.w));
  }
  ((short4*)(Xg + (size_t)row * CD))[tid] = o;
}

// out[t] = x1[t] + sum_k top_p[t,k] * ff_rows[row_of[t,k]]
__global__ __launch_bounds__(256) void combine_kernel(
    const float* __restrict__ x1, const float* __restrict__ ff_rows,
    const int* __restrict__ row_of, const float* __restrict__ top_p,
    float* __restrict__ out) {
  int t = blockIdx.x;
  int tid = threadIdx.x;
  float4 r = ((const float4*)(x1 + (size_t)t * CD))[tid];
#pragma unroll
  for (int s = 0; s < CK; ++s) {
    float w = top_p[t * 2 + s];
    int row = row_of[t * 2 + s];
    float4 f = ((const float4*)(ff_rows + (size_t)row * CD))[tid];
    r.x += w * f.x; r.y += w * f.y; r.z += w * f.z; r.w += w * f.w;
  }
  ((float4*)(out + (size_t)t * CD))[tid] = r;
}

// ---------------------------------------------------------------------------
extern "C" void kernel_launch(void* const* d_in, const int* in_sizes, int n_in,
                              void* d_out, int out_size, void* d_ws,
                              size_t ws_size, hipStream_t stream) {
  const float* x   = (const float*)d_in[0];
  const float* n1w = (const float*)d_in[1];
  const float* n2w = (const float*)d_in[2];
  const float* wq  = (const float*)d_in[3];
  const float* bq  = (const float*)d_in[4];
  const float* wk  = (const float*)d_in[5];
  const float* bk  = (const float*)d_in[6];
  const float* wv  = (const float*)d_in[7];
  const float* bv  = (const float*)d_in[8];
  const float* wo  = (const float*)d_in[9];
  const float* bo  = (const float*)d_in[10];
  const float* wr  = (const float*)d_in[11];
  const float* br  = (const float*)d_in[12];
  const float* w1  = (const float*)d_in[13];
  const float* b1  = (const float*)d_in[14];
  const float* w2  = (const float*)d_in[15];
  const float* b2  = (const float*)d_in[16];
  float* out = (float*)d_out;

  char* base = (char*)d_ws;
  size_t off = 0;
  auto alloc = [&](size_t bytes) -> void* {
    void* p = base + off;
    off += (bytes + 255) & ~(size_t)255;
    return p;
  };
  float* f_x1   = (float*)alloc((size_t)CT * CD * 4);
  float* f_h2   = (float*)alloc((size_t)CT * CD * 4);
  short* f_xg   = (short*)alloc((size_t)MAXROWS * CD * 2);
  short* f_hid  = (short*)alloc((size_t)MAXROWS * CF * 2);
  float* f_ff   = (float*)alloc((size_t)MAXROWS * CD * 4);
  // attention-phase buffers (hi/lo planes)
  short* f_hh   = (short*)alloc((size_t)CT * CD * 2);
  short* f_hl   = (short*)alloc((size_t)CT * CD * 2);
  short* f_wqkvh = (short*)alloc((size_t)QKVP * CD * 2);
  short* f_wqkvl = (short*)alloc((size_t)QKVP * CD * 2);
  float* f_qkv  = (float*)alloc((size_t)CT * QKVP * 4);
  short* f_ctxh = (short*)alloc((size_t)CT * CD * 2);
  short* f_ctxl = (short*)alloc((size_t)CT * CD * 2);
  short* f_woth = (short*)alloc((size_t)CD * CD * 2);
  short* f_wotl = (short*)alloc((size_t)CD * CD * 2);
  float* f_bqkv = (float*)alloc(QKVP * 4);
  float* f_topp = (float*)alloc(CT * CK * 4);
  float* f_probs = (float*)alloc(CT * CE * 4);
  int* i_topi   = (int*)alloc(CT * CK * 4);
  int* i_rowof  = (int*)alloc(CT * CK * 4);
  int* i_rowmap = (int*)alloc(MAXROWS * 4);
  int* i_cursor = (int*)alloc(CE * 4);
  int* i_offs   = (int*)alloc((CE + 1) * 4);
  int* i_tile   = (int*)alloc(MAXTILES * 4);
  int* i_total  = (int*)alloc(4);
  // G (64MB): w1t -> w2t (sequential reuse)
  short* f_wG = (short*)alloc((size_t)CE * CD * CF * 2);
  short* f_w1t = f_wG;
  short* f_w2t = f_wG;
  // Rs (48MB): QKV partials (2x1024x3072) -> scores (32MB) -> WO partials
  //            (4x1024x1024) -> GEMM2 partials (4x3072x1024 = 48MB)
  void* Rs = alloc((size_t)4 * MAXROWS * CD * 4);
  float* f_partqkv = (float*)Rs;
  float* f_scores = (float*)Rs;
  float* f_partwo = (float*)Rs;
  float* f_partg2 = (float*)Rs;

  dim3 b256(256);

  zero_kernel<<<1, 64, 0, stream>>>(i_cursor);
  pack_bias_kernel<<<QKVP / 256, b256, 0, stream>>>(bq, bk, bv, f_bqkv);
  // weight preprocessing (hi/lo planes for attention, hi-only for experts' w1)
  transpose_convert_kernel<<<dim3(32, 32, 1), b256, 0, stream>>>(
      wq, f_wqkvh + 0 * (size_t)CD * CD, f_wqkvl + 0 * (size_t)CD * CD, CD, CD);
  transpose_convert_kernel<<<dim3(32, 32, 1), b256, 0, stream>>>(
      wk, f_wqkvh + 1 * (size_t)CD * CD, f_wqkvl + 1 * (size_t)CD * CD, CD, CD);
  transpose_convert_kernel<<<dim3(32, 32, 1), b256, 0, stream>>>(
      wv, f_wqkvh + 2 * (size_t)CD * CD, f_wqkvl + 2 * (size_t)CD * CD, CD, CD);
  transpose_convert_kernel<<<dim3(32, 32, 1), b256, 0, stream>>>(
      wo, f_woth, f_wotl, CD, CD);
  transpose_convert_kernel<<<dim3(CF / 32, CD / 32, CE), b256, 0, stream>>>(
      w1, f_w1t, nullptr, CD, CF);

  // ---- attention (hi/lo MFMA projections; fp32 scores/softmax/pv) ----
  rmsnorm_kernel<2><<<CT, b256, 0, stream>>>(x, n1w, f_hh, f_hl);
  // fused QKV: [1024,1024] @ [1024,3072], split-K=2 partials + reduce
  mfma_gemm_kernel<1><<<dim3(QKVP / 128, CT / 128, 2), b256, 0, stream>>>(
      f_hh, f_hl, f_wqkvh, f_wqkvl, f_partqkv, CT, QKVP, CD);
  reduce_splitk_kernel<<<CT, b256, 0, stream>>>(f_partqkv, CT, 2, f_bqkv,
                                                nullptr, nullptr, f_qkv, QKVP,
                                                nullptr);
  scores_kernel<<<dim3(CS / 64, CS / 64, CBH), b256, 0, stream>>>(f_qkv, f_scores);
  softmax_kernel<<<CBH * CS, b256, 0, stream>>>(f_scores);
  pv_kernel<<<dim3(CS / 64, CBH), b256, 0, stream>>>(f_scores, f_qkv, f_ctxh,
                                                     f_ctxl);
  // WO: split-K=4 partials (scores now dead), reduce adds bo + residual x
  mfma_gemm_kernel<1><<<dim3(CD / 128, CT / 128, 4), b256, 0, stream>>>(
      f_ctxh, f_ctxl, f_woth, f_wotl, f_partwo, CT, CD, CD);
  reduce_splitk_kernel<<<CT, b256, 0, stream>>>(f_partwo, CT, 4, bo, nullptr, x,
                                                f_x1, CD, nullptr);

  // ---- MoE ----
  rmsnorm_kernel<0><<<CT, b256, 0, stream>>>(f_x1, n2w, f_h2, nullptr);
  router_kernel<<<CT, dim3(64), 0, stream>>>(f_h2, wr, br, i_topi, f_topp,
                                             f_probs);
  finalize_kernel<<<1, 256, 0, stream>>>(i_topi, f_probs, i_offs, i_tile,
                                         i_total, i_rowmap,
                                         out + (size_t)CT * CD);
  gather_kernel<<<(CT * CK + 255) / 256, b256, 0, stream>>>(i_topi, i_offs,
                                                            i_cursor, i_rowmap,
                                                            i_rowof);
  gatherx_kernel<<<MAXROWS, b256, 0, stream>>>(f_h2, i_rowmap, f_xg);

  // expert GEMM1: hid = silu(Xg @ w1[e] + b1[e])  (bf16 out, no split)
  moe_gemm_kernel<1, 1><<<dim3(CF / 256, MAXTILES, 1), dim3(512), 0, stream>>>(
      f_xg, f_w1t, b1, f_hid, nullptr, 0, CF, CD, i_tile, i_total);
  // expert GEMM2: split-K=4 partials, reduce adds b2[e]
  transpose_convert_kernel<<<dim3(CD / 32, CF / 32, CE), b256, 0, stream>>>(
      w2, f_w2t, nullptr, CF, CD);
  moe_gemm_kernel<0, 0><<<dim3(CD / 256, MAXTILES, 4), dim3(512), 0, stream>>>(
      f_hid, f_w2t, nullptr, nullptr, f_partg2, MAXROWS, CD, CF, i_tile,
      i_total);
  reduce_splitk_kernel<<<MAXROWS, b256, 0, stream>>>(f_partg2, MAXROWS, 4, b2,
                                                     i_tile, nullptr, f_ff, CD,
                                                     i_total);

  combine_kernel<<<CT, b256, 0, stream>>>(f_x1, f_ff, i_rowof, f_topp, out);
}